// Round 8
// baseline (2213.626 us; speedup 1.0000x reference)
//
#include <hip/hip_runtime.h>

#define NN 10000
#define EE 160000
#define CC 128
#define NEL 10
#define NGR 16

static inline int cdiv(int a, int b) { return (a + b - 1) / b; }

__device__ __forceinline__ float silu_f(float x) { return x / (1.0f + __expf(-x)); }

// ---------------------------------------------------------------------------
// Generic row-GEMM: out[r][c] = sum_k in[r][k] * W[k][c]   (W row-major, w_ld)
// MODE 0: store   1: store+silu   6: out += (accumulate)
// ---------------------------------------------------------------------------
template <int K, int N, int MODE>
__global__ __launch_bounds__(256) void rowgemm_k(
    const float* __restrict__ in, int in_ld,
    const float* __restrict__ W, int w_ld,
    float* __restrict__ out, int out_ld,
    int R, float scale)
{
    constexpr int TR = 8192 / N;
    constexpr int CG = N / 8;
    constexpr int RG = 256 / CG;
    static_assert(RG * 4 == TR, "tile shape mismatch");
    constexpr int KC = (K < 64 ? K : 64);

    __shared__ float Wl[KC][N];
    __shared__ float inT[K][TR + 4];

    const int tid = threadIdx.x;
    const int cg = tid % CG, rg = tid / CG;
    const int c0 = cg * 8, r0 = rg * 4;
    const int row0 = blockIdx.x * TR;

    for (int i = tid; i < K * TR; i += 256) {
        int r = i / K, k = i - r * K;
        int row = row0 + r;
        inT[k][r] = (row < R) ? in[row * in_ld + k] : 0.0f;
    }

    float acc[4][8];
#pragma unroll
    for (int i = 0; i < 4; ++i)
#pragma unroll
        for (int j = 0; j < 8; ++j) acc[i][j] = 0.0f;

    for (int kc = 0; kc < K; kc += KC) {
        __syncthreads();
        for (int i = tid; i < KC * N; i += 256) {
            int k = i / N, c = i - k * N;
            Wl[k][c] = W[(kc + k) * w_ld + c];
        }
        __syncthreads();
#pragma unroll 8
        for (int kk = 0; kk < KC; ++kk) {
            const float4 a  = *(const float4*)&inT[kc + kk][r0];
            const float4 b0 = *(const float4*)&Wl[kk][c0];
            const float4 b1 = *(const float4*)&Wl[kk][c0 + 4];
            const float av[4] = {a.x, a.y, a.z, a.w};
            const float bv[8] = {b0.x, b0.y, b0.z, b0.w, b1.x, b1.y, b1.z, b1.w};
#pragma unroll
            for (int i = 0; i < 4; ++i)
#pragma unroll
                for (int j = 0; j < 8; ++j)
                    acc[i][j] = fmaf(av[i], bv[j], acc[i][j]);
        }
    }

#pragma unroll
    for (int i = 0; i < 4; ++i) {
        int row = row0 + r0 + i;
        if (row >= R) break;
#pragma unroll
        for (int j = 0; j < 8; ++j) {
            float v = acc[i][j] * scale;
            if constexpr (MODE == 1) v = silu_f(v);
            int idx = row * out_ld + c0 + j;
            if constexpr (MODE == 6) out[idx] += v;
            else out[idx] = v;
        }
    }
}

// ---------------------------------------------------------------------------
// CSR build
// ---------------------------------------------------------------------------
__global__ void k_count(const int* __restrict__ rcv, int* __restrict__ deg)
{
    int e = blockIdx.x * 256 + threadIdx.x;
    if (e < EE) atomicAdd(&deg[rcv[e]], 1);
}

__global__ __launch_bounds__(256) void k_scan(const int* __restrict__ deg,
                                              int* __restrict__ rowptr,
                                              int* __restrict__ cursor)
{
    __shared__ int part[256];
    const int t = threadIdx.x;
    const int PER = (NN + 255) / 256;   // 40
    int base = t * PER;
    int s = 0;
    for (int j = 0; j < PER; ++j) { int idx = base + j; if (idx < NN) s += deg[idx]; }
    part[t] = s;
    __syncthreads();
    for (int off = 1; off < 256; off <<= 1) {
        int v = (t >= off) ? part[t - off] : 0;
        __syncthreads();
        part[t] += v;
        __syncthreads();
    }
    int run = (t == 0) ? 0 : part[t - 1];
    for (int j = 0; j < PER; ++j) {
        int idx = base + j;
        if (idx < NN) { rowptr[idx] = run; cursor[idx] = run; run += deg[idx]; }
    }
    if (t == 255) rowptr[NN] = part[255];
}

__global__ void k_fill(const int* __restrict__ rcv, int* __restrict__ cursor,
                       int* __restrict__ perm)
{
    int e = blockIdx.x * 256 + threadIdx.x;
    if (e >= EE) return;
    int pos = atomicAdd(&cursor[rcv[e]], 1);
    perm[pos] = e;
}

__global__ void k_sortseg(const int* __restrict__ rowptr, int* __restrict__ perm)
{
    int n = blockIdx.x * 256 + threadIdx.x;
    if (n >= NN) return;
    int a = rowptr[n], b = rowptr[n + 1];
    for (int i = a + 1; i < b; ++i) {
        int v = perm[i];
        int j = i - 1;
        while (j >= a && perm[j] > v) { perm[j + 1] = perm[j]; --j; }
        perm[j + 1] = v;
    }
}

// geometry, written in CSR (permuted) edge order
__global__ void k_geom_perm(const float* __restrict__ pos, const float* __restrict__ shifts,
                            const int* __restrict__ snd, const int* __restrict__ rcv,
                            const int* __restrict__ perm,
                            float* __restrict__ Yv, float* __restrict__ ef,
                            int* __restrict__ psnd)
{
    int i = blockIdx.x * 256 + threadIdx.x;
    if (i >= EE) return;
    int e = perm[i];
    int s = snd[e], r = rcv[e];
    psnd[i] = s;
    float vx = pos[r * 3 + 0] - pos[s * 3 + 0] + shifts[e * 3 + 0];
    float vy = pos[r * 3 + 1] - pos[s * 3 + 1] + shifts[e * 3 + 1];
    float vz = pos[r * 3 + 2] - pos[s * 3 + 2] + shifts[e * 3 + 2];
    float len = sqrtf(vx * vx + vy * vy + vz * vz + 1e-12f);
    float inv = 1.0f / len;
    const float SQ3 = 1.7320508075688772f;
    Yv[i * 3 + 0] = SQ3 * vx * inv;
    Yv[i * 3 + 1] = SQ3 * vy * inv;
    Yv[i * 3 + 2] = SQ3 * vz * inv;
    float u = len * 0.2f;
    float fc = 0.0f;
    if (u < 1.0f) {
        float u2 = u * u, u4 = u2 * u2, u5 = u4 * u, u6 = u5 * u, u7 = u6 * u;
        fc = 1.0f - 21.0f * u5 + 35.0f * u6 - 15.0f * u7;
    }
    float pref = 0.6324555320336759f * inv * fc;
    const float PIO5 = 0.6283185307179586f;
#pragma unroll
    for (int n = 1; n <= 8; ++n)
        ef[i * 8 + n - 1] = pref * sinf((float)n * PIO5 * len);
}

// ---------------------------------------------------------------------------
// Layer-1 fused output-GEMM + gather. 8-edge micro-GEMM: each W value is
// loaded ONCE per 8 edges (scalar load, no register-array residency fight —
// rounds 4-7 proved the compiler remats per-edge W loads regardless of
// launch bounds). h-row loads are block-uniform -> L1 broadcast. Partial
// blocks run the same path on padded hb rows; garbage dots never applied.
// ---------------------------------------------------------------------------
__global__ __launch_bounds__(256, 4) void k_gather1(
    const int* __restrict__ rowptr, const int* __restrict__ psnd,
    const float* __restrict__ Yv, const float* __restrict__ hb, int e0, int e1,
    const float* __restrict__ W, int wld,
    const float* __restrict__ gS,
    float* __restrict__ outS, float* __restrict__ outV)
{
    constexpr int NPB = 4;
    const int t = threadIdx.x;
    const int c = t & 127;
    const int hi = t >> 7;
    const int n0 = blockIdx.x * NPB;

    for (int n = n0; n < n0 + NPB; ++n) {
        int rs = rowptr[n], re = rowptr[n + 1];
        if (rs < e0) rs = e0;
        if (re > e1) re = e1;
        float accs = 0.0f, a0 = 0.0f, a1 = 0.0f, a2 = 0.0f;
        for (int i = rs; i < re; i += 8) {
            int ne = re - i; if (ne > 8) ne = 8;
            const float* hbase = hb + (size_t)(i - e0) * 64;
            float d[8] = {0.f, 0.f, 0.f, 0.f, 0.f, 0.f, 0.f, 0.f};
#pragma unroll
            for (int k0 = 0; k0 < 64; k0 += 4) {
                const float w0 = W[(k0 + 0) * wld + t];
                const float w1 = W[(k0 + 1) * wld + t];
                const float w2 = W[(k0 + 2) * wld + t];
                const float w3 = W[(k0 + 3) * wld + t];
#pragma unroll
                for (int j = 0; j < 8; ++j) {
                    const float4 h = *(const float4*)(hbase + j * 64 + k0);
                    d[j] = fmaf(h.x, w0, fmaf(h.y, w1, fmaf(h.z, w2, fmaf(h.w, w3, d[j]))));
                }
            }
#pragma unroll
            for (int j = 0; j < 8; ++j) {
                if (j >= ne) break;
                const int idx = i + j;
                const int s = psnd[idx];
                const float g = gS[s * 128 + c];
                if (hi == 0) {
                    accs = fmaf(d[j], g, accs);
                } else {
                    float tv = d[j] * g;
                    float y0 = Yv[idx * 3], y1 = Yv[idx * 3 + 1], y2 = Yv[idx * 3 + 2];
                    a0 = fmaf(tv, y0, a0); a1 = fmaf(tv, y1, a1); a2 = fmaf(tv, y2, a2);
                }
            }
        }
        if (hi == 0) {
            outS[n * 128 + c] += accs;
        } else {
            outV[n * 384 + c]       += a0;
            outV[n * 384 + 128 + c] += a1;
            outV[n * 384 + 256 + c] += a2;
        }
    }
}

// ---------------------------------------------------------------------------
// Layer-2 merged gather, 512 threads = 4 column groups (w_a,w_b,w_c,w_d).
// Same 8-edge micro-GEMM; W traffic amortized 8x. Partials combined per node
// via LDS (block exclusively owns its nodes -> no atomics).
// ---------------------------------------------------------------------------
__global__ __launch_bounds__(512, 4) void k_gather23(
    const int* __restrict__ rowptr, const int* __restrict__ psnd,
    const float* __restrict__ Yv, const float* __restrict__ hb, int e0, int e1,
    const float* __restrict__ W,   // Wr2_o, 64 x 512
    const float* __restrict__ gS, const float* __restrict__ gV,
    float* __restrict__ outS, float* __restrict__ outV)
{
    constexpr int NPB = 2;
    __shared__ float reds[256];   // grp0 -> [c], grp1 -> [128+c]
    __shared__ float redv[768];   // (p*128+c)*3+d,  p=0 grp2, p=1 grp3
    const int t = threadIdx.x;
    const int c = t & 127;
    const int g = t >> 7;        // 0:w_a 1:w_b 2:w_c 3:w_d (wave-uniform)
    const int n0 = blockIdx.x * NPB;
    const int col = g * 128 + c;
    const bool useS = (g == 0) || (g == 2);

    for (int n = n0; n < n0 + NPB; ++n) {
        int rs = rowptr[n], re = rowptr[n + 1];
        if (rs < e0) rs = e0;
        if (re > e1) re = e1;
        float accs = 0.0f, a0 = 0.0f, a1 = 0.0f, a2 = 0.0f;
        for (int i = rs; i < re; i += 8) {
            int ne = re - i; if (ne > 8) ne = 8;
            const float* hbase = hb + (size_t)(i - e0) * 64;
            float d[8] = {0.f, 0.f, 0.f, 0.f, 0.f, 0.f, 0.f, 0.f};
#pragma unroll
            for (int k0 = 0; k0 < 64; k0 += 4) {
                const float w0 = W[(k0 + 0) * 512 + col];
                const float w1 = W[(k0 + 1) * 512 + col];
                const float w2 = W[(k0 + 2) * 512 + col];
                const float w3 = W[(k0 + 3) * 512 + col];
#pragma unroll
                for (int j = 0; j < 8; ++j) {
                    const float4 h = *(const float4*)(hbase + j * 64 + k0);
                    d[j] = fmaf(h.x, w0, fmaf(h.y, w1, fmaf(h.z, w2, fmaf(h.w, w3, d[j]))));
                }
            }
#pragma unroll
            for (int j = 0; j < 8; ++j) {
                if (j >= ne) break;
                const int idx = i + j;
                const int s = psnd[idx];
                const float dot = d[j];
                const float y0 = Yv[idx * 3], y1 = Yv[idx * 3 + 1], y2 = Yv[idx * 3 + 2];
                if (g == 0) {
                    accs = fmaf(dot, gS[s * 128 + c], accs);
                } else if (g == 1) {
                    float q0 = gV[s * 384 + c];
                    float q1 = gV[s * 384 + 128 + c];
                    float q2 = gV[s * 384 + 256 + c];
                    float hd = q0 * y0 + q1 * y1 + q2 * y2;
                    accs = fmaf(dot, hd * 0.57735026919f, accs);
                } else if (g == 2) {
                    float tv = dot * gS[s * 128 + c];
                    a0 = fmaf(tv, y0, a0); a1 = fmaf(tv, y1, a1); a2 = fmaf(tv, y2, a2);
                } else {
                    a0 = fmaf(dot, gV[s * 384 + c], a0);
                    a1 = fmaf(dot, gV[s * 384 + 128 + c], a1);
                    a2 = fmaf(dot, gV[s * 384 + 256 + c], a2);
                }
            }
        }
        // per-node cross-group reduction
        if (g < 2) {
            reds[g * 128 + c] = accs;
        } else {
            int p = g - 2;
            redv[(p * 128 + c) * 3 + 0] = a0;
            redv[(p * 128 + c) * 3 + 1] = a1;
            redv[(p * 128 + c) * 3 + 2] = a2;
        }
        __syncthreads();
        if (g == 0) {
            outS[n * 128 + c] += reds[c] + reds[128 + c];
        } else {
            int d2 = g - 1;  // 0,1,2
            outV[n * 384 + d2 * 128 + c] += redv[c * 3 + d2] + redv[(128 + c) * 3 + d2];
        }
        __syncthreads();
    }
}

// ---------------------------------------------------------------------------
__global__ void k_species(const float* __restrict__ attrs, int* __restrict__ species)
{
    int n = blockIdx.x * 256 + threadIdx.x;
    if (n >= NN) return;
    int sp = 0;
#pragma unroll
    for (int j = 0; j < NEL; ++j)
        if (attrs[n * NEL + j] > 0.5f) sp = j;
    species[n] = sp;
}

__global__ void k_embed(const float* __restrict__ W_emb, const int* __restrict__ species,
                        float* __restrict__ h)
{
    int t = blockIdx.x * 256 + threadIdx.x;
    if (t >= NN * CC) return;
    int n = t >> 7, c = t & 127;
    h[t] = W_emb[species[n] * CC + c];
}

__global__ void k_rmix(const float* __restrict__ Rmid, const float* __restrict__ Rout,
                       float* __restrict__ rmix)
{
    int c = threadIdx.x;
    float s = 0.f;
#pragma unroll
    for (int k = 0; k < 16; ++k) s = fmaf(Rmid[c * 16 + k], Rout[k], s);
    rmix[c] = s;
}

__global__ void k_B1(const int* __restrict__ species,
                     const float* __restrict__ As_l, const float* __restrict__ Av_l,
                     const float* __restrict__ P_s1, const float* __restrict__ P_ss,
                     const float* __restrict__ P_vv, const float* __restrict__ P_v1,
                     const float* __restrict__ P_sv,
                     float* __restrict__ Bs, float* __restrict__ Bv)
{
    int t = blockIdx.x * 256 + threadIdx.x;
    if (t >= NN * CC) return;
    int n = t >> 7, c = t & 127;
    int sp = species[n];
    int pb = sp * CC + c;
    int vb = n * 384 + c;
    float as = As_l[t];
    float a0 = Av_l[vb], a1 = Av_l[vb + CC], a2 = Av_l[vb + 2 * CC];
    Bs[t] = P_s1[pb] * as + P_ss[pb] * as * as
          + P_vv[pb] * (a0 * a0 + a1 * a1 + a2 * a2) * 0.57735026919f;
    float tv = P_v1[pb] + P_sv[pb] * as;
    Bv[vb] = tv * a0; Bv[vb + CC] = tv * a1; Bv[vb + 2 * CC] = tv * a2;
}

__global__ void k_B2(const int* __restrict__ species,
                     const float* __restrict__ As_l, const float* __restrict__ Av_l,
                     const float* __restrict__ P_v1, const float* __restrict__ P_sv,
                     float* __restrict__ Bv)
{
    int t = blockIdx.x * 256 + threadIdx.x;
    if (t >= NN * CC) return;
    int n = t >> 7, c = t & 127;
    int sp = species[n];
    int pb = sp * CC + c;
    int vb = n * 384 + c;
    float as = As_l[t];
    float tv = P_v1[pb] + P_sv[pb] * as;
    Bv[vb] = tv * Av_l[vb];
    Bv[vb + CC] = tv * Av_l[vb + CC];
    Bv[vb + 2 * CC] = tv * Av_l[vb + 2 * CC];
}

__global__ void k_dip1(const float* __restrict__ h_v, const float* __restrict__ R1,
                       float* __restrict__ dip1)
{
    int n = blockIdx.x, l = threadIdx.x;
    const float* hb = h_v + n * 384;
#pragma unroll
    for (int d = 0; d < 3; ++d) {
        float v = hb[d * CC + l] * R1[l] + hb[d * CC + 64 + l] * R1[64 + l];
        for (int o = 32; o > 0; o >>= 1) v += __shfl_down(v, o);
        if (l == 0) dip1[n * 3 + d] = v;
    }
}

__global__ void k_sc(const int* __restrict__ species, const float* __restrict__ h_v,
                     const float* __restrict__ Wsk, float* __restrict__ h2v)
{
    int n = blockIdx.x, f = threadIdx.x;
    int sp = species[n];
    const float* Wp = Wsk + sp * (CC * CC);
    const float* hvn = h_v + n * 384;
    float a0 = 0.f, a1 = 0.f, a2 = 0.f;
    for (int c = 0; c < CC; ++c) {
        float w = Wp[c * CC + f];
        a0 = fmaf(hvn[c], w, a0);
        a1 = fmaf(hvn[CC + c], w, a1);
        a2 = fmaf(hvn[2 * CC + c], w, a2);
    }
    h2v[n * 384 + f] = a0;
    h2v[n * 384 + CC + f] = a1;
    h2v[n * 384 + 2 * CC + f] = a2;
}

// per-node output: atomic dipole -> out[48+...], graph contribution -> tot[n][3]
__global__ void k_node_out(const float* __restrict__ h2v, const float* __restrict__ rmix,
                           const float* __restrict__ dip1,
                           const float* __restrict__ charges, const float* __restrict__ pos,
                           float* __restrict__ out, float* __restrict__ tot)
{
    int n = blockIdx.x, l = threadIdx.x;
    const float* hb = h2v + n * 384;
    float r0 = rmix[l], r1 = rmix[64 + l];
    float red[3];
#pragma unroll
    for (int d = 0; d < 3; ++d) {
        float v = hb[d * CC + l] * r0 + hb[d * CC + 64 + l] * r1;
        for (int o = 32; o > 0; o >>= 1) v += __shfl_down(v, o);
        red[d] = v;
    }
    if (l == 0) {
        float q = charges[n];
#pragma unroll
        for (int d = 0; d < 3; ++d) {
            float a = dip1[n * 3 + d] + 0.5f * red[d];
            out[48 + n * 3 + d] = a;
            tot[n * 3 + d] = a + q * pos[n * 3 + d];
        }
    }
}

// graph totals: one block per graph, no atomics
__global__ __launch_bounds__(256) void k_greduce(const float* __restrict__ tot,
                                                 const int* __restrict__ batch,
                                                 float* __restrict__ out)
{
    __shared__ float r[256 * 3];
    const int g = blockIdx.x;
    const int t = threadIdx.x;
    float s0 = 0.f, s1 = 0.f, s2 = 0.f;
    for (int n = t; n < NN; n += 256) {
        if (batch[n] == g) {
            s0 += tot[n * 3]; s1 += tot[n * 3 + 1]; s2 += tot[n * 3 + 2];
        }
    }
    r[t] = s0; r[256 + t] = s1; r[512 + t] = s2;
    __syncthreads();
    for (int off = 128; off > 0; off >>= 1) {
        if (t < off) {
            r[t] += r[t + off];
            r[256 + t] += r[256 + t + off];
            r[512 + t] += r[512 + t + off];
        }
        __syncthreads();
    }
    if (t < 3) out[g * 3 + t] = r[t * 256];
}

// ---------------------------------------------------------------------------
extern "C" void kernel_launch(void* const* d_in, const int* in_sizes, int n_in,
                              void* d_out, int out_size, void* d_ws, size_t ws_size,
                              hipStream_t stream)
{
    const float* positions = (const float*)d_in[0];
    const float* node_attrs = (const float*)d_in[1];
    const float* charges = (const float*)d_in[2];
    const float* shifts = (const float*)d_in[3];
    const int*   eidx = (const int*)d_in[4];
    const int*   batch = (const int*)d_in[5];
    const float* W_emb  = (const float*)d_in[7];
    const float* W_up1  = (const float*)d_in[8];
    const float* Wr1_1  = (const float*)d_in[9];
    const float* Wr1_2  = (const float*)d_in[10];
    const float* Wr1_3  = (const float*)d_in[11];
    const float* Wr1_o  = (const float*)d_in[12];
    const float* Wlin1_s = (const float*)d_in[13];
    const float* Wlin1_v = (const float*)d_in[14];
    const float* P1_s1 = (const float*)d_in[15];
    const float* P1_ss = (const float*)d_in[16];
    const float* P1_vv = (const float*)d_in[17];
    const float* P1_v1 = (const float*)d_in[18];
    const float* P1_sv = (const float*)d_in[19];
    const float* Lp1_s = (const float*)d_in[20];
    const float* Lp1_v = (const float*)d_in[21];
    const float* R1    = (const float*)d_in[22];
    const float* Wsk   = (const float*)d_in[23];
    const float* Wup2_s = (const float*)d_in[24];
    const float* Wup2_v = (const float*)d_in[25];
    const float* Wr2_1 = (const float*)d_in[26];
    const float* Wr2_2 = (const float*)d_in[27];
    const float* Wr2_3 = (const float*)d_in[28];
    const float* Wr2_o = (const float*)d_in[29];
    const float* Wlin2_s = (const float*)d_in[30];
    const float* Wlin2_v = (const float*)d_in[31];
    const float* P2_v1 = (const float*)d_in[32];
    const float* P2_sv = (const float*)d_in[33];
    const float* Lp2_v = (const float*)d_in[34];
    const float* Rmid  = (const float*)d_in[35];
    const float* Rout  = (const float*)d_in[36];
    (void)in_sizes; (void)n_in; (void)out_size;

    const int* snd = eidx;
    const int* rcv = eidx + EE;
    float* out = (float*)d_out;

    const int NCH  = (ws_size >= (size_t)175 * 1024 * 1024) ? 1 : 2;
    const int ECHn = EE / NCH;

    char* ws = (char*)d_ws;
    size_t off = 0;
    auto alloc = [&](size_t bytes) -> float* {
        float* p = (float*)(ws + off);
        off = (off + bytes + 255) & ~(size_t)255;
        return p;
    };
    int*   species = (int*)alloc((size_t)NN * 4);
    int*   deg     = (int*)alloc((size_t)NN * 4);
    int*   rowptr  = (int*)alloc((size_t)(NN + 16) * 4);
    int*   cursor  = (int*)alloc((size_t)NN * 4);
    int*   perm    = (int*)alloc((size_t)EE * 4);
    int*   psnd    = (int*)alloc((size_t)EE * 4);
    float* Yv   = alloc((size_t)EE * 3 * 4);
    float* ef   = alloc((size_t)EE * 8 * 4);
    float* A_s  = alloc((size_t)NN * CC * 4);       // A_s / As_l (in place); A2_s
    float* A_v  = alloc((size_t)NN * 3 * CC * 4);   // A_v / Av_l / Bv / A2_v / B2v
    float* hbuf = alloc((size_t)NN * CC * 4);       // h -> Bs -> hs
    float* hu   = alloc((size_t)NN * CC * 4);       // hu -> h_s
    float* h_v  = alloc((size_t)NN * 3 * CC * 4);   // layer-1 vector feats (kept for sc_v)
    float* hv   = alloc((size_t)NN * 3 * CC * 4);
    float* h2v  = alloc((size_t)NN * 3 * CC * 4);
    float* dip1 = alloc((size_t)NN * 3 * 4);
    float* rmix = alloc((size_t)CC * 4);
    float* tot  = alloc((size_t)NN * 3 * 4);
    float* hbA  = alloc((size_t)(ECHn + 8) * 64 * 4);   // +8 rows: padded reads
    float* hbB  = alloc((size_t)(ECHn + 8) * 64 * 4);

    const float inv16 = 1.0f / 16.0f;
    const float one = 1.0f;

    hipMemsetAsync(deg, 0, (size_t)NN * 4, stream);
    hipMemsetAsync(A_s, 0, (size_t)NN * CC * 4, stream);
    hipMemsetAsync(A_v, 0, (size_t)NN * 3 * CC * 4, stream);

    // ---- CSR build + permuted geometry ----
    k_count<<<cdiv(EE, 256), 256, 0, stream>>>(rcv, deg);
    k_scan<<<1, 256, 0, stream>>>(deg, rowptr, cursor);
    k_fill<<<cdiv(EE, 256), 256, 0, stream>>>(rcv, cursor, perm);
    k_sortseg<<<cdiv(NN, 256), 256, 0, stream>>>(rowptr, perm);
    k_geom_perm<<<cdiv(EE, 256), 256, 0, stream>>>(positions, shifts, snd, rcv, perm, Yv, ef, psnd);

    k_species<<<cdiv(NN, 256), 256, 0, stream>>>(node_attrs, species);
    k_embed<<<cdiv(NN * CC, 256), 256, 0, stream>>>(W_emb, species, hbuf);
    k_rmix<<<1, CC, 0, stream>>>(Rmid, Rout, rmix);

    // hu = h @ W_up1
    rowgemm_k<128, 128, 0><<<cdiv(NN, 64), 256, 0, stream>>>(
        hbuf, 128, W_up1, 128, hu, 128, NN, one);

    // ---- layer 1: edge MLP + fused gather ----
    for (int ch = 0; ch < NCH; ++ch) {
        int e0 = ch * ECHn, e1 = e0 + ECHn;
        rowgemm_k<8, 64, 1><<<cdiv(ECHn, 128), 256, 0, stream>>>(
            ef + (size_t)e0 * 8, 8, Wr1_1, 64, hbA, 64, ECHn, one);
        rowgemm_k<64, 64, 1><<<cdiv(ECHn, 128), 256, 0, stream>>>(
            hbA, 64, Wr1_2, 64, hbB, 64, ECHn, one);
        rowgemm_k<64, 64, 1><<<cdiv(ECHn, 128), 256, 0, stream>>>(
            hbB, 64, Wr1_3, 64, hbA, 64, ECHn, one);
        k_gather1<<<NN / 4, 256, 0, stream>>>(
            rowptr, psnd, Yv, hbA, e0, e1, Wr1_o, 256, hu, A_s, A_v);
    }

    // ---- layer 1 node side (Wlin in place) ----
    rowgemm_k<128, 128, 0><<<cdiv(NN, 64), 256, 0, stream>>>(
        A_s, 128, Wlin1_s, 128, A_s, 128, NN, inv16);
    rowgemm_k<128, 128, 0><<<cdiv(3 * NN, 64), 256, 0, stream>>>(
        A_v, 128, Wlin1_v, 128, A_v, 128, 3 * NN, inv16);
    k_B1<<<cdiv(NN * CC, 256), 256, 0, stream>>>(
        species, A_s, A_v, P1_s1, P1_ss, P1_vv, P1_v1, P1_sv, hbuf /*Bs*/, A_v /*Bv*/);
    rowgemm_k<128, 128, 0><<<cdiv(NN, 64), 256, 0, stream>>>(
        hbuf, 128, Lp1_s, 128, hu /*h_s*/, 128, NN, one);
    rowgemm_k<128, 128, 0><<<cdiv(3 * NN, 64), 256, 0, stream>>>(
        A_v /*Bv*/, 128, Lp1_v, 128, h_v, 128, 3 * NN, one);
    k_dip1<<<NN, 64, 0, stream>>>(h_v, R1, dip1);
    rowgemm_k<128, 128, 0><<<cdiv(NN, 64), 256, 0, stream>>>(
        hu /*h_s*/, 128, Wup2_s, 128, hbuf /*hs*/, 128, NN, one);
    rowgemm_k<128, 128, 0><<<cdiv(3 * NN, 64), 256, 0, stream>>>(
        h_v, 128, Wup2_v, 128, hv, 128, 3 * NN, one);

    // ---- layer 2: edge MLP + merged fused gather ----
    hipMemsetAsync(A_s, 0, (size_t)NN * CC * 4, stream);
    hipMemsetAsync(A_v, 0, (size_t)NN * 3 * CC * 4, stream);
    for (int ch = 0; ch < NCH; ++ch) {
        int e0 = ch * ECHn, e1 = e0 + ECHn;
        rowgemm_k<8, 64, 1><<<cdiv(ECHn, 128), 256, 0, stream>>>(
            ef + (size_t)e0 * 8, 8, Wr2_1, 64, hbA, 64, ECHn, one);
        rowgemm_k<64, 64, 1><<<cdiv(ECHn, 128), 256, 0, stream>>>(
            hbA, 64, Wr2_2, 64, hbB, 64, ECHn, one);
        rowgemm_k<64, 64, 1><<<cdiv(ECHn, 128), 256, 0, stream>>>(
            hbB, 64, Wr2_3, 64, hbA, 64, ECHn, one);
        k_gather23<<<NN / 2, 512, 0, stream>>>(
            rowptr, psnd, Yv, hbA, e0, e1, Wr2_o, hbuf /*hs*/, hv, A_s, A_v);
    }

    // ---- layer 2 node side ----
    rowgemm_k<128, 128, 0><<<cdiv(NN, 64), 256, 0, stream>>>(
        A_s, 128, Wlin2_s, 128, A_s, 128, NN, inv16);
    rowgemm_k<128, 128, 0><<<cdiv(3 * NN, 64), 256, 0, stream>>>(
        A_v, 128, Wlin2_v, 128, A_v, 128, 3 * NN, inv16);
    k_sc<<<NN, 128, 0, stream>>>(species, h_v, Wsk, h2v);
    k_B2<<<cdiv(NN * CC, 256), 256, 0, stream>>>(species, A_s, A_v, P2_v1, P2_sv, A_v /*B2v*/);
    rowgemm_k<128, 128, 6><<<cdiv(3 * NN, 64), 256, 0, stream>>>(
        A_v /*B2v*/, 128, Lp2_v, 128, h2v, 128, 3 * NN, one);

    k_node_out<<<NN, 64, 0, stream>>>(h2v, rmix, dip1, charges, positions, out, tot);
    k_greduce<<<NGR, 256, 0, stream>>>(tot, batch, out);
}

// Round 9
// 2053.303 us; speedup vs baseline: 1.0781x; 1.0781x over previous
//
#include <hip/hip_runtime.h>

#define NN 10000
#define EE 160000
#define CC 128
#define NEL 10
#define NGR 16

static inline int cdiv(int a, int b) { return (a + b - 1) / b; }

__device__ __forceinline__ float silu_f(float x) { return x / (1.0f + __expf(-x)); }

// ---------------------------------------------------------------------------
// Generic row-GEMM: out[r][c] = sum_k in[r][k] * W[k][c]   (W row-major, w_ld)
// MODE 0: store   1: store+silu   6: out += (accumulate)
// ---------------------------------------------------------------------------
template <int K, int N, int MODE>
__global__ __launch_bounds__(256) void rowgemm_k(
    const float* __restrict__ in, int in_ld,
    const float* __restrict__ W, int w_ld,
    float* __restrict__ out, int out_ld,
    int R, float scale)
{
    constexpr int TR = 8192 / N;
    constexpr int CG = N / 8;
    constexpr int RG = 256 / CG;
    static_assert(RG * 4 == TR, "tile shape mismatch");
    constexpr int KC = (K < 64 ? K : 64);

    __shared__ float Wl[KC][N];
    __shared__ float inT[K][TR + 4];

    const int tid = threadIdx.x;
    const int cg = tid % CG, rg = tid / CG;
    const int c0 = cg * 8, r0 = rg * 4;
    const int row0 = blockIdx.x * TR;

    for (int i = tid; i < K * TR; i += 256) {
        int r = i / K, k = i - r * K;
        int row = row0 + r;
        inT[k][r] = (row < R) ? in[row * in_ld + k] : 0.0f;
    }

    float acc[4][8];
#pragma unroll
    for (int i = 0; i < 4; ++i)
#pragma unroll
        for (int j = 0; j < 8; ++j) acc[i][j] = 0.0f;

    for (int kc = 0; kc < K; kc += KC) {
        __syncthreads();
        for (int i = tid; i < KC * N; i += 256) {
            int k = i / N, c = i - k * N;
            Wl[k][c] = W[(kc + k) * w_ld + c];
        }
        __syncthreads();
#pragma unroll 8
        for (int kk = 0; kk < KC; ++kk) {
            const float4 a  = *(const float4*)&inT[kc + kk][r0];
            const float4 b0 = *(const float4*)&Wl[kk][c0];
            const float4 b1 = *(const float4*)&Wl[kk][c0 + 4];
            const float av[4] = {a.x, a.y, a.z, a.w};
            const float bv[8] = {b0.x, b0.y, b0.z, b0.w, b1.x, b1.y, b1.z, b1.w};
#pragma unroll
            for (int i = 0; i < 4; ++i)
#pragma unroll
                for (int j = 0; j < 8; ++j)
                    acc[i][j] = fmaf(av[i], bv[j], acc[i][j]);
        }
    }

#pragma unroll
    for (int i = 0; i < 4; ++i) {
        int row = row0 + r0 + i;
        if (row >= R) break;
#pragma unroll
        for (int j = 0; j < 8; ++j) {
            float v = acc[i][j] * scale;
            if constexpr (MODE == 1) v = silu_f(v);
            int idx = row * out_ld + c0 + j;
            if constexpr (MODE == 6) out[idx] += v;
            else out[idx] = v;
        }
    }
}

// ---------------------------------------------------------------------------
// CSR build
// ---------------------------------------------------------------------------
__global__ void k_count(const int* __restrict__ rcv, int* __restrict__ deg)
{
    int e = blockIdx.x * 256 + threadIdx.x;
    if (e < EE) atomicAdd(&deg[rcv[e]], 1);
}

__global__ __launch_bounds__(256) void k_scan(const int* __restrict__ deg,
                                              int* __restrict__ rowptr,
                                              int* __restrict__ cursor)
{
    __shared__ int part[256];
    const int t = threadIdx.x;
    const int PER = (NN + 255) / 256;   // 40
    int base = t * PER;
    int s = 0;
    for (int j = 0; j < PER; ++j) { int idx = base + j; if (idx < NN) s += deg[idx]; }
    part[t] = s;
    __syncthreads();
    for (int off = 1; off < 256; off <<= 1) {
        int v = (t >= off) ? part[t - off] : 0;
        __syncthreads();
        part[t] += v;
        __syncthreads();
    }
    int run = (t == 0) ? 0 : part[t - 1];
    for (int j = 0; j < PER; ++j) {
        int idx = base + j;
        if (idx < NN) { rowptr[idx] = run; cursor[idx] = run; run += deg[idx]; }
    }
    if (t == 255) rowptr[NN] = part[255];
}

__global__ void k_fill(const int* __restrict__ rcv, int* __restrict__ cursor,
                       int* __restrict__ perm)
{
    int e = blockIdx.x * 256 + threadIdx.x;
    if (e >= EE) return;
    int pos = atomicAdd(&cursor[rcv[e]], 1);
    perm[pos] = e;
}

__global__ void k_sortseg(const int* __restrict__ rowptr, int* __restrict__ perm)
{
    int n = blockIdx.x * 256 + threadIdx.x;
    if (n >= NN) return;
    int a = rowptr[n], b = rowptr[n + 1];
    for (int i = a + 1; i < b; ++i) {
        int v = perm[i];
        int j = i - 1;
        while (j >= a && perm[j] > v) { perm[j + 1] = perm[j]; --j; }
        perm[j + 1] = v;
    }
}

// geometry, written in CSR (permuted) edge order
__global__ void k_geom_perm(const float* __restrict__ pos, const float* __restrict__ shifts,
                            const int* __restrict__ snd, const int* __restrict__ rcv,
                            const int* __restrict__ perm,
                            float* __restrict__ Yv, float* __restrict__ ef,
                            int* __restrict__ psnd)
{
    int i = blockIdx.x * 256 + threadIdx.x;
    if (i >= EE) return;
    int e = perm[i];
    int s = snd[e], r = rcv[e];
    psnd[i] = s;
    float vx = pos[r * 3 + 0] - pos[s * 3 + 0] + shifts[e * 3 + 0];
    float vy = pos[r * 3 + 1] - pos[s * 3 + 1] + shifts[e * 3 + 1];
    float vz = pos[r * 3 + 2] - pos[s * 3 + 2] + shifts[e * 3 + 2];
    float len = sqrtf(vx * vx + vy * vy + vz * vz + 1e-12f);
    float inv = 1.0f / len;
    const float SQ3 = 1.7320508075688772f;
    Yv[i * 3 + 0] = SQ3 * vx * inv;
    Yv[i * 3 + 1] = SQ3 * vy * inv;
    Yv[i * 3 + 2] = SQ3 * vz * inv;
    float u = len * 0.2f;
    float fc = 0.0f;
    if (u < 1.0f) {
        float u2 = u * u, u4 = u2 * u2, u5 = u4 * u, u6 = u5 * u, u7 = u6 * u;
        fc = 1.0f - 21.0f * u5 + 35.0f * u6 - 15.0f * u7;
    }
    float pref = 0.6324555320336759f * inv * fc;
    const float PIO5 = 0.6283185307179586f;
#pragma unroll
    for (int n = 1; n <= 8; ++n)
        ef[i * 8 + n - 1] = pref * sinf((float)n * PIO5 * len);
}

// ---------------------------------------------------------------------------
// Layer-1 fused output-GEMM + gather. 4-edge micro-GEMM: W loaded once per
// 4 edges (4x amortization vs per-edge remat), d[4] + one float4 live ->
// ~35 VGPRs, no spill (round 8's 8-edge tile spilled: WRITE_SIZE 990MB).
// ---------------------------------------------------------------------------
__global__ __launch_bounds__(256, 4) void k_gather1(
    const int* __restrict__ rowptr, const int* __restrict__ psnd,
    const float* __restrict__ Yv, const float* __restrict__ hb, int e0, int e1,
    const float* __restrict__ W, int wld,
    const float* __restrict__ gS,
    float* __restrict__ outS, float* __restrict__ outV)
{
    constexpr int NPB = 4;
    const int t = threadIdx.x;
    const int c = t & 127;
    const int hi = t >> 7;
    const int n0 = blockIdx.x * NPB;

    for (int n = n0; n < n0 + NPB; ++n) {
        int rs = rowptr[n], re = rowptr[n + 1];
        if (rs < e0) rs = e0;
        if (re > e1) re = e1;
        float accs = 0.0f, a0 = 0.0f, a1 = 0.0f, a2 = 0.0f;
        for (int i = rs; i < re; i += 4) {
            int ne = re - i; if (ne > 4) ne = 4;
            const float* hbase = hb + (size_t)(i - e0) * 64;
            float d[4] = {0.f, 0.f, 0.f, 0.f};
#pragma unroll
            for (int k0 = 0; k0 < 64; k0 += 4) {
                const float w0 = W[(k0 + 0) * wld + t];
                const float w1 = W[(k0 + 1) * wld + t];
                const float w2 = W[(k0 + 2) * wld + t];
                const float w3 = W[(k0 + 3) * wld + t];
#pragma unroll
                for (int j = 0; j < 4; ++j) {
                    const float4 h = *(const float4*)(hbase + j * 64 + k0);
                    d[j] = fmaf(h.x, w0, fmaf(h.y, w1, fmaf(h.z, w2, fmaf(h.w, w3, d[j]))));
                }
            }
#pragma unroll
            for (int j = 0; j < 4; ++j) {
                if (j >= ne) break;
                const int idx = i + j;
                const int s = psnd[idx];
                const float g = gS[s * 128 + c];
                if (hi == 0) {
                    accs = fmaf(d[j], g, accs);
                } else {
                    float tv = d[j] * g;
                    float y0 = Yv[idx * 3], y1 = Yv[idx * 3 + 1], y2 = Yv[idx * 3 + 2];
                    a0 = fmaf(tv, y0, a0); a1 = fmaf(tv, y1, a1); a2 = fmaf(tv, y2, a2);
                }
            }
        }
        if (hi == 0) {
            outS[n * 128 + c] += accs;
        } else {
            outV[n * 384 + c]       += a0;
            outV[n * 384 + 128 + c] += a1;
            outV[n * 384 + 256 + c] += a2;
        }
    }
}

// ---------------------------------------------------------------------------
// Layer-2 merged gather, 512 threads = 4 column groups (w_a,w_b,w_c,w_d).
// 4-edge micro-GEMM (no spill); partials combined per node via LDS.
// ---------------------------------------------------------------------------
__global__ __launch_bounds__(512, 4) void k_gather23(
    const int* __restrict__ rowptr, const int* __restrict__ psnd,
    const float* __restrict__ Yv, const float* __restrict__ hb, int e0, int e1,
    const float* __restrict__ W,   // Wr2_o, 64 x 512
    const float* __restrict__ gS, const float* __restrict__ gV,
    float* __restrict__ outS, float* __restrict__ outV)
{
    constexpr int NPB = 2;
    __shared__ float reds[256];   // grp0 -> [c], grp1 -> [128+c]
    __shared__ float redv[768];   // (p*128+c)*3+d,  p=0 grp2, p=1 grp3
    const int t = threadIdx.x;
    const int c = t & 127;
    const int g = t >> 7;        // 0:w_a 1:w_b 2:w_c 3:w_d (wave-uniform)
    const int n0 = blockIdx.x * NPB;
    const int col = g * 128 + c;

    for (int n = n0; n < n0 + NPB; ++n) {
        int rs = rowptr[n], re = rowptr[n + 1];
        if (rs < e0) rs = e0;
        if (re > e1) re = e1;
        float accs = 0.0f, a0 = 0.0f, a1 = 0.0f, a2 = 0.0f;
        for (int i = rs; i < re; i += 4) {
            int ne = re - i; if (ne > 4) ne = 4;
            const float* hbase = hb + (size_t)(i - e0) * 64;
            float d[4] = {0.f, 0.f, 0.f, 0.f};
#pragma unroll
            for (int k0 = 0; k0 < 64; k0 += 4) {
                const float w0 = W[(k0 + 0) * 512 + col];
                const float w1 = W[(k0 + 1) * 512 + col];
                const float w2 = W[(k0 + 2) * 512 + col];
                const float w3 = W[(k0 + 3) * 512 + col];
#pragma unroll
                for (int j = 0; j < 4; ++j) {
                    const float4 h = *(const float4*)(hbase + j * 64 + k0);
                    d[j] = fmaf(h.x, w0, fmaf(h.y, w1, fmaf(h.z, w2, fmaf(h.w, w3, d[j]))));
                }
            }
#pragma unroll
            for (int j = 0; j < 4; ++j) {
                if (j >= ne) break;
                const int idx = i + j;
                const int s = psnd[idx];
                const float dot = d[j];
                const float y0 = Yv[idx * 3], y1 = Yv[idx * 3 + 1], y2 = Yv[idx * 3 + 2];
                if (g == 0) {
                    accs = fmaf(dot, gS[s * 128 + c], accs);
                } else if (g == 1) {
                    float q0 = gV[s * 384 + c];
                    float q1 = gV[s * 384 + 128 + c];
                    float q2 = gV[s * 384 + 256 + c];
                    float hd = q0 * y0 + q1 * y1 + q2 * y2;
                    accs = fmaf(dot, hd * 0.57735026919f, accs);
                } else if (g == 2) {
                    float tv = dot * gS[s * 128 + c];
                    a0 = fmaf(tv, y0, a0); a1 = fmaf(tv, y1, a1); a2 = fmaf(tv, y2, a2);
                } else {
                    a0 = fmaf(dot, gV[s * 384 + c], a0);
                    a1 = fmaf(dot, gV[s * 384 + 128 + c], a1);
                    a2 = fmaf(dot, gV[s * 384 + 256 + c], a2);
                }
            }
        }
        // per-node cross-group reduction
        if (g < 2) {
            reds[g * 128 + c] = accs;
        } else {
            int p = g - 2;
            redv[(p * 128 + c) * 3 + 0] = a0;
            redv[(p * 128 + c) * 3 + 1] = a1;
            redv[(p * 128 + c) * 3 + 2] = a2;
        }
        __syncthreads();
        if (g == 0) {
            outS[n * 128 + c] += reds[c] + reds[128 + c];
        } else {
            int d2 = g - 1;  // 0,1,2
            outV[n * 384 + d2 * 128 + c] += redv[c * 3 + d2] + redv[(128 + c) * 3 + d2];
        }
        __syncthreads();
    }
}

// ---------------------------------------------------------------------------
__global__ void k_species(const float* __restrict__ attrs, int* __restrict__ species)
{
    int n = blockIdx.x * 256 + threadIdx.x;
    if (n >= NN) return;
    int sp = 0;
#pragma unroll
    for (int j = 0; j < NEL; ++j)
        if (attrs[n * NEL + j] > 0.5f) sp = j;
    species[n] = sp;
}

__global__ void k_embed(const float* __restrict__ W_emb, const int* __restrict__ species,
                        float* __restrict__ h)
{
    int t = blockIdx.x * 256 + threadIdx.x;
    if (t >= NN * CC) return;
    int n = t >> 7, c = t & 127;
    h[t] = W_emb[species[n] * CC + c];
}

__global__ void k_rmix(const float* __restrict__ Rmid, const float* __restrict__ Rout,
                       float* __restrict__ rmix)
{
    int c = threadIdx.x;
    float s = 0.f;
#pragma unroll
    for (int k = 0; k < 16; ++k) s = fmaf(Rmid[c * 16 + k], Rout[k], s);
    rmix[c] = s;
}

__global__ void k_B1(const int* __restrict__ species,
                     const float* __restrict__ As_l, const float* __restrict__ Av_l,
                     const float* __restrict__ P_s1, const float* __restrict__ P_ss,
                     const float* __restrict__ P_vv, const float* __restrict__ P_v1,
                     const float* __restrict__ P_sv,
                     float* __restrict__ Bs, float* __restrict__ Bv)
{
    int t = blockIdx.x * 256 + threadIdx.x;
    if (t >= NN * CC) return;
    int n = t >> 7, c = t & 127;
    int sp = species[n];
    int pb = sp * CC + c;
    int vb = n * 384 + c;
    float as = As_l[t];
    float a0 = Av_l[vb], a1 = Av_l[vb + CC], a2 = Av_l[vb + 2 * CC];
    Bs[t] = P_s1[pb] * as + P_ss[pb] * as * as
          + P_vv[pb] * (a0 * a0 + a1 * a1 + a2 * a2) * 0.57735026919f;
    float tv = P_v1[pb] + P_sv[pb] * as;
    Bv[vb] = tv * a0; Bv[vb + CC] = tv * a1; Bv[vb + 2 * CC] = tv * a2;
}

__global__ void k_B2(const int* __restrict__ species,
                     const float* __restrict__ As_l, const float* __restrict__ Av_l,
                     const float* __restrict__ P_v1, const float* __restrict__ P_sv,
                     float* __restrict__ Bv)
{
    int t = blockIdx.x * 256 + threadIdx.x;
    if (t >= NN * CC) return;
    int n = t >> 7, c = t & 127;
    int sp = species[n];
    int pb = sp * CC + c;
    int vb = n * 384 + c;
    float as = As_l[t];
    float tv = P_v1[pb] + P_sv[pb] * as;
    Bv[vb] = tv * Av_l[vb];
    Bv[vb + CC] = tv * Av_l[vb + CC];
    Bv[vb + 2 * CC] = tv * Av_l[vb + 2 * CC];
}

__global__ void k_dip1(const float* __restrict__ h_v, const float* __restrict__ R1,
                       float* __restrict__ dip1)
{
    int n = blockIdx.x, l = threadIdx.x;
    const float* hb = h_v + n * 384;
#pragma unroll
    for (int d = 0; d < 3; ++d) {
        float v = hb[d * CC + l] * R1[l] + hb[d * CC + 64 + l] * R1[64 + l];
        for (int o = 32; o > 0; o >>= 1) v += __shfl_down(v, o);
        if (l == 0) dip1[n * 3 + d] = v;
    }
}

__global__ void k_sc(const int* __restrict__ species, const float* __restrict__ h_v,
                     const float* __restrict__ Wsk, float* __restrict__ h2v)
{
    int n = blockIdx.x, f = threadIdx.x;
    int sp = species[n];
    const float* Wp = Wsk + sp * (CC * CC);
    const float* hvn = h_v + n * 384;
    float a0 = 0.f, a1 = 0.f, a2 = 0.f;
    for (int c = 0; c < CC; ++c) {
        float w = Wp[c * CC + f];
        a0 = fmaf(hvn[c], w, a0);
        a1 = fmaf(hvn[CC + c], w, a1);
        a2 = fmaf(hvn[2 * CC + c], w, a2);
    }
    h2v[n * 384 + f] = a0;
    h2v[n * 384 + CC + f] = a1;
    h2v[n * 384 + 2 * CC + f] = a2;
}

// per-node output: atomic dipole -> out[48+...], graph contribution -> tot[n][3]
__global__ void k_node_out(const float* __restrict__ h2v, const float* __restrict__ rmix,
                           const float* __restrict__ dip1,
                           const float* __restrict__ charges, const float* __restrict__ pos,
                           float* __restrict__ out, float* __restrict__ tot)
{
    int n = blockIdx.x, l = threadIdx.x;
    const float* hb = h2v + n * 384;
    float r0 = rmix[l], r1 = rmix[64 + l];
    float red[3];
#pragma unroll
    for (int d = 0; d < 3; ++d) {
        float v = hb[d * CC + l] * r0 + hb[d * CC + 64 + l] * r1;
        for (int o = 32; o > 0; o >>= 1) v += __shfl_down(v, o);
        red[d] = v;
    }
    if (l == 0) {
        float q = charges[n];
#pragma unroll
        for (int d = 0; d < 3; ++d) {
            float a = dip1[n * 3 + d] + 0.5f * red[d];
            out[48 + n * 3 + d] = a;
            tot[n * 3 + d] = a + q * pos[n * 3 + d];
        }
    }
}

// graph totals: one block per graph, no atomics
__global__ __launch_bounds__(256) void k_greduce(const float* __restrict__ tot,
                                                 const int* __restrict__ batch,
                                                 float* __restrict__ out)
{
    __shared__ float r[256 * 3];
    const int g = blockIdx.x;
    const int t = threadIdx.x;
    float s0 = 0.f, s1 = 0.f, s2 = 0.f;
    for (int n = t; n < NN; n += 256) {
        if (batch[n] == g) {
            s0 += tot[n * 3]; s1 += tot[n * 3 + 1]; s2 += tot[n * 3 + 2];
        }
    }
    r[t] = s0; r[256 + t] = s1; r[512 + t] = s2;
    __syncthreads();
    for (int off = 128; off > 0; off >>= 1) {
        if (t < off) {
            r[t] += r[t + off];
            r[256 + t] += r[256 + t + off];
            r[512 + t] += r[512 + t + off];
        }
        __syncthreads();
    }
    if (t < 3) out[g * 3 + t] = r[t * 256];
}

// ---------------------------------------------------------------------------
extern "C" void kernel_launch(void* const* d_in, const int* in_sizes, int n_in,
                              void* d_out, int out_size, void* d_ws, size_t ws_size,
                              hipStream_t stream)
{
    const float* positions = (const float*)d_in[0];
    const float* node_attrs = (const float*)d_in[1];
    const float* charges = (const float*)d_in[2];
    const float* shifts = (const float*)d_in[3];
    const int*   eidx = (const int*)d_in[4];
    const int*   batch = (const int*)d_in[5];
    const float* W_emb  = (const float*)d_in[7];
    const float* W_up1  = (const float*)d_in[8];
    const float* Wr1_1  = (const float*)d_in[9];
    const float* Wr1_2  = (const float*)d_in[10];
    const float* Wr1_3  = (const float*)d_in[11];
    const float* Wr1_o  = (const float*)d_in[12];
    const float* Wlin1_s = (const float*)d_in[13];
    const float* Wlin1_v = (const float*)d_in[14];
    const float* P1_s1 = (const float*)d_in[15];
    const float* P1_ss = (const float*)d_in[16];
    const float* P1_vv = (const float*)d_in[17];
    const float* P1_v1 = (const float*)d_in[18];
    const float* P1_sv = (const float*)d_in[19];
    const float* Lp1_s = (const float*)d_in[20];
    const float* Lp1_v = (const float*)d_in[21];
    const float* R1    = (const float*)d_in[22];
    const float* Wsk   = (const float*)d_in[23];
    const float* Wup2_s = (const float*)d_in[24];
    const float* Wup2_v = (const float*)d_in[25];
    const float* Wr2_1 = (const float*)d_in[26];
    const float* Wr2_2 = (const float*)d_in[27];
    const float* Wr2_3 = (const float*)d_in[28];
    const float* Wr2_o = (const float*)d_in[29];
    const float* Wlin2_s = (const float*)d_in[30];
    const float* Wlin2_v = (const float*)d_in[31];
    const float* P2_v1 = (const float*)d_in[32];
    const float* P2_sv = (const float*)d_in[33];
    const float* Lp2_v = (const float*)d_in[34];
    const float* Rmid  = (const float*)d_in[35];
    const float* Rout  = (const float*)d_in[36];
    (void)in_sizes; (void)n_in; (void)out_size;

    const int* snd = eidx;
    const int* rcv = eidx + EE;
    float* out = (float*)d_out;

    const int NCH  = (ws_size >= (size_t)175 * 1024 * 1024) ? 1 : 2;
    const int ECHn = EE / NCH;

    char* ws = (char*)d_ws;
    size_t off = 0;
    auto alloc = [&](size_t bytes) -> float* {
        float* p = (float*)(ws + off);
        off = (off + bytes + 255) & ~(size_t)255;
        return p;
    };
    int*   species = (int*)alloc((size_t)NN * 4);
    int*   deg     = (int*)alloc((size_t)NN * 4);
    int*   rowptr  = (int*)alloc((size_t)(NN + 16) * 4);
    int*   cursor  = (int*)alloc((size_t)NN * 4);
    int*   perm    = (int*)alloc((size_t)EE * 4);
    int*   psnd    = (int*)alloc((size_t)EE * 4);
    float* Yv   = alloc((size_t)EE * 3 * 4);
    float* ef   = alloc((size_t)EE * 8 * 4);
    float* A_s  = alloc((size_t)NN * CC * 4);       // A_s / As_l (in place); A2_s
    float* A_v  = alloc((size_t)NN * 3 * CC * 4);   // A_v / Av_l / Bv / A2_v / B2v
    float* hbuf = alloc((size_t)NN * CC * 4);       // h -> Bs -> hs
    float* hu   = alloc((size_t)NN * CC * 4);       // hu -> h_s
    float* h_v  = alloc((size_t)NN * 3 * CC * 4);   // layer-1 vector feats (kept for sc_v)
    float* hv   = alloc((size_t)NN * 3 * CC * 4);
    float* h2v  = alloc((size_t)NN * 3 * CC * 4);
    float* dip1 = alloc((size_t)NN * 3 * 4);
    float* rmix = alloc((size_t)CC * 4);
    float* tot  = alloc((size_t)NN * 3 * 4);
    float* hbA  = alloc((size_t)(ECHn + 8) * 64 * 4);   // +8 rows: padded reads
    float* hbB  = alloc((size_t)(ECHn + 8) * 64 * 4);

    const float inv16 = 1.0f / 16.0f;
    const float one = 1.0f;

    hipMemsetAsync(deg, 0, (size_t)NN * 4, stream);
    hipMemsetAsync(A_s, 0, (size_t)NN * CC * 4, stream);
    hipMemsetAsync(A_v, 0, (size_t)NN * 3 * CC * 4, stream);

    // ---- CSR build + permuted geometry ----
    k_count<<<cdiv(EE, 256), 256, 0, stream>>>(rcv, deg);
    k_scan<<<1, 256, 0, stream>>>(deg, rowptr, cursor);
    k_fill<<<cdiv(EE, 256), 256, 0, stream>>>(rcv, cursor, perm);
    k_sortseg<<<cdiv(NN, 256), 256, 0, stream>>>(rowptr, perm);
    k_geom_perm<<<cdiv(EE, 256), 256, 0, stream>>>(positions, shifts, snd, rcv, perm, Yv, ef, psnd);

    k_species<<<cdiv(NN, 256), 256, 0, stream>>>(node_attrs, species);
    k_embed<<<cdiv(NN * CC, 256), 256, 0, stream>>>(W_emb, species, hbuf);
    k_rmix<<<1, CC, 0, stream>>>(Rmid, Rout, rmix);

    // hu = h @ W_up1
    rowgemm_k<128, 128, 0><<<cdiv(NN, 64), 256, 0, stream>>>(
        hbuf, 128, W_up1, 128, hu, 128, NN, one);

    // ---- layer 1: edge MLP + fused gather ----
    for (int ch = 0; ch < NCH; ++ch) {
        int e0 = ch * ECHn, e1 = e0 + ECHn;
        rowgemm_k<8, 64, 1><<<cdiv(ECHn, 128), 256, 0, stream>>>(
            ef + (size_t)e0 * 8, 8, Wr1_1, 64, hbA, 64, ECHn, one);
        rowgemm_k<64, 64, 1><<<cdiv(ECHn, 128), 256, 0, stream>>>(
            hbA, 64, Wr1_2, 64, hbB, 64, ECHn, one);
        rowgemm_k<64, 64, 1><<<cdiv(ECHn, 128), 256, 0, stream>>>(
            hbB, 64, Wr1_3, 64, hbA, 64, ECHn, one);
        k_gather1<<<NN / 4, 256, 0, stream>>>(
            rowptr, psnd, Yv, hbA, e0, e1, Wr1_o, 256, hu, A_s, A_v);
    }

    // ---- layer 1 node side (Wlin in place) ----
    rowgemm_k<128, 128, 0><<<cdiv(NN, 64), 256, 0, stream>>>(
        A_s, 128, Wlin1_s, 128, A_s, 128, NN, inv16);
    rowgemm_k<128, 128, 0><<<cdiv(3 * NN, 64), 256, 0, stream>>>(
        A_v, 128, Wlin1_v, 128, A_v, 128, 3 * NN, inv16);
    k_B1<<<cdiv(NN * CC, 256), 256, 0, stream>>>(
        species, A_s, A_v, P1_s1, P1_ss, P1_vv, P1_v1, P1_sv, hbuf /*Bs*/, A_v /*Bv*/);
    rowgemm_k<128, 128, 0><<<cdiv(NN, 64), 256, 0, stream>>>(
        hbuf, 128, Lp1_s, 128, hu /*h_s*/, 128, NN, one);
    rowgemm_k<128, 128, 0><<<cdiv(3 * NN, 64), 256, 0, stream>>>(
        A_v /*Bv*/, 128, Lp1_v, 128, h_v, 128, 3 * NN, one);
    k_dip1<<<NN, 64, 0, stream>>>(h_v, R1, dip1);
    rowgemm_k<128, 128, 0><<<cdiv(NN, 64), 256, 0, stream>>>(
        hu /*h_s*/, 128, Wup2_s, 128, hbuf /*hs*/, 128, NN, one);
    rowgemm_k<128, 128, 0><<<cdiv(3 * NN, 64), 256, 0, stream>>>(
        h_v, 128, Wup2_v, 128, hv, 128, 3 * NN, one);

    // ---- layer 2: edge MLP + merged fused gather ----
    hipMemsetAsync(A_s, 0, (size_t)NN * CC * 4, stream);
    hipMemsetAsync(A_v, 0, (size_t)NN * 3 * CC * 4, stream);
    for (int ch = 0; ch < NCH; ++ch) {
        int e0 = ch * ECHn, e1 = e0 + ECHn;
        rowgemm_k<8, 64, 1><<<cdiv(ECHn, 128), 256, 0, stream>>>(
            ef + (size_t)e0 * 8, 8, Wr2_1, 64, hbA, 64, ECHn, one);
        rowgemm_k<64, 64, 1><<<cdiv(ECHn, 128), 256, 0, stream>>>(
            hbA, 64, Wr2_2, 64, hbB, 64, ECHn, one);
        rowgemm_k<64, 64, 1><<<cdiv(ECHn, 128), 256, 0, stream>>>(
            hbB, 64, Wr2_3, 64, hbA, 64, ECHn, one);
        k_gather23<<<NN / 2, 512, 0, stream>>>(
            rowptr, psnd, Yv, hbA, e0, e1, Wr2_o, hbuf /*hs*/, hv, A_s, A_v);
    }

    // ---- layer 2 node side ----
    rowgemm_k<128, 128, 0><<<cdiv(NN, 64), 256, 0, stream>>>(
        A_s, 128, Wlin2_s, 128, A_s, 128, NN, inv16);
    rowgemm_k<128, 128, 0><<<cdiv(3 * NN, 64), 256, 0, stream>>>(
        A_v, 128, Wlin2_v, 128, A_v, 128, 3 * NN, inv16);
    k_sc<<<NN, 128, 0, stream>>>(species, h_v, Wsk, h2v);
    k_B2<<<cdiv(NN * CC, 256), 256, 0, stream>>>(species, A_s, A_v, P2_v1, P2_sv, A_v /*B2v*/);
    rowgemm_k<128, 128, 6><<<cdiv(3 * NN, 64), 256, 0, stream>>>(
        A_v /*B2v*/, 128, Lp2_v, 128, h2v, 128, 3 * NN, one);

    k_node_out<<<NN, 64, 0, stream>>>(h2v, rmix, dip1, charges, positions, out, tot);
    k_greduce<<<NGR, 256, 0, stream>>>(tot, batch, out);
}

// Round 10
// 1620.601 us; speedup vs baseline: 1.3659x; 1.2670x over previous
//
#include <hip/hip_runtime.h>

#define NN 10000
#define EE 160000
#define CC 128
#define NEL 10
#define NGR 16

static inline int cdiv(int a, int b) { return (a + b - 1) / b; }

__device__ __forceinline__ float silu_f(float x) { return x / (1.0f + __expf(-x)); }

// ---------------------------------------------------------------------------
// Generic row-GEMM: out[r][c] = sum_k in[r][k] * W[k][c]   (W row-major, w_ld)
// MODE 0: store   1: store+silu   6: out += (accumulate)
// ---------------------------------------------------------------------------
template <int K, int N, int MODE>
__global__ __launch_bounds__(256) void rowgemm_k(
    const float* __restrict__ in, int in_ld,
    const float* __restrict__ W, int w_ld,
    float* __restrict__ out, int out_ld,
    int R, float scale)
{
    constexpr int TR = 8192 / N;
    constexpr int CG = N / 8;
    constexpr int RG = 256 / CG;
    static_assert(RG * 4 == TR, "tile shape mismatch");
    constexpr int KC = (K < 64 ? K : 64);

    __shared__ float Wl[KC][N];
    __shared__ float inT[K][TR + 4];

    const int tid = threadIdx.x;
    const int cg = tid % CG, rg = tid / CG;
    const int c0 = cg * 8, r0 = rg * 4;
    const int row0 = blockIdx.x * TR;

    for (int i = tid; i < K * TR; i += 256) {
        int r = i / K, k = i - r * K;
        int row = row0 + r;
        inT[k][r] = (row < R) ? in[row * in_ld + k] : 0.0f;
    }

    float acc[4][8];
#pragma unroll
    for (int i = 0; i < 4; ++i)
#pragma unroll
        for (int j = 0; j < 8; ++j) acc[i][j] = 0.0f;

    for (int kc = 0; kc < K; kc += KC) {
        __syncthreads();
        for (int i = tid; i < KC * N; i += 256) {
            int k = i / N, c = i - k * N;
            Wl[k][c] = W[(kc + k) * w_ld + c];
        }
        __syncthreads();
#pragma unroll 8
        for (int kk = 0; kk < KC; ++kk) {
            const float4 a  = *(const float4*)&inT[kc + kk][r0];
            const float4 b0 = *(const float4*)&Wl[kk][c0];
            const float4 b1 = *(const float4*)&Wl[kk][c0 + 4];
            const float av[4] = {a.x, a.y, a.z, a.w};
            const float bv[8] = {b0.x, b0.y, b0.z, b0.w, b1.x, b1.y, b1.z, b1.w};
#pragma unroll
            for (int i = 0; i < 4; ++i)
#pragma unroll
                for (int j = 0; j < 8; ++j)
                    acc[i][j] = fmaf(av[i], bv[j], acc[i][j]);
        }
    }

#pragma unroll
    for (int i = 0; i < 4; ++i) {
        int row = row0 + r0 + i;
        if (row >= R) break;
#pragma unroll
        for (int j = 0; j < 8; ++j) {
            float v = acc[i][j] * scale;
            if constexpr (MODE == 1) v = silu_f(v);
            int idx = row * out_ld + c0 + j;
            if constexpr (MODE == 6) out[idx] += v;
            else out[idx] = v;
        }
    }
}

// ---------------------------------------------------------------------------
// CSR build
// ---------------------------------------------------------------------------
__global__ void k_count(const int* __restrict__ rcv, int* __restrict__ deg)
{
    int e = blockIdx.x * 256 + threadIdx.x;
    if (e < EE) atomicAdd(&deg[rcv[e]], 1);
}

__global__ __launch_bounds__(256) void k_scan(const int* __restrict__ deg,
                                              int* __restrict__ rowptr,
                                              int* __restrict__ cursor)
{
    __shared__ int part[256];
    const int t = threadIdx.x;
    const int PER = (NN + 255) / 256;   // 40
    int base = t * PER;
    int s = 0;
    for (int j = 0; j < PER; ++j) { int idx = base + j; if (idx < NN) s += deg[idx]; }
    part[t] = s;
    __syncthreads();
    for (int off = 1; off < 256; off <<= 1) {
        int v = (t >= off) ? part[t - off] : 0;
        __syncthreads();
        part[t] += v;
        __syncthreads();
    }
    int run = (t == 0) ? 0 : part[t - 1];
    for (int j = 0; j < PER; ++j) {
        int idx = base + j;
        if (idx < NN) { rowptr[idx] = run; cursor[idx] = run; run += deg[idx]; }
    }
    if (t == 255) rowptr[NN] = part[255];
}

__global__ void k_fill(const int* __restrict__ rcv, int* __restrict__ cursor,
                       int* __restrict__ perm)
{
    int e = blockIdx.x * 256 + threadIdx.x;
    if (e >= EE) return;
    int pos = atomicAdd(&cursor[rcv[e]], 1);
    perm[pos] = e;
}

__global__ void k_sortseg(const int* __restrict__ rowptr, int* __restrict__ perm)
{
    int n = blockIdx.x * 256 + threadIdx.x;
    if (n >= NN) return;
    int a = rowptr[n], b = rowptr[n + 1];
    for (int i = a + 1; i < b; ++i) {
        int v = perm[i];
        int j = i - 1;
        while (j >= a && perm[j] > v) { perm[j + 1] = perm[j]; --j; }
        perm[j + 1] = v;
    }
}

// geometry, written in CSR (permuted) edge order
__global__ void k_geom_perm(const float* __restrict__ pos, const float* __restrict__ shifts,
                            const int* __restrict__ snd, const int* __restrict__ rcv,
                            const int* __restrict__ perm,
                            float* __restrict__ Yv, float* __restrict__ ef,
                            int* __restrict__ psnd)
{
    int i = blockIdx.x * 256 + threadIdx.x;
    if (i >= EE) return;
    int e = perm[i];
    int s = snd[e], r = rcv[e];
    psnd[i] = s;
    float vx = pos[r * 3 + 0] - pos[s * 3 + 0] + shifts[e * 3 + 0];
    float vy = pos[r * 3 + 1] - pos[s * 3 + 1] + shifts[e * 3 + 1];
    float vz = pos[r * 3 + 2] - pos[s * 3 + 2] + shifts[e * 3 + 2];
    float len = sqrtf(vx * vx + vy * vy + vz * vz + 1e-12f);
    float inv = 1.0f / len;
    const float SQ3 = 1.7320508075688772f;
    Yv[i * 3 + 0] = SQ3 * vx * inv;
    Yv[i * 3 + 1] = SQ3 * vy * inv;
    Yv[i * 3 + 2] = SQ3 * vz * inv;
    float u = len * 0.2f;
    float fc = 0.0f;
    if (u < 1.0f) {
        float u2 = u * u, u4 = u2 * u2, u5 = u4 * u, u6 = u5 * u, u7 = u6 * u;
        fc = 1.0f - 21.0f * u5 + 35.0f * u6 - 15.0f * u7;
    }
    float pref = 0.6324555320336759f * inv * fc;
    const float PIO5 = 0.6283185307179586f;
#pragma unroll
    for (int n = 1; n <= 8; ++n)
        ef[i * 8 + n - 1] = pref * sinf((float)n * PIO5 * len);
}

// ---------------------------------------------------------------------------
// Layer-1 gather: w pre-materialized in wb[e][256] (rowgemm). Per edge:
// one coalesced wb read + random gS row with next-edge prefetch. No dot
// product in-kernel -> no register-pressure fight (round 6 structure: 0 spill).
// ---------------------------------------------------------------------------
__global__ __launch_bounds__(256) void k_gather1(
    const int* __restrict__ rowptr, const int* __restrict__ psnd,
    const float* __restrict__ Yv, const float* __restrict__ wb, int e0, int e1,
    const float* __restrict__ gS,
    float* __restrict__ outS, float* __restrict__ outV)
{
    constexpr int NPB = 4;
    const int t = threadIdx.x;
    const int c = t & 127;
    const int hi = t >> 7;
    const int n0 = blockIdx.x * NPB;

    for (int n = n0; n < n0 + NPB; ++n) {
        int rs = rowptr[n], re = rowptr[n + 1];
        if (rs < e0) rs = e0;
        if (re > e1) re = e1;
        if (rs >= re) continue;
        float accs = 0.f, a0 = 0.f, a1 = 0.f, a2 = 0.f;
        float pw = wb[(size_t)(rs - e0) * 256 + t];
        float pg = gS[psnd[rs] * 128 + c];
        for (int i = rs; i < re; ++i) {
            const float w = pw, g = pg;
            if (i + 1 < re) {
                pw = wb[(size_t)(i + 1 - e0) * 256 + t];
                pg = gS[psnd[i + 1] * 128 + c];
            }
            if (hi == 0) {
                accs = fmaf(w, g, accs);
            } else {
                float tv = w * g;
                a0 = fmaf(tv, Yv[i * 3], a0);
                a1 = fmaf(tv, Yv[i * 3 + 1], a1);
                a2 = fmaf(tv, Yv[i * 3 + 2], a2);
            }
        }
        if (hi == 0) {
            outS[n * 128 + c] += accs;
        } else {
            outV[n * 384 + c]       += a0;
            outV[n * 384 + 128 + c] += a1;
            outV[n * 384 + 256 + c] += a2;
        }
    }
}

// ---------------------------------------------------------------------------
// Layer-2 merged gather: w pre-materialized in wb[e][512]. 512 threads =
// 4 column groups (w_a,w_b,w_c,w_d); per edge one coalesced wb read +
// random hs/hv payload row with prefetch; per-node LDS cross-group reduce.
// ---------------------------------------------------------------------------
__global__ __launch_bounds__(512) void k_gather23(
    const int* __restrict__ rowptr, const int* __restrict__ psnd,
    const float* __restrict__ Yv, const float* __restrict__ wb, int e0, int e1,
    const float* __restrict__ gS, const float* __restrict__ gV,
    float* __restrict__ outS, float* __restrict__ outV)
{
    constexpr int NPB = 2;
    __shared__ float reds[256];   // grp0 -> [c], grp1 -> [128+c]
    __shared__ float redv[768];   // (p*128+c)*3+d,  p=0 grp2, p=1 grp3
    const int t = threadIdx.x;
    const int c = t & 127;
    const int g = t >> 7;        // 0:w_a 1:w_b 2:w_c 3:w_d (wave-uniform)
    const int n0 = blockIdx.x * NPB;
    const bool useS = (g == 0) || (g == 2);

    for (int n = n0; n < n0 + NPB; ++n) {
        int rs = rowptr[n], re = rowptr[n + 1];
        if (rs < e0) rs = e0;
        if (re > e1) re = e1;
        float accs = 0.f, a0 = 0.f, a1 = 0.f, a2 = 0.f;
        float pw = 0.f, p0 = 0.f, p1 = 0.f, p2 = 0.f;
        if (rs < re) {
            pw = wb[(size_t)(rs - e0) * 512 + t];
            int s = psnd[rs];
            if (useS) {
                p0 = gS[s * 128 + c];
            } else {
                p0 = gV[s * 384 + c];
                p1 = gV[s * 384 + 128 + c];
                p2 = gV[s * 384 + 256 + c];
            }
        }
        for (int i = rs; i < re; ++i) {
            const float w = pw, q0 = p0, q1 = p1, q2 = p2;
            if (i + 1 < re) {
                pw = wb[(size_t)(i + 1 - e0) * 512 + t];
                int s2 = psnd[i + 1];
                if (useS) {
                    p0 = gS[s2 * 128 + c];
                } else {
                    p0 = gV[s2 * 384 + c];
                    p1 = gV[s2 * 384 + 128 + c];
                    p2 = gV[s2 * 384 + 256 + c];
                }
            }
            const float y0 = Yv[i * 3], y1 = Yv[i * 3 + 1], y2 = Yv[i * 3 + 2];
            if (g == 0) {
                accs = fmaf(w, q0, accs);                      // w_a * hs
            } else if (g == 1) {
                float hd = q0 * y0 + q1 * y1 + q2 * y2;        // w_b * (hv.Yv)/sqrt3
                accs = fmaf(w, hd * 0.57735026919f, accs);
            } else if (g == 2) {
                float tv = w * q0;                             // w_c * hs * Yv
                a0 = fmaf(tv, y0, a0); a1 = fmaf(tv, y1, a1); a2 = fmaf(tv, y2, a2);
            } else {
                a0 = fmaf(w, q0, a0);                          // w_d * hv
                a1 = fmaf(w, q1, a1);
                a2 = fmaf(w, q2, a2);
            }
        }
        // per-node cross-group reduction (block exclusively owns node n)
        if (g < 2) {
            reds[g * 128 + c] = accs;
        } else {
            int p = g - 2;
            redv[(p * 128 + c) * 3 + 0] = a0;
            redv[(p * 128 + c) * 3 + 1] = a1;
            redv[(p * 128 + c) * 3 + 2] = a2;
        }
        __syncthreads();
        if (g == 0) {
            outS[n * 128 + c] += reds[c] + reds[128 + c];
        } else {
            int d2 = g - 1;  // 0,1,2
            outV[n * 384 + d2 * 128 + c] += redv[c * 3 + d2] + redv[(128 + c) * 3 + d2];
        }
        __syncthreads();
    }
}

// ---------------------------------------------------------------------------
__global__ void k_species(const float* __restrict__ attrs, int* __restrict__ species)
{
    int n = blockIdx.x * 256 + threadIdx.x;
    if (n >= NN) return;
    int sp = 0;
#pragma unroll
    for (int j = 0; j < NEL; ++j)
        if (attrs[n * NEL + j] > 0.5f) sp = j;
    species[n] = sp;
}

__global__ void k_embed(const float* __restrict__ W_emb, const int* __restrict__ species,
                        float* __restrict__ h)
{
    int t = blockIdx.x * 256 + threadIdx.x;
    if (t >= NN * CC) return;
    int n = t >> 7, c = t & 127;
    h[t] = W_emb[species[n] * CC + c];
}

__global__ void k_rmix(const float* __restrict__ Rmid, const float* __restrict__ Rout,
                       float* __restrict__ rmix)
{
    int c = threadIdx.x;
    float s = 0.f;
#pragma unroll
    for (int k = 0; k < 16; ++k) s = fmaf(Rmid[c * 16 + k], Rout[k], s);
    rmix[c] = s;
}

__global__ void k_B1(const int* __restrict__ species,
                     const float* __restrict__ As_l, const float* __restrict__ Av_l,
                     const float* __restrict__ P_s1, const float* __restrict__ P_ss,
                     const float* __restrict__ P_vv, const float* __restrict__ P_v1,
                     const float* __restrict__ P_sv,
                     float* __restrict__ Bs, float* __restrict__ Bv)
{
    int t = blockIdx.x * 256 + threadIdx.x;
    if (t >= NN * CC) return;
    int n = t >> 7, c = t & 127;
    int sp = species[n];
    int pb = sp * CC + c;
    int vb = n * 384 + c;
    float as = As_l[t];
    float a0 = Av_l[vb], a1 = Av_l[vb + CC], a2 = Av_l[vb + 2 * CC];
    Bs[t] = P_s1[pb] * as + P_ss[pb] * as * as
          + P_vv[pb] * (a0 * a0 + a1 * a1 + a2 * a2) * 0.57735026919f;
    float tv = P_v1[pb] + P_sv[pb] * as;
    Bv[vb] = tv * a0; Bv[vb + CC] = tv * a1; Bv[vb + 2 * CC] = tv * a2;
}

__global__ void k_B2(const int* __restrict__ species,
                     const float* __restrict__ As_l, const float* __restrict__ Av_l,
                     const float* __restrict__ P_v1, const float* __restrict__ P_sv,
                     float* __restrict__ Bv)
{
    int t = blockIdx.x * 256 + threadIdx.x;
    if (t >= NN * CC) return;
    int n = t >> 7, c = t & 127;
    int sp = species[n];
    int pb = sp * CC + c;
    int vb = n * 384 + c;
    float as = As_l[t];
    float tv = P_v1[pb] + P_sv[pb] * as;
    Bv[vb] = tv * Av_l[vb];
    Bv[vb + CC] = tv * Av_l[vb + CC];
    Bv[vb + 2 * CC] = tv * Av_l[vb + 2 * CC];
}

__global__ void k_dip1(const float* __restrict__ h_v, const float* __restrict__ R1,
                       float* __restrict__ dip1)
{
    int n = blockIdx.x, l = threadIdx.x;
    const float* hb = h_v + n * 384;
#pragma unroll
    for (int d = 0; d < 3; ++d) {
        float v = hb[d * CC + l] * R1[l] + hb[d * CC + 64 + l] * R1[64 + l];
        for (int o = 32; o > 0; o >>= 1) v += __shfl_down(v, o);
        if (l == 0) dip1[n * 3 + d] = v;
    }
}

__global__ void k_sc(const int* __restrict__ species, const float* __restrict__ h_v,
                     const float* __restrict__ Wsk, float* __restrict__ h2v)
{
    int n = blockIdx.x, f = threadIdx.x;
    int sp = species[n];
    const float* Wp = Wsk + sp * (CC * CC);
    const float* hvn = h_v + n * 384;
    float a0 = 0.f, a1 = 0.f, a2 = 0.f;
    for (int c = 0; c < CC; ++c) {
        float w = Wp[c * CC + f];
        a0 = fmaf(hvn[c], w, a0);
        a1 = fmaf(hvn[CC + c], w, a1);
        a2 = fmaf(hvn[2 * CC + c], w, a2);
    }
    h2v[n * 384 + f] = a0;
    h2v[n * 384 + CC + f] = a1;
    h2v[n * 384 + 2 * CC + f] = a2;
}

// per-node output: atomic dipole -> out[48+...], graph contribution -> tot[n][3]
__global__ void k_node_out(const float* __restrict__ h2v, const float* __restrict__ rmix,
                           const float* __restrict__ dip1,
                           const float* __restrict__ charges, const float* __restrict__ pos,
                           float* __restrict__ out, float* __restrict__ tot)
{
    int n = blockIdx.x, l = threadIdx.x;
    const float* hb = h2v + n * 384;
    float r0 = rmix[l], r1 = rmix[64 + l];
    float red[3];
#pragma unroll
    for (int d = 0; d < 3; ++d) {
        float v = hb[d * CC + l] * r0 + hb[d * CC + 64 + l] * r1;
        for (int o = 32; o > 0; o >>= 1) v += __shfl_down(v, o);
        red[d] = v;
    }
    if (l == 0) {
        float q = charges[n];
#pragma unroll
        for (int d = 0; d < 3; ++d) {
            float a = dip1[n * 3 + d] + 0.5f * red[d];
            out[48 + n * 3 + d] = a;
            tot[n * 3 + d] = a + q * pos[n * 3 + d];
        }
    }
}

// graph totals: one block per graph, no atomics
__global__ __launch_bounds__(256) void k_greduce(const float* __restrict__ tot,
                                                 const int* __restrict__ batch,
                                                 float* __restrict__ out)
{
    __shared__ float r[256 * 3];
    const int g = blockIdx.x;
    const int t = threadIdx.x;
    float s0 = 0.f, s1 = 0.f, s2 = 0.f;
    for (int n = t; n < NN; n += 256) {
        if (batch[n] == g) {
            s0 += tot[n * 3]; s1 += tot[n * 3 + 1]; s2 += tot[n * 3 + 2];
        }
    }
    r[t] = s0; r[256 + t] = s1; r[512 + t] = s2;
    __syncthreads();
    for (int off = 128; off > 0; off >>= 1) {
        if (t < off) {
            r[t] += r[t + off];
            r[256 + t] += r[256 + t + off];
            r[512 + t] += r[512 + t + off];
        }
        __syncthreads();
    }
    if (t < 3) out[g * 3 + t] = r[t * 256];
}

// ---------------------------------------------------------------------------
extern "C" void kernel_launch(void* const* d_in, const int* in_sizes, int n_in,
                              void* d_out, int out_size, void* d_ws, size_t ws_size,
                              hipStream_t stream)
{
    const float* positions = (const float*)d_in[0];
    const float* node_attrs = (const float*)d_in[1];
    const float* charges = (const float*)d_in[2];
    const float* shifts = (const float*)d_in[3];
    const int*   eidx = (const int*)d_in[4];
    const int*   batch = (const int*)d_in[5];
    const float* W_emb  = (const float*)d_in[7];
    const float* W_up1  = (const float*)d_in[8];
    const float* Wr1_1  = (const float*)d_in[9];
    const float* Wr1_2  = (const float*)d_in[10];
    const float* Wr1_3  = (const float*)d_in[11];
    const float* Wr1_o  = (const float*)d_in[12];
    const float* Wlin1_s = (const float*)d_in[13];
    const float* Wlin1_v = (const float*)d_in[14];
    const float* P1_s1 = (const float*)d_in[15];
    const float* P1_ss = (const float*)d_in[16];
    const float* P1_vv = (const float*)d_in[17];
    const float* P1_v1 = (const float*)d_in[18];
    const float* P1_sv = (const float*)d_in[19];
    const float* Lp1_s = (const float*)d_in[20];
    const float* Lp1_v = (const float*)d_in[21];
    const float* R1    = (const float*)d_in[22];
    const float* Wsk   = (const float*)d_in[23];
    const float* Wup2_s = (const float*)d_in[24];
    const float* Wup2_v = (const float*)d_in[25];
    const float* Wr2_1 = (const float*)d_in[26];
    const float* Wr2_2 = (const float*)d_in[27];
    const float* Wr2_3 = (const float*)d_in[28];
    const float* Wr2_o = (const float*)d_in[29];
    const float* Wlin2_s = (const float*)d_in[30];
    const float* Wlin2_v = (const float*)d_in[31];
    const float* P2_v1 = (const float*)d_in[32];
    const float* P2_sv = (const float*)d_in[33];
    const float* Lp2_v = (const float*)d_in[34];
    const float* Rmid  = (const float*)d_in[35];
    const float* Rout  = (const float*)d_in[36];
    (void)in_sizes; (void)n_in; (void)out_size;

    const int* snd = eidx;
    const int* rcv = eidx + EE;
    float* out = (float*)d_out;

    // chunk count: persistent ~86MB + EC*2560B chunked must fit ws_size
    const size_t pers = (size_t)92 * 1024 * 1024;  // persistent + slack
    int C = 16;
    if (pers + (size_t)(EE / 4) * 2560 <= ws_size) C = 4;
    else if (pers + (size_t)(EE / 8) * 2560 <= ws_size) C = 8;
    const int EC = EE / C;

    char* ws = (char*)d_ws;
    size_t off = 0;
    auto alloc = [&](size_t bytes) -> float* {
        float* p = (float*)(ws + off);
        off = (off + bytes + 255) & ~(size_t)255;
        return p;
    };
    int*   species = (int*)alloc((size_t)NN * 4);
    int*   deg     = (int*)alloc((size_t)NN * 4);
    int*   rowptr  = (int*)alloc((size_t)(NN + 16) * 4);
    int*   cursor  = (int*)alloc((size_t)NN * 4);
    int*   perm    = (int*)alloc((size_t)EE * 4);
    int*   psnd    = (int*)alloc((size_t)EE * 4);
    float* Yv   = alloc((size_t)EE * 3 * 4);
    float* ef   = alloc((size_t)EE * 8 * 4);
    float* A_s  = alloc((size_t)NN * CC * 4);       // A_s / As_l (in place); A2_s
    float* A_v  = alloc((size_t)NN * 3 * CC * 4);   // A_v / Av_l / Bv / A2_v / B2v
    float* hbuf = alloc((size_t)NN * CC * 4);       // h -> Bs -> hs
    float* hu   = alloc((size_t)NN * CC * 4);       // hu -> h_s
    float* h_v  = alloc((size_t)NN * 3 * CC * 4);   // layer-1 vector feats (kept for sc_v)
    float* hv   = alloc((size_t)NN * 3 * CC * 4);
    float* h2v  = alloc((size_t)NN * 3 * CC * 4);
    float* dip1 = alloc((size_t)NN * 3 * 4);
    float* rmix = alloc((size_t)CC * 4);
    float* tot  = alloc((size_t)NN * 3 * 4);
    float* hbA  = alloc((size_t)EC * 64 * 4);
    float* hbB  = alloc((size_t)EC * 64 * 4);
    float* wbuf = alloc((size_t)EC * 512 * 4);      // layer1 uses EC*256 of it

    const float inv16 = 1.0f / 16.0f;
    const float one = 1.0f;

    hipMemsetAsync(deg, 0, (size_t)NN * 4, stream);
    hipMemsetAsync(A_s, 0, (size_t)NN * CC * 4, stream);
    hipMemsetAsync(A_v, 0, (size_t)NN * 3 * CC * 4, stream);

    // ---- CSR build + permuted geometry ----
    k_count<<<cdiv(EE, 256), 256, 0, stream>>>(rcv, deg);
    k_scan<<<1, 256, 0, stream>>>(deg, rowptr, cursor);
    k_fill<<<cdiv(EE, 256), 256, 0, stream>>>(rcv, cursor, perm);
    k_sortseg<<<cdiv(NN, 256), 256, 0, stream>>>(rowptr, perm);
    k_geom_perm<<<cdiv(EE, 256), 256, 0, stream>>>(positions, shifts, snd, rcv, perm, Yv, ef, psnd);

    k_species<<<cdiv(NN, 256), 256, 0, stream>>>(node_attrs, species);
    k_embed<<<cdiv(NN * CC, 256), 256, 0, stream>>>(W_emb, species, hbuf);
    k_rmix<<<1, CC, 0, stream>>>(Rmid, Rout, rmix);

    // hu = h @ W_up1
    rowgemm_k<128, 128, 0><<<cdiv(NN, 64), 256, 0, stream>>>(
        hbuf, 128, W_up1, 128, hu, 128, NN, one);

    // ---- layer 1: edge MLP -> w materialization -> gather ----
    for (int ch = 0; ch < C; ++ch) {
        int e0 = ch * EC, e1 = e0 + EC;
        rowgemm_k<8, 64, 1><<<cdiv(EC, 128), 256, 0, stream>>>(
            ef + (size_t)e0 * 8, 8, Wr1_1, 64, hbA, 64, EC, one);
        rowgemm_k<64, 64, 1><<<cdiv(EC, 128), 256, 0, stream>>>(
            hbA, 64, Wr1_2, 64, hbB, 64, EC, one);
        rowgemm_k<64, 64, 1><<<cdiv(EC, 128), 256, 0, stream>>>(
            hbB, 64, Wr1_3, 64, hbA, 64, EC, one);
        rowgemm_k<64, 128, 0><<<cdiv(EC, 64), 256, 0, stream>>>(
            hbA, 64, Wr1_o, 256, wbuf, 256, EC, one);
        rowgemm_k<64, 128, 0><<<cdiv(EC, 64), 256, 0, stream>>>(
            hbA, 64, Wr1_o + 128, 256, wbuf + 128, 256, EC, one);
        k_gather1<<<NN / 4, 256, 0, stream>>>(
            rowptr, psnd, Yv, wbuf, e0, e1, hu, A_s, A_v);
    }

    // ---- layer 1 node side (Wlin in place) ----
    rowgemm_k<128, 128, 0><<<cdiv(NN, 64), 256, 0, stream>>>(
        A_s, 128, Wlin1_s, 128, A_s, 128, NN, inv16);
    rowgemm_k<128, 128, 0><<<cdiv(3 * NN, 64), 256, 0, stream>>>(
        A_v, 128, Wlin1_v, 128, A_v, 128, 3 * NN, inv16);
    k_B1<<<cdiv(NN * CC, 256), 256, 0, stream>>>(
        species, A_s, A_v, P1_s1, P1_ss, P1_vv, P1_v1, P1_sv, hbuf /*Bs*/, A_v /*Bv*/);
    rowgemm_k<128, 128, 0><<<cdiv(NN, 64), 256, 0, stream>>>(
        hbuf, 128, Lp1_s, 128, hu /*h_s*/, 128, NN, one);
    rowgemm_k<128, 128, 0><<<cdiv(3 * NN, 64), 256, 0, stream>>>(
        A_v /*Bv*/, 128, Lp1_v, 128, h_v, 128, 3 * NN, one);
    k_dip1<<<NN, 64, 0, stream>>>(h_v, R1, dip1);
    rowgemm_k<128, 128, 0><<<cdiv(NN, 64), 256, 0, stream>>>(
        hu /*h_s*/, 128, Wup2_s, 128, hbuf /*hs*/, 128, NN, one);
    rowgemm_k<128, 128, 0><<<cdiv(3 * NN, 64), 256, 0, stream>>>(
        h_v, 128, Wup2_v, 128, hv, 128, 3 * NN, one);

    // ---- layer 2: edge MLP -> w materialization -> merged gather ----
    hipMemsetAsync(A_s, 0, (size_t)NN * CC * 4, stream);
    hipMemsetAsync(A_v, 0, (size_t)NN * 3 * CC * 4, stream);
    for (int ch = 0; ch < C; ++ch) {
        int e0 = ch * EC, e1 = e0 + EC;
        rowgemm_k<8, 64, 1><<<cdiv(EC, 128), 256, 0, stream>>>(
            ef + (size_t)e0 * 8, 8, Wr2_1, 64, hbA, 64, EC, one);
        rowgemm_k<64, 64, 1><<<cdiv(EC, 128), 256, 0, stream>>>(
            hbA, 64, Wr2_2, 64, hbB, 64, EC, one);
        rowgemm_k<64, 64, 1><<<cdiv(EC, 128), 256, 0, stream>>>(
            hbB, 64, Wr2_3, 64, hbA, 64, EC, one);
        rowgemm_k<64, 128, 0><<<cdiv(EC, 64), 256, 0, stream>>>(
            hbA, 64, Wr2_o, 512, wbuf, 512, EC, one);
        rowgemm_k<64, 128, 0><<<cdiv(EC, 64), 256, 0, stream>>>(
            hbA, 64, Wr2_o + 128, 512, wbuf + 128, 512, EC, one);
        rowgemm_k<64, 128, 0><<<cdiv(EC, 64), 256, 0, stream>>>(
            hbA, 64, Wr2_o + 256, 512, wbuf + 256, 512, EC, one);
        rowgemm_k<64, 128, 0><<<cdiv(EC, 64), 256, 0, stream>>>(
            hbA, 64, Wr2_o + 384, 512, wbuf + 384, 512, EC, one);
        k_gather23<<<NN / 2, 512, 0, stream>>>(
            rowptr, psnd, Yv, wbuf, e0, e1, hbuf /*hs*/, hv, A_s, A_v);
    }

    // ---- layer 2 node side ----
    rowgemm_k<128, 128, 0><<<cdiv(NN, 64), 256, 0, stream>>>(
        A_s, 128, Wlin2_s, 128, A_s, 128, NN, inv16);
    rowgemm_k<128, 128, 0><<<cdiv(3 * NN, 64), 256, 0, stream>>>(
        A_v, 128, Wlin2_v, 128, A_v, 128, 3 * NN, inv16);
    k_sc<<<NN, 128, 0, stream>>>(species, h_v, Wsk, h2v);
    k_B2<<<cdiv(NN * CC, 256), 256, 0, stream>>>(species, A_s, A_v, P2_v1, P2_sv, A_v /*B2v*/);
    rowgemm_k<128, 128, 6><<<cdiv(3 * NN, 64), 256, 0, stream>>>(
        A_v /*B2v*/, 128, Lp2_v, 128, h2v, 128, 3 * NN, one);

    k_node_out<<<NN, 64, 0, stream>>>(h2v, rmix, dip1, charges, positions, out, tot);
    k_greduce<<<NGR, 256, 0, stream>>>(tot, batch, out);
}

// Round 11
// 1095.570 us; speedup vs baseline: 2.0205x; 1.4792x over previous
//
#include <hip/hip_runtime.h>

#define NN 10000
#define EE 160000
#define CC 128
#define NEL 10
#define NGR 16

static inline int cdiv(int a, int b) { return (a + b - 1) / b; }

__device__ __forceinline__ float silu_f(float x) { return x / (1.0f + __expf(-x)); }

__device__ __forceinline__ float bf2f(unsigned short u) {
    unsigned int x = ((unsigned int)u) << 16;
    return __uint_as_float(x);
}
__device__ __forceinline__ unsigned short f2bf(float f) {
    unsigned int x = __float_as_uint(f);
    unsigned int r = x + 0x7fffu + ((x >> 16) & 1u);   // round-to-nearest-even
    return (unsigned short)(r >> 16);
}

// ---------------------------------------------------------------------------
// Generic row-GEMM: out[r][cb+c] = sum_k in[r][k] * W[k][cb+c], cb=blockIdx.y*N
// MODE 0: store   1: store+silu   2: store bf16   6: out += (accumulate)
// ---------------------------------------------------------------------------
template <int K, int N, int MODE>
__global__ __launch_bounds__(256) void rowgemm_k(
    const float* __restrict__ in, int in_ld,
    const float* __restrict__ W, int w_ld,
    float* __restrict__ out, int out_ld,
    int R, float scale)
{
    constexpr int TR = 8192 / N;
    constexpr int CG = N / 8;
    constexpr int RG = 256 / CG;
    static_assert(RG * 4 == TR, "tile shape mismatch");
    constexpr int KC = (K < 64 ? K : 64);

    __shared__ float Wl[KC][N];
    __shared__ float inT[K][TR + 4];

    const int tid = threadIdx.x;
    const int cg = tid % CG, rg = tid / CG;
    const int c0 = cg * 8, r0 = rg * 4;
    const int row0 = blockIdx.x * TR;
    const int cb = blockIdx.y * N;

    for (int i = tid; i < K * TR; i += 256) {
        int r = i / K, k = i - r * K;
        int row = row0 + r;
        inT[k][r] = (row < R) ? in[row * in_ld + k] : 0.0f;
    }

    float acc[4][8];
#pragma unroll
    for (int i = 0; i < 4; ++i)
#pragma unroll
        for (int j = 0; j < 8; ++j) acc[i][j] = 0.0f;

    for (int kc = 0; kc < K; kc += KC) {
        __syncthreads();
        for (int i = tid; i < KC * N; i += 256) {
            int k = i / N, c = i - k * N;
            Wl[k][c] = W[(kc + k) * w_ld + cb + c];
        }
        __syncthreads();
#pragma unroll 8
        for (int kk = 0; kk < KC; ++kk) {
            const float4 a  = *(const float4*)&inT[kc + kk][r0];
            const float4 b0 = *(const float4*)&Wl[kk][c0];
            const float4 b1 = *(const float4*)&Wl[kk][c0 + 4];
            const float av[4] = {a.x, a.y, a.z, a.w};
            const float bv[8] = {b0.x, b0.y, b0.z, b0.w, b1.x, b1.y, b1.z, b1.w};
#pragma unroll
            for (int i = 0; i < 4; ++i)
#pragma unroll
                for (int j = 0; j < 8; ++j)
                    acc[i][j] = fmaf(av[i], bv[j], acc[i][j]);
        }
    }

#pragma unroll
    for (int i = 0; i < 4; ++i) {
        int row = row0 + r0 + i;
        if (row >= R) break;
#pragma unroll
        for (int j = 0; j < 8; ++j) {
            float v = acc[i][j] * scale;
            if constexpr (MODE == 1) v = silu_f(v);
            int idx = row * out_ld + cb + c0 + j;
            if constexpr (MODE == 6)      out[idx] += v;
            else if constexpr (MODE == 2) ((unsigned short*)out)[idx] = f2bf(v);
            else                          out[idx] = v;
        }
    }
}

// ---------------------------------------------------------------------------
// CSR build
// ---------------------------------------------------------------------------
__global__ void k_count(const int* __restrict__ rcv, int* __restrict__ deg)
{
    int e = blockIdx.x * 256 + threadIdx.x;
    if (e < EE) atomicAdd(&deg[rcv[e]], 1);
}

__global__ __launch_bounds__(256) void k_scan(const int* __restrict__ deg,
                                              int* __restrict__ rowptr,
                                              int* __restrict__ cursor)
{
    __shared__ int part[256];
    const int t = threadIdx.x;
    const int PER = (NN + 255) / 256;   // 40
    int base = t * PER;
    int s = 0;
    for (int j = 0; j < PER; ++j) { int idx = base + j; if (idx < NN) s += deg[idx]; }
    part[t] = s;
    __syncthreads();
    for (int off = 1; off < 256; off <<= 1) {
        int v = (t >= off) ? part[t - off] : 0;
        __syncthreads();
        part[t] += v;
        __syncthreads();
    }
    int run = (t == 0) ? 0 : part[t - 1];
    for (int j = 0; j < PER; ++j) {
        int idx = base + j;
        if (idx < NN) { rowptr[idx] = run; cursor[idx] = run; run += deg[idx]; }
    }
    if (t == 255) rowptr[NN] = part[255];
}

__global__ void k_fill(const int* __restrict__ rcv, int* __restrict__ cursor,
                       int* __restrict__ perm)
{
    int e = blockIdx.x * 256 + threadIdx.x;
    if (e >= EE) return;
    int pos = atomicAdd(&cursor[rcv[e]], 1);
    perm[pos] = e;
}

// one wave per node: rank-sort (deterministic order restoration, parallel)
__global__ __launch_bounds__(256) void k_sortwave(const int* __restrict__ rowptr,
                                                  int* __restrict__ perm)
{
    int gid = blockIdx.x * 256 + threadIdx.x;
    int wid = gid >> 6;          // node
    int lane = gid & 63;
    if (wid >= NN) return;
    int a = rowptr[wid], b = rowptr[wid + 1];
    int d = b - a;
    if (d <= 1) return;
    if (d <= 64) {
        int v = (lane < d) ? perm[a + lane] : 0x7fffffff;
        int rank = 0;
        for (int j = 0; j < 64; ++j) {
            int vj = __shfl(v, j);
            if (j < d && vj < v) ++rank;
        }
        if (lane < d) perm[a + rank] = v;
    } else if (lane == 0) {      // rare fallback
        for (int i = a + 1; i < b; ++i) {
            int v = perm[i]; int j = i - 1;
            while (j >= a && perm[j] > v) { perm[j + 1] = perm[j]; --j; }
            perm[j + 1] = v;
        }
    }
}

// geometry, written in CSR (permuted) edge order
__global__ void k_geom_perm(const float* __restrict__ pos, const float* __restrict__ shifts,
                            const int* __restrict__ snd, const int* __restrict__ rcv,
                            const int* __restrict__ perm,
                            float* __restrict__ Yv, float* __restrict__ ef,
                            int* __restrict__ psnd)
{
    int i = blockIdx.x * 256 + threadIdx.x;
    if (i >= EE) return;
    int e = perm[i];
    int s = snd[e], r = rcv[e];
    psnd[i] = s;
    float vx = pos[r * 3 + 0] - pos[s * 3 + 0] + shifts[e * 3 + 0];
    float vy = pos[r * 3 + 1] - pos[s * 3 + 1] + shifts[e * 3 + 1];
    float vz = pos[r * 3 + 2] - pos[s * 3 + 2] + shifts[e * 3 + 2];
    float len = sqrtf(vx * vx + vy * vy + vz * vz + 1e-12f);
    float inv = 1.0f / len;
    const float SQ3 = 1.7320508075688772f;
    Yv[i * 3 + 0] = SQ3 * vx * inv;
    Yv[i * 3 + 1] = SQ3 * vy * inv;
    Yv[i * 3 + 2] = SQ3 * vz * inv;
    float u = len * 0.2f;
    float fc = 0.0f;
    if (u < 1.0f) {
        float u2 = u * u, u4 = u2 * u2, u5 = u4 * u, u6 = u5 * u, u7 = u6 * u;
        fc = 1.0f - 21.0f * u5 + 35.0f * u6 - 15.0f * u7;
    }
    float pref = 0.6324555320336759f * inv * fc;
    const float PIO5 = 0.6283185307179586f;
#pragma unroll
    for (int n = 1; n <= 8; ++n)
        ef[i * 8 + n - 1] = pref * sinf((float)n * PIO5 * len);
}

// ---------------------------------------------------------------------------
// Layer-1 gather: w pre-materialized as bf16 in wb[e][256]. 128 threads/node,
// 2 nodes/block (5000 blocks). Per edge: 2 coalesced bf16 w + 1 random hu.
// ---------------------------------------------------------------------------
__global__ __launch_bounds__(256) void k_gather1(
    const int* __restrict__ rowptr, const int* __restrict__ psnd,
    const float* __restrict__ Yv, const unsigned short* __restrict__ wb,
    int e0, int e1,
    const float* __restrict__ gS,
    float* __restrict__ outS, float* __restrict__ outV)
{
    const int t = threadIdx.x;
    const int c = t & 127;
    const int n = blockIdx.x * 2 + (t >> 7);
    if (n >= NN) return;
    int rs = rowptr[n], re = rowptr[n + 1];
    if (rs < e0) rs = e0;
    if (re > e1) re = e1;
    if (rs >= re) return;
    float accs = 0.f, a0 = 0.f, a1 = 0.f, a2 = 0.f;
    for (int i = rs; i < re; ++i) {
        const unsigned short* wp = wb + (size_t)(i - e0) * 256;
        float wss = bf2f(wp[c]);
        float wsv = bf2f(wp[128 + c]);
        float h = gS[psnd[i] * 128 + c];
        float y0 = Yv[i * 3], y1 = Yv[i * 3 + 1], y2 = Yv[i * 3 + 2];
        accs = fmaf(wss, h, accs);
        float tv = wsv * h;
        a0 = fmaf(tv, y0, a0); a1 = fmaf(tv, y1, a1); a2 = fmaf(tv, y2, a2);
    }
    outS[n * 128 + c] += accs;
    outV[n * 384 + c]       += a0;
    outV[n * 384 + 128 + c] += a1;
    outV[n * 384 + 256 + c] += a2;
}

// ---------------------------------------------------------------------------
// Layer-2 merged gather: wb[e][512] bf16 (w_a,w_b,w_c,w_d). One thread handles
// all 4 groups for its column -> hs/hv payload read ONCE per edge, no LDS.
// ---------------------------------------------------------------------------
__global__ __launch_bounds__(256) void k_gather23(
    const int* __restrict__ rowptr, const int* __restrict__ psnd,
    const float* __restrict__ Yv, const unsigned short* __restrict__ wb,
    int e0, int e1,
    const float* __restrict__ gS, const float* __restrict__ gV,
    float* __restrict__ outS, float* __restrict__ outV)
{
    const int t = threadIdx.x;
    const int c = t & 127;
    const int n = blockIdx.x * 2 + (t >> 7);
    if (n >= NN) return;
    int rs = rowptr[n], re = rowptr[n + 1];
    if (rs < e0) rs = e0;
    if (re > e1) re = e1;
    if (rs >= re) return;
    float accs = 0.f, a0 = 0.f, a1 = 0.f, a2 = 0.f;
    for (int i = rs; i < re; ++i) {
        const unsigned short* wp = wb + (size_t)(i - e0) * 512;
        float wa = bf2f(wp[c]);
        float wbv = bf2f(wp[128 + c]);
        float wc = bf2f(wp[256 + c]);
        float wd = bf2f(wp[384 + c]);
        int s = psnd[i];
        float hs = gS[s * 128 + c];
        float v0 = gV[s * 384 + c];
        float v1 = gV[s * 384 + 128 + c];
        float v2 = gV[s * 384 + 256 + c];
        float y0 = Yv[i * 3], y1 = Yv[i * 3 + 1], y2 = Yv[i * 3 + 2];
        float hd = v0 * y0 + v1 * y1 + v2 * y2;
        accs = fmaf(wa, hs, accs);
        accs = fmaf(wbv, hd * 0.57735026919f, accs);
        float tv = wc * hs;
        a0 = fmaf(tv, y0, a0); a0 = fmaf(wd, v0, a0);
        a1 = fmaf(tv, y1, a1); a1 = fmaf(wd, v1, a1);
        a2 = fmaf(tv, y2, a2); a2 = fmaf(wd, v2, a2);
    }
    outS[n * 128 + c] += accs;
    outV[n * 384 + c]       += a0;
    outV[n * 384 + 128 + c] += a1;
    outV[n * 384 + 256 + c] += a2;
}

// ---------------------------------------------------------------------------
__global__ void k_species(const float* __restrict__ attrs, int* __restrict__ species)
{
    int n = blockIdx.x * 256 + threadIdx.x;
    if (n >= NN) return;
    int sp = 0;
#pragma unroll
    for (int j = 0; j < NEL; ++j)
        if (attrs[n * NEL + j] > 0.5f) sp = j;
    species[n] = sp;
}

__global__ void k_embed(const float* __restrict__ W_emb, const int* __restrict__ species,
                        float* __restrict__ h)
{
    int t = blockIdx.x * 256 + threadIdx.x;
    if (t >= NN * CC) return;
    int n = t >> 7, c = t & 127;
    h[t] = W_emb[species[n] * CC + c];
}

__global__ void k_rmix(const float* __restrict__ Rmid, const float* __restrict__ Rout,
                       float* __restrict__ rmix)
{
    int c = threadIdx.x;
    float s = 0.f;
#pragma unroll
    for (int k = 0; k < 16; ++k) s = fmaf(Rmid[c * 16 + k], Rout[k], s);
    rmix[c] = s;
}

__global__ void k_B1(const int* __restrict__ species,
                     const float* __restrict__ As_l, const float* __restrict__ Av_l,
                     const float* __restrict__ P_s1, const float* __restrict__ P_ss,
                     const float* __restrict__ P_vv, const float* __restrict__ P_v1,
                     const float* __restrict__ P_sv,
                     float* __restrict__ Bs, float* __restrict__ Bv)
{
    int t = blockIdx.x * 256 + threadIdx.x;
    if (t >= NN * CC) return;
    int n = t >> 7, c = t & 127;
    int sp = species[n];
    int pb = sp * CC + c;
    int vb = n * 384 + c;
    float as = As_l[t];
    float a0 = Av_l[vb], a1 = Av_l[vb + CC], a2 = Av_l[vb + 2 * CC];
    Bs[t] = P_s1[pb] * as + P_ss[pb] * as * as
          + P_vv[pb] * (a0 * a0 + a1 * a1 + a2 * a2) * 0.57735026919f;
    float tv = P_v1[pb] + P_sv[pb] * as;
    Bv[vb] = tv * a0; Bv[vb + CC] = tv * a1; Bv[vb + 2 * CC] = tv * a2;
}

__global__ void k_B2(const int* __restrict__ species,
                     const float* __restrict__ As_l, const float* __restrict__ Av_l,
                     const float* __restrict__ P_v1, const float* __restrict__ P_sv,
                     float* __restrict__ Bv)
{
    int t = blockIdx.x * 256 + threadIdx.x;
    if (t >= NN * CC) return;
    int n = t >> 7, c = t & 127;
    int sp = species[n];
    int pb = sp * CC + c;
    int vb = n * 384 + c;
    float as = As_l[t];
    float tv = P_v1[pb] + P_sv[pb] * as;
    Bv[vb] = tv * Av_l[vb];
    Bv[vb + CC] = tv * Av_l[vb + CC];
    Bv[vb + 2 * CC] = tv * Av_l[vb + 2 * CC];
}

__global__ void k_dip1(const float* __restrict__ h_v, const float* __restrict__ R1,
                       float* __restrict__ dip1)
{
    int n = blockIdx.x, l = threadIdx.x;
    const float* hb = h_v + n * 384;
#pragma unroll
    for (int d = 0; d < 3; ++d) {
        float v = hb[d * CC + l] * R1[l] + hb[d * CC + 64 + l] * R1[64 + l];
        for (int o = 32; o > 0; o >>= 1) v += __shfl_down(v, o);
        if (l == 0) dip1[n * 3 + d] = v;
    }
}

__global__ void k_sc(const int* __restrict__ species, const float* __restrict__ h_v,
                     const float* __restrict__ Wsk, float* __restrict__ h2v)
{
    int n = blockIdx.x, f = threadIdx.x;
    int sp = species[n];
    const float* Wp = Wsk + sp * (CC * CC);
    const float* hvn = h_v + n * 384;
    float a0 = 0.f, a1 = 0.f, a2 = 0.f;
    for (int c = 0; c < CC; ++c) {
        float w = Wp[c * CC + f];
        a0 = fmaf(hvn[c], w, a0);
        a1 = fmaf(hvn[CC + c], w, a1);
        a2 = fmaf(hvn[2 * CC + c], w, a2);
    }
    h2v[n * 384 + f] = a0;
    h2v[n * 384 + CC + f] = a1;
    h2v[n * 384 + 2 * CC + f] = a2;
}

// per-node output: atomic dipole -> out[48+...], graph contribution -> tot[n][3]
__global__ void k_node_out(const float* __restrict__ h2v, const float* __restrict__ rmix,
                           const float* __restrict__ dip1,
                           const float* __restrict__ charges, const float* __restrict__ pos,
                           float* __restrict__ out, float* __restrict__ tot)
{
    int n = blockIdx.x, l = threadIdx.x;
    const float* hb = h2v + n * 384;
    float r0 = rmix[l], r1 = rmix[64 + l];
    float red[3];
#pragma unroll
    for (int d = 0; d < 3; ++d) {
        float v = hb[d * CC + l] * r0 + hb[d * CC + 64 + l] * r1;
        for (int o = 32; o > 0; o >>= 1) v += __shfl_down(v, o);
        red[d] = v;
    }
    if (l == 0) {
        float q = charges[n];
#pragma unroll
        for (int d = 0; d < 3; ++d) {
            float a = dip1[n * 3 + d] + 0.5f * red[d];
            out[48 + n * 3 + d] = a;
            tot[n * 3 + d] = a + q * pos[n * 3 + d];
        }
    }
}

// graph totals: one block per graph, no atomics
__global__ __launch_bounds__(256) void k_greduce(const float* __restrict__ tot,
                                                 const int* __restrict__ batch,
                                                 float* __restrict__ out)
{
    __shared__ float r[256 * 3];
    const int g = blockIdx.x;
    const int t = threadIdx.x;
    float s0 = 0.f, s1 = 0.f, s2 = 0.f;
    for (int n = t; n < NN; n += 256) {
        if (batch[n] == g) {
            s0 += tot[n * 3]; s1 += tot[n * 3 + 1]; s2 += tot[n * 3 + 2];
        }
    }
    r[t] = s0; r[256 + t] = s1; r[512 + t] = s2;
    __syncthreads();
    for (int off = 128; off > 0; off >>= 1) {
        if (t < off) {
            r[t] += r[t + off];
            r[256 + t] += r[256 + t + off];
            r[512 + t] += r[512 + t + off];
        }
        __syncthreads();
    }
    if (t < 3) out[g * 3 + t] = r[t * 256];
}

// ---------------------------------------------------------------------------
extern "C" void kernel_launch(void* const* d_in, const int* in_sizes, int n_in,
                              void* d_out, int out_size, void* d_ws, size_t ws_size,
                              hipStream_t stream)
{
    const float* positions = (const float*)d_in[0];
    const float* node_attrs = (const float*)d_in[1];
    const float* charges = (const float*)d_in[2];
    const float* shifts = (const float*)d_in[3];
    const int*   eidx = (const int*)d_in[4];
    const int*   batch = (const int*)d_in[5];
    const float* W_emb  = (const float*)d_in[7];
    const float* W_up1  = (const float*)d_in[8];
    const float* Wr1_1  = (const float*)d_in[9];
    const float* Wr1_2  = (const float*)d_in[10];
    const float* Wr1_3  = (const float*)d_in[11];
    const float* Wr1_o  = (const float*)d_in[12];
    const float* Wlin1_s = (const float*)d_in[13];
    const float* Wlin1_v = (const float*)d_in[14];
    const float* P1_s1 = (const float*)d_in[15];
    const float* P1_ss = (const float*)d_in[16];
    const float* P1_vv = (const float*)d_in[17];
    const float* P1_v1 = (const float*)d_in[18];
    const float* P1_sv = (const float*)d_in[19];
    const float* Lp1_s = (const float*)d_in[20];
    const float* Lp1_v = (const float*)d_in[21];
    const float* R1    = (const float*)d_in[22];
    const float* Wsk   = (const float*)d_in[23];
    const float* Wup2_s = (const float*)d_in[24];
    const float* Wup2_v = (const float*)d_in[25];
    const float* Wr2_1 = (const float*)d_in[26];
    const float* Wr2_2 = (const float*)d_in[27];
    const float* Wr2_3 = (const float*)d_in[28];
    const float* Wr2_o = (const float*)d_in[29];
    const float* Wlin2_s = (const float*)d_in[30];
    const float* Wlin2_v = (const float*)d_in[31];
    const float* P2_v1 = (const float*)d_in[32];
    const float* P2_sv = (const float*)d_in[33];
    const float* Lp2_v = (const float*)d_in[34];
    const float* Rmid  = (const float*)d_in[35];
    const float* Rout  = (const float*)d_in[36];
    (void)in_sizes; (void)n_in; (void)out_size;

    const int* snd = eidx;
    const int* rcv = eidx + EE;
    float* out = (float*)d_out;

    char* ws = (char*)d_ws;
    size_t off = 0;
    auto alloc = [&](size_t bytes) -> float* {
        float* p = (float*)(ws + off);
        off = (off + bytes + 255) & ~(size_t)255;
        return p;
    };
    int*   species = (int*)alloc((size_t)NN * 4);
    int*   deg     = (int*)alloc((size_t)NN * 4);
    int*   rowptr  = (int*)alloc((size_t)(NN + 16) * 4);
    int*   cursor  = (int*)alloc((size_t)NN * 4);
    int*   perm    = (int*)alloc((size_t)EE * 4);
    int*   psnd    = (int*)alloc((size_t)EE * 4);
    float* Yv   = alloc((size_t)EE * 3 * 4);
    float* ef   = alloc((size_t)EE * 8 * 4);
    float* A_s  = alloc((size_t)NN * CC * 4);
    float* A_v  = alloc((size_t)NN * 3 * CC * 4);
    float* hbuf = alloc((size_t)NN * CC * 4);       // h -> Bs -> hs
    float* hu   = alloc((size_t)NN * CC * 4);       // hu -> h_s
    float* h_v  = alloc((size_t)NN * 3 * CC * 4);
    float* hv   = alloc((size_t)NN * 3 * CC * 4);
    float* h2v  = alloc((size_t)NN * 3 * CC * 4);
    float* dip1 = alloc((size_t)NN * 3 * 4);
    float* rmix = alloc((size_t)CC * 4);
    float* tot  = alloc((size_t)NN * 3 * 4);

    // full-MLP mode if hbA+hbB (2 x 41MB) fit; wbuf (bf16) aliases hbB.
    const size_t hbFull = (size_t)EE * 64 * 4;
    const bool full = (off + 2 * hbFull + 8192) <= ws_size;
    int C, EC;
    float *hbA, *hbB;
    unsigned short* wbuf;
    if (full) {
        C = 4; EC = EE / C;
        hbA = alloc(hbFull);
        hbB = alloc(hbFull);
        wbuf = (unsigned short*)hbB;                // EC*512*2 == hbFull exactly
    } else {
        C = 8; EC = EE / C;
        hbA = alloc((size_t)EC * 64 * 4);
        hbB = alloc((size_t)EC * 64 * 4);
        wbuf = (unsigned short*)alloc((size_t)EC * 512 * 2);
    }

    const float inv16 = 1.0f / 16.0f;
    const float one = 1.0f;

    hipMemsetAsync(deg, 0, (size_t)NN * 4, stream);
    hipMemsetAsync(A_s, 0, (size_t)NN * CC * 4, stream);
    hipMemsetAsync(A_v, 0, (size_t)NN * 3 * CC * 4, stream);

    // ---- CSR build + permuted geometry ----
    k_count<<<cdiv(EE, 256), 256, 0, stream>>>(rcv, deg);
    k_scan<<<1, 256, 0, stream>>>(deg, rowptr, cursor);
    k_fill<<<cdiv(EE, 256), 256, 0, stream>>>(rcv, cursor, perm);
    k_sortwave<<<cdiv(NN * 64, 256), 256, 0, stream>>>(rowptr, perm);
    k_geom_perm<<<cdiv(EE, 256), 256, 0, stream>>>(positions, shifts, snd, rcv, perm, Yv, ef, psnd);

    k_species<<<cdiv(NN, 256), 256, 0, stream>>>(node_attrs, species);
    k_embed<<<cdiv(NN * CC, 256), 256, 0, stream>>>(W_emb, species, hbuf);
    k_rmix<<<1, CC, 0, stream>>>(Rmid, Rout, rmix);

    // hu = h @ W_up1
    rowgemm_k<128, 128, 0><<<cdiv(NN, 64), 256, 0, stream>>>(
        hbuf, 128, W_up1, 128, hu, 128, NN, one);

    // ---- layer 1: edge MLP -> bf16 w materialization -> gather ----
    if (full) {
        rowgemm_k<8, 64, 1><<<cdiv(EE, 128), 256, 0, stream>>>(
            ef, 8, Wr1_1, 64, hbA, 64, EE, one);
        rowgemm_k<64, 64, 1><<<cdiv(EE, 128), 256, 0, stream>>>(
            hbA, 64, Wr1_2, 64, hbB, 64, EE, one);
        rowgemm_k<64, 64, 1><<<cdiv(EE, 128), 256, 0, stream>>>(
            hbB, 64, Wr1_3, 64, hbA, 64, EE, one);
    }
    for (int ch = 0; ch < C; ++ch) {
        int e0 = ch * EC, e1 = e0 + EC;
        const float* hin;
        if (full) {
            hin = hbA + (size_t)e0 * 64;
        } else {
            rowgemm_k<8, 64, 1><<<cdiv(EC, 128), 256, 0, stream>>>(
                ef + (size_t)e0 * 8, 8, Wr1_1, 64, hbA, 64, EC, one);
            rowgemm_k<64, 64, 1><<<cdiv(EC, 128), 256, 0, stream>>>(
                hbA, 64, Wr1_2, 64, hbB, 64, EC, one);
            rowgemm_k<64, 64, 1><<<cdiv(EC, 128), 256, 0, stream>>>(
                hbB, 64, Wr1_3, 64, hbA, 64, EC, one);
            hin = hbA;
        }
        rowgemm_k<64, 128, 2><<<dim3(cdiv(EC, 64), 2), 256, 0, stream>>>(
            hin, 64, Wr1_o, 256, (float*)wbuf, 256, EC, one);
        k_gather1<<<NN / 2, 256, 0, stream>>>(
            rowptr, psnd, Yv, wbuf, e0, e1, hu, A_s, A_v);
    }

    // ---- layer 1 node side (Wlin in place) ----
    rowgemm_k<128, 128, 0><<<cdiv(NN, 64), 256, 0, stream>>>(
        A_s, 128, Wlin1_s, 128, A_s, 128, NN, inv16);
    rowgemm_k<128, 128, 0><<<cdiv(3 * NN, 64), 256, 0, stream>>>(
        A_v, 128, Wlin1_v, 128, A_v, 128, 3 * NN, inv16);
    k_B1<<<cdiv(NN * CC, 256), 256, 0, stream>>>(
        species, A_s, A_v, P1_s1, P1_ss, P1_vv, P1_v1, P1_sv, hbuf /*Bs*/, A_v /*Bv*/);
    rowgemm_k<128, 128, 0><<<cdiv(NN, 64), 256, 0, stream>>>(
        hbuf, 128, Lp1_s, 128, hu /*h_s*/, 128, NN, one);
    rowgemm_k<128, 128, 0><<<cdiv(3 * NN, 64), 256, 0, stream>>>(
        A_v /*Bv*/, 128, Lp1_v, 128, h_v, 128, 3 * NN, one);
    k_dip1<<<NN, 64, 0, stream>>>(h_v, R1, dip1);
    rowgemm_k<128, 128, 0><<<cdiv(NN, 64), 256, 0, stream>>>(
        hu /*h_s*/, 128, Wup2_s, 128, hbuf /*hs*/, 128, NN, one);
    rowgemm_k<128, 128, 0><<<cdiv(3 * NN, 64), 256, 0, stream>>>(
        h_v, 128, Wup2_v, 128, hv, 128, 3 * NN, one);

    // ---- layer 2: edge MLP -> bf16 w materialization -> merged gather ----
    hipMemsetAsync(A_s, 0, (size_t)NN * CC * 4, stream);
    hipMemsetAsync(A_v, 0, (size_t)NN * 3 * CC * 4, stream);
    if (full) {
        rowgemm_k<8, 64, 1><<<cdiv(EE, 128), 256, 0, stream>>>(
            ef, 8, Wr2_1, 64, hbA, 64, EE, one);
        rowgemm_k<64, 64, 1><<<cdiv(EE, 128), 256, 0, stream>>>(
            hbA, 64, Wr2_2, 64, hbB, 64, EE, one);
        rowgemm_k<64, 64, 1><<<cdiv(EE, 128), 256, 0, stream>>>(
            hbB, 64, Wr2_3, 64, hbA, 64, EE, one);
    }
    for (int ch = 0; ch < C; ++ch) {
        int e0 = ch * EC, e1 = e0 + EC;
        const float* hin;
        if (full) {
            hin = hbA + (size_t)e0 * 64;
        } else {
            rowgemm_k<8, 64, 1><<<cdiv(EC, 128), 256, 0, stream>>>(
                ef + (size_t)e0 * 8, 8, Wr2_1, 64, hbA, 64, EC, one);
            rowgemm_k<64, 64, 1><<<cdiv(EC, 128), 256, 0, stream>>>(
                hbA, 64, Wr2_2, 64, hbB, 64, EC, one);
            rowgemm_k<64, 64, 1><<<cdiv(EC, 128), 256, 0, stream>>>(
                hbB, 64, Wr2_3, 64, hbA, 64, EC, one);
            hin = hbA;
        }
        rowgemm_k<64, 128, 2><<<dim3(cdiv(EC, 64), 4), 256, 0, stream>>>(
            hin, 64, Wr2_o, 512, (float*)wbuf, 512, EC, one);
        k_gather23<<<NN / 2, 256, 0, stream>>>(
            rowptr, psnd, Yv, wbuf, e0, e1, hbuf /*hs*/, hv, A_s, A_v);
    }

    // ---- layer 2 node side ----
    rowgemm_k<128, 128, 0><<<cdiv(NN, 64), 256, 0, stream>>>(
        A_s, 128, Wlin2_s, 128, A_s, 128, NN, inv16);
    rowgemm_k<128, 128, 0><<<cdiv(3 * NN, 64), 256, 0, stream>>>(
        A_v, 128, Wlin2_v, 128, A_v, 128, 3 * NN, inv16);
    k_sc<<<NN, 128, 0, stream>>>(species, h_v, Wsk, h2v);
    k_B2<<<cdiv(NN * CC, 256), 256, 0, stream>>>(species, A_s, A_v, P2_v1, P2_sv, A_v /*B2v*/);
    rowgemm_k<128, 128, 6><<<cdiv(3 * NN, 64), 256, 0, stream>>>(
        A_v /*B2v*/, 128, Lp2_v, 128, h2v, 128, 3 * NN, one);

    k_node_out<<<NN, 64, 0, stream>>>(h2v, rmix, dip1, charges, positions, out, tot);
    k_greduce<<<NGR, 256, 0, stream>>>(tot, batch, out);
}

// Round 12
// 774.337 us; speedup vs baseline: 2.8587x; 1.4148x over previous
//
#include <hip/hip_runtime.h>

#define NN 10000
#define EE 160000
#define CC 128
#define NEL 10
#define NGR 16

static inline int cdiv(int a, int b) { return (a + b - 1) / b; }

__device__ __forceinline__ float silu_f(float x) { return x / (1.0f + __expf(-x)); }

__device__ __forceinline__ float bf2f(unsigned short u) {
    unsigned int x = ((unsigned int)u) << 16;
    return __uint_as_float(x);
}
__device__ __forceinline__ unsigned short f2bf(float f) {
    unsigned int x = __float_as_uint(f);
    unsigned int r = x + 0x7fffu + ((x >> 16) & 1u);
    return (unsigned short)(r >> 16);
}

typedef __attribute__((ext_vector_type(8))) short bf16x8;
typedef __attribute__((ext_vector_type(4))) float f32x4;

// ---------------------------------------------------------------------------
// MFMA GEMM (bf16 in, bf16 out): out[r][cb+n] = act(sum_k in[r][k]*W[k][cb+n])
// Wt is pre-transposed bf16 [Ntot][K]. MODE 1: silu, MODE 2: plain.
// 64-row tile, 4 waves; A/Wt staged in LDS with XOR swizzle (row&7)<<4.
// Fragment layout (guide m89, 16x16x32_bf16): A row=lane&15, k=(lane>>4)*8+e;
// B col=lane&15, same k; D col=lane&15, row=(lane>>4)*4+reg.
// ---------------------------------------------------------------------------
template <int K, int N, int MODE>
__global__ __launch_bounds__(256) void mfma_gemm(
    const unsigned short* __restrict__ in, int in_ld,
    const unsigned short* __restrict__ Wt,
    unsigned short* __restrict__ out, int out_ld,
    int R)
{
    constexpr int NT = N / 16;
    constexpr int KC = K / 32;
    constexpr int CPR = K / 8;           // 16B chunks per row
    __shared__ __align__(16) unsigned short Ash[64 * K];
    __shared__ __align__(16) unsigned short Bsh[N * K];

    const int tid = threadIdx.x;
    const int w = tid >> 6;
    const int l = tid & 63;
    const int row0 = blockIdx.x * 64;
    const int cb = blockIdx.y * N;

    for (int cid = tid; cid < 64 * CPR; cid += 256) {
        int r = cid / CPR, k8 = cid % CPR;
        int row = row0 + r;
        uint4 val = make_uint4(0u, 0u, 0u, 0u);
        if (row < R) val = *(const uint4*)(in + (size_t)row * in_ld + k8 * 8);
        unsigned bo = ((unsigned)(r * K + k8 * 8) * 2u) ^ (((unsigned)(r & 7)) << 4);
        *(uint4*)((char*)Ash + bo) = val;
    }
    for (int cid = tid; cid < N * CPR; cid += 256) {
        int nn = cid / CPR, k8 = cid % CPR;
        uint4 val = *(const uint4*)(Wt + (size_t)(cb + nn) * K + k8 * 8);
        unsigned bo = ((unsigned)(nn * K + k8 * 8) * 2u) ^ (((unsigned)(nn & 7)) << 4);
        *(uint4*)((char*)Bsh + bo) = val;
    }
    __syncthreads();

    // A fragments (per k-chunk), row = w*16 + (l&15)
    bf16x8 afr[KC];
#pragma unroll
    for (int kc = 0; kc < KC; ++kc) {
        int r = w * 16 + (l & 15);
        int k = kc * 32 + (l >> 4) * 8;
        unsigned bo = ((unsigned)(r * K + k) * 2u) ^ (((unsigned)(r & 7)) << 4);
        afr[kc] = *(const bf16x8*)((char*)Ash + bo);
    }

    f32x4 acc[NT];
#pragma unroll
    for (int nt = 0; nt < NT; ++nt) {
        acc[nt] = (f32x4){0.f, 0.f, 0.f, 0.f};
#pragma unroll
        for (int kc = 0; kc < KC; ++kc) {
            int col = nt * 16 + (l & 15);
            int k = kc * 32 + (l >> 4) * 8;
            unsigned bo = ((unsigned)(col * K + k) * 2u) ^ (((unsigned)(col & 7)) << 4);
            bf16x8 bfr = *(const bf16x8*)((char*)Bsh + bo);
            acc[nt] = __builtin_amdgcn_mfma_f32_16x16x32_bf16(afr[kc], bfr, acc[nt], 0, 0, 0);
        }
    }

#pragma unroll
    for (int nt = 0; nt < NT; ++nt) {
#pragma unroll
        for (int rg = 0; rg < 4; ++rg) {
            int row = row0 + w * 16 + (l >> 4) * 4 + rg;
            if (row < R) {
                int col = cb + nt * 16 + (l & 15);
                float v = acc[nt][rg];
                if constexpr (MODE == 1) v = silu_f(v);
                out[(size_t)row * out_ld + col] = f2bf(v);
            }
        }
    }
}

// weight prep: dst[n][k] (bf16, [N][Kpad]) = src[k][n] (f32, [K][N]), zero-pad k>=K
__global__ void k_wprep(const float* __restrict__ src, unsigned short* __restrict__ dst,
                        int K, int N, int Kpad)
{
    int i = blockIdx.x * 256 + threadIdx.x;
    if (i >= N * Kpad) return;
    int n = i / Kpad, k = i % Kpad;
    dst[i] = (k < K) ? f2bf(src[k * N + n]) : (unsigned short)0;
}

// ---------------------------------------------------------------------------
// fp32 row-GEMM (node-side): MODE 0 store, 6 accumulate
// ---------------------------------------------------------------------------
template <int K, int N, int MODE>
__global__ __launch_bounds__(256) void rowgemm_k(
    const float* __restrict__ in, int in_ld,
    const float* __restrict__ W, int w_ld,
    float* __restrict__ out, int out_ld,
    int R, float scale)
{
    constexpr int TR = 8192 / N;
    constexpr int CG = N / 8;
    constexpr int RG = 256 / CG;
    static_assert(RG * 4 == TR, "tile shape mismatch");
    constexpr int KC = (K < 64 ? K : 64);

    __shared__ float Wl[KC][N];
    __shared__ float inT[K][TR + 4];

    const int tid = threadIdx.x;
    const int cg = tid % CG, rg = tid / CG;
    const int c0 = cg * 8, r0 = rg * 4;
    const int row0 = blockIdx.x * TR;

    for (int i = tid; i < K * TR; i += 256) {
        int r = i / K, k = i - r * K;
        int row = row0 + r;
        inT[k][r] = (row < R) ? in[row * in_ld + k] : 0.0f;
    }

    float acc[4][8];
#pragma unroll
    for (int i = 0; i < 4; ++i)
#pragma unroll
        for (int j = 0; j < 8; ++j) acc[i][j] = 0.0f;

    for (int kc = 0; kc < K; kc += KC) {
        __syncthreads();
        for (int i = tid; i < KC * N; i += 256) {
            int k = i / N, c = i - k * N;
            Wl[k][c] = W[(kc + k) * w_ld + c];
        }
        __syncthreads();
#pragma unroll 8
        for (int kk = 0; kk < KC; ++kk) {
            const float4 a  = *(const float4*)&inT[kc + kk][r0];
            const float4 b0 = *(const float4*)&Wl[kk][c0];
            const float4 b1 = *(const float4*)&Wl[kk][c0 + 4];
            const float av[4] = {a.x, a.y, a.z, a.w};
            const float bv[8] = {b0.x, b0.y, b0.z, b0.w, b1.x, b1.y, b1.z, b1.w};
#pragma unroll
            for (int i = 0; i < 4; ++i)
#pragma unroll
                for (int j = 0; j < 8; ++j)
                    acc[i][j] = fmaf(av[i], bv[j], acc[i][j]);
        }
    }

#pragma unroll
    for (int i = 0; i < 4; ++i) {
        int row = row0 + r0 + i;
        if (row >= R) break;
#pragma unroll
        for (int j = 0; j < 8; ++j) {
            float v = acc[i][j] * scale;
            int idx = row * out_ld + c0 + j;
            if constexpr (MODE == 6) out[idx] += v;
            else out[idx] = v;
        }
    }
}

// ---------------------------------------------------------------------------
// CSR build
// ---------------------------------------------------------------------------
__global__ void k_count(const int* __restrict__ rcv, int* __restrict__ deg)
{
    int e = blockIdx.x * 256 + threadIdx.x;
    if (e < EE) atomicAdd(&deg[rcv[e]], 1);
}

__global__ __launch_bounds__(256) void k_scan(const int* __restrict__ deg,
                                              int* __restrict__ rowptr,
                                              int* __restrict__ cursor)
{
    __shared__ int part[256];
    const int t = threadIdx.x;
    const int PER = (NN + 255) / 256;
    int base = t * PER;
    int s = 0;
    for (int j = 0; j < PER; ++j) { int idx = base + j; if (idx < NN) s += deg[idx]; }
    part[t] = s;
    __syncthreads();
    for (int off = 1; off < 256; off <<= 1) {
        int v = (t >= off) ? part[t - off] : 0;
        __syncthreads();
        part[t] += v;
        __syncthreads();
    }
    int run = (t == 0) ? 0 : part[t - 1];
    for (int j = 0; j < PER; ++j) {
        int idx = base + j;
        if (idx < NN) { rowptr[idx] = run; cursor[idx] = run; run += deg[idx]; }
    }
    if (t == 255) rowptr[NN] = part[255];
}

__global__ void k_fill(const int* __restrict__ rcv, int* __restrict__ cursor,
                       int* __restrict__ perm)
{
    int e = blockIdx.x * 256 + threadIdx.x;
    if (e >= EE) return;
    int pos = atomicAdd(&cursor[rcv[e]], 1);
    perm[pos] = e;
}

__global__ __launch_bounds__(256) void k_sortwave(const int* __restrict__ rowptr,
                                                  int* __restrict__ perm)
{
    int gid = blockIdx.x * 256 + threadIdx.x;
    int wid = gid >> 6;
    int lane = gid & 63;
    if (wid >= NN) return;
    int a = rowptr[wid], b = rowptr[wid + 1];
    int d = b - a;
    if (d <= 1) return;
    if (d <= 64) {
        int v = (lane < d) ? perm[a + lane] : 0x7fffffff;
        int rank = 0;
        for (int j = 0; j < 64; ++j) {
            int vj = __shfl(v, j);
            if (j < d && vj < v) ++rank;
        }
        if (lane < d) perm[a + rank] = v;
    } else if (lane == 0) {
        for (int i = a + 1; i < b; ++i) {
            int v = perm[i]; int j = i - 1;
            while (j >= a && perm[j] > v) { perm[j + 1] = perm[j]; --j; }
            perm[j + 1] = v;
        }
    }
}

// geometry in CSR order; ef written as bf16 [EE][32] (k>=8 zero-padded)
__global__ void k_geom_perm(const float* __restrict__ pos, const float* __restrict__ shifts,
                            const int* __restrict__ snd, const int* __restrict__ rcv,
                            const int* __restrict__ perm,
                            float* __restrict__ Yv, unsigned short* __restrict__ efb,
                            int* __restrict__ psnd)
{
    int i = blockIdx.x * 256 + threadIdx.x;
    if (i >= EE) return;
    int e = perm[i];
    int s = snd[e], r = rcv[e];
    psnd[i] = s;
    float vx = pos[r * 3 + 0] - pos[s * 3 + 0] + shifts[e * 3 + 0];
    float vy = pos[r * 3 + 1] - pos[s * 3 + 1] + shifts[e * 3 + 1];
    float vz = pos[r * 3 + 2] - pos[s * 3 + 2] + shifts[e * 3 + 2];
    float len = sqrtf(vx * vx + vy * vy + vz * vz + 1e-12f);
    float inv = 1.0f / len;
    const float SQ3 = 1.7320508075688772f;
    Yv[i * 3 + 0] = SQ3 * vx * inv;
    Yv[i * 3 + 1] = SQ3 * vy * inv;
    Yv[i * 3 + 2] = SQ3 * vz * inv;
    float u = len * 0.2f;
    float fc = 0.0f;
    if (u < 1.0f) {
        float u2 = u * u, u4 = u2 * u2, u5 = u4 * u, u6 = u5 * u, u7 = u6 * u;
        fc = 1.0f - 21.0f * u5 + 35.0f * u6 - 15.0f * u7;
    }
    float pref = 0.6324555320336759f * inv * fc;
    const float PIO5 = 0.6283185307179586f;
    union { unsigned short u16[8]; uint4 v; } pk;
#pragma unroll
    for (int n = 1; n <= 8; ++n)
        pk.u16[n - 1] = f2bf(pref * sinf((float)n * PIO5 * len));
    uint4* dst = (uint4*)(efb + (size_t)i * 32);
    dst[0] = pk.v;
    dst[1] = make_uint4(0u, 0u, 0u, 0u);
    dst[2] = make_uint4(0u, 0u, 0u, 0u);
    dst[3] = make_uint4(0u, 0u, 0u, 0u);
}

// ---------------------------------------------------------------------------
// gathers (unchanged from round 11: streaming + payload, no spill)
// ---------------------------------------------------------------------------
__global__ __launch_bounds__(256) void k_gather1(
    const int* __restrict__ rowptr, const int* __restrict__ psnd,
    const float* __restrict__ Yv, const unsigned short* __restrict__ wb,
    int e0, int e1,
    const float* __restrict__ gS,
    float* __restrict__ outS, float* __restrict__ outV)
{
    const int t = threadIdx.x;
    const int c = t & 127;
    const int n = blockIdx.x * 2 + (t >> 7);
    if (n >= NN) return;
    int rs = rowptr[n], re = rowptr[n + 1];
    if (rs < e0) rs = e0;
    if (re > e1) re = e1;
    if (rs >= re) return;
    float accs = 0.f, a0 = 0.f, a1 = 0.f, a2 = 0.f;
    for (int i = rs; i < re; ++i) {
        const unsigned short* wp = wb + (size_t)(i - e0) * 256;
        float wss = bf2f(wp[c]);
        float wsv = bf2f(wp[128 + c]);
        float h = gS[psnd[i] * 128 + c];
        float y0 = Yv[i * 3], y1 = Yv[i * 3 + 1], y2 = Yv[i * 3 + 2];
        accs = fmaf(wss, h, accs);
        float tv = wsv * h;
        a0 = fmaf(tv, y0, a0); a1 = fmaf(tv, y1, a1); a2 = fmaf(tv, y2, a2);
    }
    outS[n * 128 + c] += accs;
    outV[n * 384 + c]       += a0;
    outV[n * 384 + 128 + c] += a1;
    outV[n * 384 + 256 + c] += a2;
}

__global__ __launch_bounds__(256) void k_gather23(
    const int* __restrict__ rowptr, const int* __restrict__ psnd,
    const float* __restrict__ Yv, const unsigned short* __restrict__ wb,
    int e0, int e1,
    const float* __restrict__ gS, const float* __restrict__ gV,
    float* __restrict__ outS, float* __restrict__ outV)
{
    const int t = threadIdx.x;
    const int c = t & 127;
    const int n = blockIdx.x * 2 + (t >> 7);
    if (n >= NN) return;
    int rs = rowptr[n], re = rowptr[n + 1];
    if (rs < e0) rs = e0;
    if (re > e1) re = e1;
    if (rs >= re) return;
    float accs = 0.f, a0 = 0.f, a1 = 0.f, a2 = 0.f;
    for (int i = rs; i < re; ++i) {
        const unsigned short* wp = wb + (size_t)(i - e0) * 512;
        float wa = bf2f(wp[c]);
        float wbv = bf2f(wp[128 + c]);
        float wc = bf2f(wp[256 + c]);
        float wd = bf2f(wp[384 + c]);
        int s = psnd[i];
        float hs = gS[s * 128 + c];
        float v0 = gV[s * 384 + c];
        float v1 = gV[s * 384 + 128 + c];
        float v2 = gV[s * 384 + 256 + c];
        float y0 = Yv[i * 3], y1 = Yv[i * 3 + 1], y2 = Yv[i * 3 + 2];
        float hd = v0 * y0 + v1 * y1 + v2 * y2;
        accs = fmaf(wa, hs, accs);
        accs = fmaf(wbv, hd * 0.57735026919f, accs);
        float tv = wc * hs;
        a0 = fmaf(tv, y0, a0); a0 = fmaf(wd, v0, a0);
        a1 = fmaf(tv, y1, a1); a1 = fmaf(wd, v1, a1);
        a2 = fmaf(tv, y2, a2); a2 = fmaf(wd, v2, a2);
    }
    outS[n * 128 + c] += accs;
    outV[n * 384 + c]       += a0;
    outV[n * 384 + 128 + c] += a1;
    outV[n * 384 + 256 + c] += a2;
}

// ---------------------------------------------------------------------------
__global__ void k_species(const float* __restrict__ attrs, int* __restrict__ species)
{
    int n = blockIdx.x * 256 + threadIdx.x;
    if (n >= NN) return;
    int sp = 0;
#pragma unroll
    for (int j = 0; j < NEL; ++j)
        if (attrs[n * NEL + j] > 0.5f) sp = j;
    species[n] = sp;
}

__global__ void k_embed(const float* __restrict__ W_emb, const int* __restrict__ species,
                        float* __restrict__ h)
{
    int t = blockIdx.x * 256 + threadIdx.x;
    if (t >= NN * CC) return;
    int n = t >> 7, c = t & 127;
    h[t] = W_emb[species[n] * CC + c];
}

__global__ void k_rmix(const float* __restrict__ Rmid, const float* __restrict__ Rout,
                       float* __restrict__ rmix)
{
    int c = threadIdx.x;
    float s = 0.f;
#pragma unroll
    for (int k = 0; k < 16; ++k) s = fmaf(Rmid[c * 16 + k], Rout[k], s);
    rmix[c] = s;
}

__global__ void k_B1(const int* __restrict__ species,
                     const float* __restrict__ As_l, const float* __restrict__ Av_l,
                     const float* __restrict__ P_s1, const float* __restrict__ P_ss,
                     const float* __restrict__ P_vv, const float* __restrict__ P_v1,
                     const float* __restrict__ P_sv,
                     float* __restrict__ Bs, float* __restrict__ Bv)
{
    int t = blockIdx.x * 256 + threadIdx.x;
    if (t >= NN * CC) return;
    int n = t >> 7, c = t & 127;
    int sp = species[n];
    int pb = sp * CC + c;
    int vb = n * 384 + c;
    float as = As_l[t];
    float a0 = Av_l[vb], a1 = Av_l[vb + CC], a2 = Av_l[vb + 2 * CC];
    Bs[t] = P_s1[pb] * as + P_ss[pb] * as * as
          + P_vv[pb] * (a0 * a0 + a1 * a1 + a2 * a2) * 0.57735026919f;
    float tv = P_v1[pb] + P_sv[pb] * as;
    Bv[vb] = tv * a0; Bv[vb + CC] = tv * a1; Bv[vb + 2 * CC] = tv * a2;
}

__global__ void k_B2(const int* __restrict__ species,
                     const float* __restrict__ As_l, const float* __restrict__ Av_l,
                     const float* __restrict__ P_v1, const float* __restrict__ P_sv,
                     float* __restrict__ Bv)
{
    int t = blockIdx.x * 256 + threadIdx.x;
    if (t >= NN * CC) return;
    int n = t >> 7, c = t & 127;
    int sp = species[n];
    int pb = sp * CC + c;
    int vb = n * 384 + c;
    float as = As_l[t];
    float tv = P_v1[pb] + P_sv[pb] * as;
    Bv[vb] = tv * Av_l[vb];
    Bv[vb + CC] = tv * Av_l[vb + CC];
    Bv[vb + 2 * CC] = tv * Av_l[vb + 2 * CC];
}

__global__ void k_dip1(const float* __restrict__ h_v, const float* __restrict__ R1,
                       float* __restrict__ dip1)
{
    int n = blockIdx.x, l = threadIdx.x;
    const float* hb = h_v + n * 384;
#pragma unroll
    for (int d = 0; d < 3; ++d) {
        float v = hb[d * CC + l] * R1[l] + hb[d * CC + 64 + l] * R1[64 + l];
        for (int o = 32; o > 0; o >>= 1) v += __shfl_down(v, o);
        if (l == 0) dip1[n * 3 + d] = v;
    }
}

__global__ void k_sc(const int* __restrict__ species, const float* __restrict__ h_v,
                     const float* __restrict__ Wsk, float* __restrict__ h2v)
{
    int n = blockIdx.x, f = threadIdx.x;
    int sp = species[n];
    const float* Wp = Wsk + sp * (CC * CC);
    const float* hvn = h_v + n * 384;
    float a0 = 0.f, a1 = 0.f, a2 = 0.f;
    for (int c = 0; c < CC; ++c) {
        float w = Wp[c * CC + f];
        a0 = fmaf(hvn[c], w, a0);
        a1 = fmaf(hvn[CC + c], w, a1);
        a2 = fmaf(hvn[2 * CC + c], w, a2);
    }
    h2v[n * 384 + f] = a0;
    h2v[n * 384 + CC + f] = a1;
    h2v[n * 384 + 2 * CC + f] = a2;
}

__global__ void k_node_out(const float* __restrict__ h2v, const float* __restrict__ rmix,
                           const float* __restrict__ dip1,
                           const float* __restrict__ charges, const float* __restrict__ pos,
                           float* __restrict__ out, float* __restrict__ tot)
{
    int n = blockIdx.x, l = threadIdx.x;
    const float* hb = h2v + n * 384;
    float r0 = rmix[l], r1 = rmix[64 + l];
    float red[3];
#pragma unroll
    for (int d = 0; d < 3; ++d) {
        float v = hb[d * CC + l] * r0 + hb[d * CC + 64 + l] * r1;
        for (int o = 32; o > 0; o >>= 1) v += __shfl_down(v, o);
        red[d] = v;
    }
    if (l == 0) {
        float q = charges[n];
#pragma unroll
        for (int d = 0; d < 3; ++d) {
            float a = dip1[n * 3 + d] + 0.5f * red[d];
            out[48 + n * 3 + d] = a;
            tot[n * 3 + d] = a + q * pos[n * 3 + d];
        }
    }
}

__global__ __launch_bounds__(256) void k_greduce(const float* __restrict__ tot,
                                                 const int* __restrict__ batch,
                                                 float* __restrict__ out)
{
    __shared__ float r[256 * 3];
    const int g = blockIdx.x;
    const int t = threadIdx.x;
    float s0 = 0.f, s1 = 0.f, s2 = 0.f;
    for (int n = t; n < NN; n += 256) {
        if (batch[n] == g) {
            s0 += tot[n * 3]; s1 += tot[n * 3 + 1]; s2 += tot[n * 3 + 2];
        }
    }
    r[t] = s0; r[256 + t] = s1; r[512 + t] = s2;
    __syncthreads();
    for (int off = 128; off > 0; off >>= 1) {
        if (t < off) {
            r[t] += r[t + off];
            r[256 + t] += r[256 + t + off];
            r[512 + t] += r[512 + t + off];
        }
        __syncthreads();
    }
    if (t < 3) out[g * 3 + t] = r[t * 256];
}

// ---------------------------------------------------------------------------
extern "C" void kernel_launch(void* const* d_in, const int* in_sizes, int n_in,
                              void* d_out, int out_size, void* d_ws, size_t ws_size,
                              hipStream_t stream)
{
    const float* positions = (const float*)d_in[0];
    const float* node_attrs = (const float*)d_in[1];
    const float* charges = (const float*)d_in[2];
    const float* shifts = (const float*)d_in[3];
    const int*   eidx = (const int*)d_in[4];
    const int*   batch = (const int*)d_in[5];
    const float* W_emb  = (const float*)d_in[7];
    const float* W_up1  = (const float*)d_in[8];
    const float* Wr1_1  = (const float*)d_in[9];
    const float* Wr1_2  = (const float*)d_in[10];
    const float* Wr1_3  = (const float*)d_in[11];
    const float* Wr1_o  = (const float*)d_in[12];
    const float* Wlin1_s = (const float*)d_in[13];
    const float* Wlin1_v = (const float*)d_in[14];
    const float* P1_s1 = (const float*)d_in[15];
    const float* P1_ss = (const float*)d_in[16];
    const float* P1_vv = (const float*)d_in[17];
    const float* P1_v1 = (const float*)d_in[18];
    const float* P1_sv = (const float*)d_in[19];
    const float* Lp1_s = (const float*)d_in[20];
    const float* Lp1_v = (const float*)d_in[21];
    const float* R1    = (const float*)d_in[22];
    const float* Wsk   = (const float*)d_in[23];
    const float* Wup2_s = (const float*)d_in[24];
    const float* Wup2_v = (const float*)d_in[25];
    const float* Wr2_1 = (const float*)d_in[26];
    const float* Wr2_2 = (const float*)d_in[27];
    const float* Wr2_3 = (const float*)d_in[28];
    const float* Wr2_o = (const float*)d_in[29];
    const float* Wlin2_s = (const float*)d_in[30];
    const float* Wlin2_v = (const float*)d_in[31];
    const float* P2_v1 = (const float*)d_in[32];
    const float* P2_sv = (const float*)d_in[33];
    const float* Lp2_v = (const float*)d_in[34];
    const float* Rmid  = (const float*)d_in[35];
    const float* Rout  = (const float*)d_in[36];
    (void)in_sizes; (void)n_in; (void)out_size;

    const int* snd = eidx;
    const int* rcv = eidx + EE;
    float* out = (float*)d_out;

    char* ws = (char*)d_ws;
    size_t off = 0;
    auto alloc = [&](size_t bytes) -> void* {
        void* p = (void*)(ws + off);
        off = (off + bytes + 255) & ~(size_t)255;
        return p;
    };
    int*   species = (int*)alloc((size_t)NN * 4);
    int*   deg     = (int*)alloc((size_t)NN * 4);
    int*   rowptr  = (int*)alloc((size_t)(NN + 16) * 4);
    int*   cursor  = (int*)alloc((size_t)NN * 4);
    int*   perm    = (int*)alloc((size_t)EE * 4);
    int*   psnd    = (int*)alloc((size_t)EE * 4);
    float* Yv   = (float*)alloc((size_t)EE * 3 * 4);
    unsigned short* efb = (unsigned short*)alloc((size_t)EE * 32 * 2);
    float* A_s  = (float*)alloc((size_t)NN * CC * 4);
    float* A_v  = (float*)alloc((size_t)NN * 3 * CC * 4);
    float* hbuf = (float*)alloc((size_t)NN * CC * 4);
    float* hu   = (float*)alloc((size_t)NN * CC * 4);
    float* h_v  = (float*)alloc((size_t)NN * 3 * CC * 4);
    float* hv   = (float*)alloc((size_t)NN * 3 * CC * 4);
    float* h2v  = (float*)alloc((size_t)NN * 3 * CC * 4);
    float* dip1 = (float*)alloc((size_t)NN * 3 * 4);
    float* rmix = (float*)alloc((size_t)CC * 4);
    float* tot  = (float*)alloc((size_t)NN * 3 * 4);
    // bf16 transposed weights
    unsigned short* W1t_l1 = (unsigned short*)alloc(64 * 32 * 2);
    unsigned short* W2t_l1 = (unsigned short*)alloc(64 * 64 * 2);
    unsigned short* W3t_l1 = (unsigned short*)alloc(64 * 64 * 2);
    unsigned short* Wot_l1 = (unsigned short*)alloc(256 * 64 * 2);
    unsigned short* W1t_l2 = (unsigned short*)alloc(64 * 32 * 2);
    unsigned short* W2t_l2 = (unsigned short*)alloc(64 * 64 * 2);
    unsigned short* W3t_l2 = (unsigned short*)alloc(64 * 64 * 2);
    unsigned short* Wot_l2 = (unsigned short*)alloc(512 * 64 * 2);
    unsigned short* hbA = (unsigned short*)alloc((size_t)EE * 64 * 2);
    unsigned short* hbB = (unsigned short*)alloc((size_t)EE * 64 * 2);

    // wbuf chunking: pick largest chunk that fits
    int C = 16;
    if (off + (size_t)(EE / 4) * 512 * 2 + 4096 <= ws_size) C = 4;
    else if (off + (size_t)(EE / 8) * 512 * 2 + 4096 <= ws_size) C = 8;
    const int EC = EE / C;
    unsigned short* wbuf = (unsigned short*)alloc((size_t)EC * 512 * 2);

    const float inv16 = 1.0f / 16.0f;
    const float one = 1.0f;

    hipMemsetAsync(deg, 0, (size_t)NN * 4, stream);
    hipMemsetAsync(A_s, 0, (size_t)NN * CC * 4, stream);
    hipMemsetAsync(A_v, 0, (size_t)NN * 3 * CC * 4, stream);

    // weight prep (tiny)
    k_wprep<<<cdiv(64 * 32, 256), 256, 0, stream>>>(Wr1_1, W1t_l1, 8, 64, 32);
    k_wprep<<<cdiv(64 * 64, 256), 256, 0, stream>>>(Wr1_2, W2t_l1, 64, 64, 64);
    k_wprep<<<cdiv(64 * 64, 256), 256, 0, stream>>>(Wr1_3, W3t_l1, 64, 64, 64);
    k_wprep<<<cdiv(256 * 64, 256), 256, 0, stream>>>(Wr1_o, Wot_l1, 64, 256, 64);
    k_wprep<<<cdiv(64 * 32, 256), 256, 0, stream>>>(Wr2_1, W1t_l2, 8, 64, 32);
    k_wprep<<<cdiv(64 * 64, 256), 256, 0, stream>>>(Wr2_2, W2t_l2, 64, 64, 64);
    k_wprep<<<cdiv(64 * 64, 256), 256, 0, stream>>>(Wr2_3, W3t_l2, 64, 64, 64);
    k_wprep<<<cdiv(512 * 64, 256), 256, 0, stream>>>(Wr2_o, Wot_l2, 64, 512, 64);

    // ---- CSR build + permuted geometry ----
    k_count<<<cdiv(EE, 256), 256, 0, stream>>>(rcv, deg);
    k_scan<<<1, 256, 0, stream>>>(deg, rowptr, cursor);
    k_fill<<<cdiv(EE, 256), 256, 0, stream>>>(rcv, cursor, perm);
    k_sortwave<<<cdiv(NN * 64, 256), 256, 0, stream>>>(rowptr, perm);
    k_geom_perm<<<cdiv(EE, 256), 256, 0, stream>>>(positions, shifts, snd, rcv, perm, Yv, efb, psnd);

    k_species<<<cdiv(NN, 256), 256, 0, stream>>>(node_attrs, species);
    k_embed<<<cdiv(NN * CC, 256), 256, 0, stream>>>(W_emb, species, hbuf);
    k_rmix<<<1, CC, 0, stream>>>(Rmid, Rout, rmix);

    // hu = h @ W_up1 (fp32)
    rowgemm_k<128, 128, 0><<<cdiv(NN, 64), 256, 0, stream>>>(
        hbuf, 128, W_up1, 128, hu, 128, NN, one);

    // ---- layer 1: MFMA edge MLP (full EE) -> chunked wgemm + gather ----
    mfma_gemm<32, 64, 1><<<cdiv(EE, 64), 256, 0, stream>>>(efb, 32, W1t_l1, hbA, 64, EE);
    mfma_gemm<64, 64, 1><<<cdiv(EE, 64), 256, 0, stream>>>(hbA, 64, W2t_l1, hbB, 64, EE);
    mfma_gemm<64, 64, 1><<<cdiv(EE, 64), 256, 0, stream>>>(hbB, 64, W3t_l1, hbA, 64, EE);
    for (int ch = 0; ch < C; ++ch) {
        int e0 = ch * EC, e1 = e0 + EC;
        mfma_gemm<64, 128, 2><<<dim3(cdiv(EC, 64), 2), 256, 0, stream>>>(
            hbA + (size_t)e0 * 64, 64, Wot_l1, wbuf, 256, EC);
        k_gather1<<<NN / 2, 256, 0, stream>>>(
            rowptr, psnd, Yv, wbuf, e0, e1, hu, A_s, A_v);
    }

    // ---- layer 1 node side (fp32) ----
    rowgemm_k<128, 128, 0><<<cdiv(NN, 64), 256, 0, stream>>>(
        A_s, 128, Wlin1_s, 128, A_s, 128, NN, inv16);
    rowgemm_k<128, 128, 0><<<cdiv(3 * NN, 64), 256, 0, stream>>>(
        A_v, 128, Wlin1_v, 128, A_v, 128, 3 * NN, inv16);
    k_B1<<<cdiv(NN * CC, 256), 256, 0, stream>>>(
        species, A_s, A_v, P1_s1, P1_ss, P1_vv, P1_v1, P1_sv, hbuf /*Bs*/, A_v /*Bv*/);
    rowgemm_k<128, 128, 0><<<cdiv(NN, 64), 256, 0, stream>>>(
        hbuf, 128, Lp1_s, 128, hu /*h_s*/, 128, NN, one);
    rowgemm_k<128, 128, 0><<<cdiv(3 * NN, 64), 256, 0, stream>>>(
        A_v /*Bv*/, 128, Lp1_v, 128, h_v, 128, 3 * NN, one);
    k_dip1<<<NN, 64, 0, stream>>>(h_v, R1, dip1);
    rowgemm_k<128, 128, 0><<<cdiv(NN, 64), 256, 0, stream>>>(
        hu /*h_s*/, 128, Wup2_s, 128, hbuf /*hs*/, 128, NN, one);
    rowgemm_k<128, 128, 0><<<cdiv(3 * NN, 64), 256, 0, stream>>>(
        h_v, 128, Wup2_v, 128, hv, 128, 3 * NN, one);

    // ---- layer 2: MFMA edge MLP -> chunked wgemm + merged gather ----
    hipMemsetAsync(A_s, 0, (size_t)NN * CC * 4, stream);
    hipMemsetAsync(A_v, 0, (size_t)NN * 3 * CC * 4, stream);
    mfma_gemm<32, 64, 1><<<cdiv(EE, 64), 256, 0, stream>>>(efb, 32, W1t_l2, hbA, 64, EE);
    mfma_gemm<64, 64, 1><<<cdiv(EE, 64), 256, 0, stream>>>(hbA, 64, W2t_l2, hbB, 64, EE);
    mfma_gemm<64, 64, 1><<<cdiv(EE, 64), 256, 0, stream>>>(hbB, 64, W3t_l2, hbA, 64, EE);
    for (int ch = 0; ch < C; ++ch) {
        int e0 = ch * EC, e1 = e0 + EC;
        mfma_gemm<64, 128, 2><<<dim3(cdiv(EC, 64), 4), 256, 0, stream>>>(
            hbA + (size_t)e0 * 64, 64, Wot_l2, wbuf, 512, EC);
        k_gather23<<<NN / 2, 256, 0, stream>>>(
            rowptr, psnd, Yv, wbuf, e0, e1, hbuf /*hs*/, hv, A_s, A_v);
    }

    // ---- layer 2 node side ----
    rowgemm_k<128, 128, 0><<<cdiv(NN, 64), 256, 0, stream>>>(
        A_s, 128, Wlin2_s, 128, A_s, 128, NN, inv16);
    rowgemm_k<128, 128, 0><<<cdiv(3 * NN, 64), 256, 0, stream>>>(
        A_v, 128, Wlin2_v, 128, A_v, 128, 3 * NN, inv16);
    k_sc<<<NN, 128, 0, stream>>>(species, h_v, Wsk, h2v);
    k_B2<<<cdiv(NN * CC, 256), 256, 0, stream>>>(species, A_s, A_v, P2_v1, P2_sv, A_v /*B2v*/);
    rowgemm_k<128, 128, 6><<<cdiv(3 * NN, 64), 256, 0, stream>>>(
        A_v /*B2v*/, 128, Lp2_v, 128, h2v, 128, 3 * NN, one);

    k_node_out<<<NN, 64, 0, stream>>>(h2v, rmix, dip1, charges, positions, out, tot);
    k_greduce<<<NGR, 256, 0, stream>>>(tot, batch, out);
}

// Round 13
// 614.612 us; speedup vs baseline: 3.6017x; 1.2599x over previous
//
#include <hip/hip_runtime.h>

#define NN 10000
#define EE 160000
#define CC 128
#define NEL 10
#define NGR 16

static inline int cdiv(int a, int b) { return (a + b - 1) / b; }

__device__ __forceinline__ float silu_f(float x) { return x / (1.0f + __expf(-x)); }

__device__ __forceinline__ float bf2f(unsigned short u) {
    unsigned int x = ((unsigned int)u) << 16;
    return __uint_as_float(x);
}
__device__ __forceinline__ unsigned short f2bf(float f) {
    unsigned int x = __float_as_uint(f);
    unsigned int r = x + 0x7fffu + ((x >> 16) & 1u);
    return (unsigned short)(r >> 16);
}

typedef __attribute__((ext_vector_type(8))) short bf16x8;
typedef __attribute__((ext_vector_type(4))) float f32x4;

// ---------------------------------------------------------------------------
// MFMA GEMM bf16->bf16 (edge MLP). Wt pre-transposed bf16 [Ntot][K].
// MODE 1: silu, 2: plain. LDS XOR swizzle (row&7)<<4; m89 fragment layout.
// ---------------------------------------------------------------------------
template <int K, int N, int MODE>
__global__ __launch_bounds__(256) void mfma_gemm(
    const unsigned short* __restrict__ in, int in_ld,
    const unsigned short* __restrict__ Wt,
    unsigned short* __restrict__ out, int out_ld,
    int R)
{
    constexpr int NT = N / 16;
    constexpr int KC = K / 32;
    constexpr int CPR = K / 8;
    __shared__ __align__(16) unsigned short Ash[64 * K];
    __shared__ __align__(16) unsigned short Bsh[N * K];

    const int tid = threadIdx.x;
    const int w = tid >> 6;
    const int l = tid & 63;
    const int row0 = blockIdx.x * 64;
    const int cb = blockIdx.y * N;

    for (int cid = tid; cid < 64 * CPR; cid += 256) {
        int r = cid / CPR, k8 = cid % CPR;
        int row = row0 + r;
        uint4 val = make_uint4(0u, 0u, 0u, 0u);
        if (row < R) val = *(const uint4*)(in + (size_t)row * in_ld + k8 * 8);
        unsigned bo = ((unsigned)(r * K + k8 * 8) * 2u) ^ (((unsigned)(r & 7)) << 4);
        *(uint4*)((char*)Ash + bo) = val;
    }
    for (int cid = tid; cid < N * CPR; cid += 256) {
        int nn = cid / CPR, k8 = cid % CPR;
        uint4 val = *(const uint4*)(Wt + (size_t)(cb + nn) * K + k8 * 8);
        unsigned bo = ((unsigned)(nn * K + k8 * 8) * 2u) ^ (((unsigned)(nn & 7)) << 4);
        *(uint4*)((char*)Bsh + bo) = val;
    }
    __syncthreads();

    bf16x8 afr[KC];
#pragma unroll
    for (int kc = 0; kc < KC; ++kc) {
        int r = w * 16 + (l & 15);
        int k = kc * 32 + (l >> 4) * 8;
        unsigned bo = ((unsigned)(r * K + k) * 2u) ^ (((unsigned)(r & 7)) << 4);
        afr[kc] = *(const bf16x8*)((char*)Ash + bo);
    }

    f32x4 acc[NT];
#pragma unroll
    for (int nt = 0; nt < NT; ++nt) {
        acc[nt] = (f32x4){0.f, 0.f, 0.f, 0.f};
#pragma unroll
        for (int kc = 0; kc < KC; ++kc) {
            int col = nt * 16 + (l & 15);
            int k = kc * 32 + (l >> 4) * 8;
            unsigned bo = ((unsigned)(col * K + k) * 2u) ^ (((unsigned)(col & 7)) << 4);
            bf16x8 bfr = *(const bf16x8*)((char*)Bsh + bo);
            acc[nt] = __builtin_amdgcn_mfma_f32_16x16x32_bf16(afr[kc], bfr, acc[nt], 0, 0, 0);
        }
    }

#pragma unroll
    for (int nt = 0; nt < NT; ++nt) {
#pragma unroll
        for (int rg = 0; rg < 4; ++rg) {
            int row = row0 + w * 16 + (l >> 4) * 4 + rg;
            if (row < R) {
                int col = cb + nt * 16 + (l & 15);
                float v = acc[nt][rg];
                if constexpr (MODE == 1) v = silu_f(v);
                out[(size_t)row * out_ld + col] = f2bf(v);
            }
        }
    }
}

// ---------------------------------------------------------------------------
// MFMA GEMM fp32->fp32 (node side): A converted to bf16 at stage time.
// MODE 0: store, 6: accumulate. K=128 N=128 typical.
// ---------------------------------------------------------------------------
template <int K, int N, int MODE>
__global__ __launch_bounds__(256) void mfma_gemm_f32(
    const float* __restrict__ in, int in_ld,
    const unsigned short* __restrict__ Wt,
    float* __restrict__ out, int out_ld,
    int R, float scale)
{
    constexpr int NT = N / 16;
    constexpr int KC = K / 32;
    constexpr int CPR = K / 8;
    __shared__ __align__(16) unsigned short Ash[64 * K];
    __shared__ __align__(16) unsigned short Bsh[N * K];

    const int tid = threadIdx.x;
    const int w = tid >> 6;
    const int l = tid & 63;
    const int row0 = blockIdx.x * 64;
    const int cb = blockIdx.y * N;

    for (int cid = tid; cid < 64 * CPR; cid += 256) {
        int r = cid / CPR, k8 = cid % CPR;
        int row = row0 + r;
        union { unsigned short u16[8]; uint4 v; } pk;
        if (row < R) {
            const float* p = in + (size_t)row * in_ld + k8 * 8;
            float4 f0 = *(const float4*)p;
            float4 f1 = *(const float4*)(p + 4);
            pk.u16[0] = f2bf(f0.x); pk.u16[1] = f2bf(f0.y);
            pk.u16[2] = f2bf(f0.z); pk.u16[3] = f2bf(f0.w);
            pk.u16[4] = f2bf(f1.x); pk.u16[5] = f2bf(f1.y);
            pk.u16[6] = f2bf(f1.z); pk.u16[7] = f2bf(f1.w);
        } else {
            pk.v = make_uint4(0u, 0u, 0u, 0u);
        }
        unsigned bo = ((unsigned)(r * K + k8 * 8) * 2u) ^ (((unsigned)(r & 7)) << 4);
        *(uint4*)((char*)Ash + bo) = pk.v;
    }
    for (int cid = tid; cid < N * CPR; cid += 256) {
        int nn = cid / CPR, k8 = cid % CPR;
        uint4 val = *(const uint4*)(Wt + (size_t)(cb + nn) * K + k8 * 8);
        unsigned bo = ((unsigned)(nn * K + k8 * 8) * 2u) ^ (((unsigned)(nn & 7)) << 4);
        *(uint4*)((char*)Bsh + bo) = val;
    }
    __syncthreads();

    bf16x8 afr[KC];
#pragma unroll
    for (int kc = 0; kc < KC; ++kc) {
        int r = w * 16 + (l & 15);
        int k = kc * 32 + (l >> 4) * 8;
        unsigned bo = ((unsigned)(r * K + k) * 2u) ^ (((unsigned)(r & 7)) << 4);
        afr[kc] = *(const bf16x8*)((char*)Ash + bo);
    }

    f32x4 acc[NT];
#pragma unroll
    for (int nt = 0; nt < NT; ++nt) {
        acc[nt] = (f32x4){0.f, 0.f, 0.f, 0.f};
#pragma unroll
        for (int kc = 0; kc < KC; ++kc) {
            int col = nt * 16 + (l & 15);
            int k = kc * 32 + (l >> 4) * 8;
            unsigned bo = ((unsigned)(col * K + k) * 2u) ^ (((unsigned)(col & 7)) << 4);
            bf16x8 bfr = *(const bf16x8*)((char*)Bsh + bo);
            acc[nt] = __builtin_amdgcn_mfma_f32_16x16x32_bf16(afr[kc], bfr, acc[nt], 0, 0, 0);
        }
    }

#pragma unroll
    for (int nt = 0; nt < NT; ++nt) {
#pragma unroll
        for (int rg = 0; rg < 4; ++rg) {
            int row = row0 + w * 16 + (l >> 4) * 4 + rg;
            if (row < R) {
                int col = cb + nt * 16 + (l & 15);
                float v = acc[nt][rg] * scale;
                size_t idx = (size_t)row * out_ld + col;
                if constexpr (MODE == 6) out[idx] += v;
                else out[idx] = v;
            }
        }
    }
}

// weight prep: dst[n][k] (bf16 [N][Kpad]) = src[k][n] (f32 [K][N]); zero-pad
__global__ void k_wprep(const float* __restrict__ src, unsigned short* __restrict__ dst,
                        int K, int N, int Kpad)
{
    int i = blockIdx.x * 256 + threadIdx.x;
    if (i >= N * Kpad) return;
    int n = i / Kpad, k = i % Kpad;
    dst[i] = (k < K) ? f2bf(src[k * N + n]) : (unsigned short)0;
}

// batched prep for ten 128x128 node weights (single dispatch)
struct WP10 { const float* s[10]; unsigned short* d[10]; };
__global__ void k_wprep10(WP10 wp)
{
    int m = blockIdx.y;
    int i = blockIdx.x * 256 + threadIdx.x;
    if (i >= 128 * 128) return;
    int n = i / 128, k = i % 128;
    wp.d[m][i] = f2bf(wp.s[m][k * 128 + n]);
}

// ---------------------------------------------------------------------------
// CSR build
// ---------------------------------------------------------------------------
__global__ void k_count(const int* __restrict__ rcv, int* __restrict__ deg)
{
    int e = blockIdx.x * 256 + threadIdx.x;
    if (e < EE) atomicAdd(&deg[rcv[e]], 1);
}

__global__ __launch_bounds__(256) void k_scan(const int* __restrict__ deg,
                                              int* __restrict__ rowptr,
                                              int* __restrict__ cursor)
{
    __shared__ int part[256];
    const int t = threadIdx.x;
    const int PER = (NN + 255) / 256;
    int base = t * PER;
    int s = 0;
    for (int j = 0; j < PER; ++j) { int idx = base + j; if (idx < NN) s += deg[idx]; }
    part[t] = s;
    __syncthreads();
    for (int off = 1; off < 256; off <<= 1) {
        int v = (t >= off) ? part[t - off] : 0;
        __syncthreads();
        part[t] += v;
        __syncthreads();
    }
    int run = (t == 0) ? 0 : part[t - 1];
    for (int j = 0; j < PER; ++j) {
        int idx = base + j;
        if (idx < NN) { rowptr[idx] = run; cursor[idx] = run; run += deg[idx]; }
    }
    if (t == 255) rowptr[NN] = part[255];
}

__global__ void k_fill(const int* __restrict__ rcv, int* __restrict__ cursor,
                       int* __restrict__ perm)
{
    int e = blockIdx.x * 256 + threadIdx.x;
    if (e >= EE) return;
    int pos = atomicAdd(&cursor[rcv[e]], 1);
    perm[pos] = e;
}

__global__ __launch_bounds__(256) void k_sortwave(const int* __restrict__ rowptr,
                                                  int* __restrict__ perm)
{
    int gid = blockIdx.x * 256 + threadIdx.x;
    int wid = gid >> 6;
    int lane = gid & 63;
    if (wid >= NN) return;
    int a = rowptr[wid], b = rowptr[wid + 1];
    int d = b - a;
    if (d <= 1) return;
    if (d <= 64) {
        int v = (lane < d) ? perm[a + lane] : 0x7fffffff;
        int rank = 0;
        for (int j = 0; j < 64; ++j) {
            int vj = __shfl(v, j);
            if (j < d && vj < v) ++rank;
        }
        if (lane < d) perm[a + rank] = v;
    } else if (lane == 0) {
        for (int i = a + 1; i < b; ++i) {
            int v = perm[i]; int j = i - 1;
            while (j >= a && perm[j] > v) { perm[j + 1] = perm[j]; --j; }
            perm[j + 1] = v;
        }
    }
}

// geometry in CSR order; ef written as bf16 [EE][32] (k>=8 zero-padded)
__global__ void k_geom_perm(const float* __restrict__ pos, const float* __restrict__ shifts,
                            const int* __restrict__ snd, const int* __restrict__ rcv,
                            const int* __restrict__ perm,
                            float* __restrict__ Yv, unsigned short* __restrict__ efb,
                            int* __restrict__ psnd)
{
    int i = blockIdx.x * 256 + threadIdx.x;
    if (i >= EE) return;
    int e = perm[i];
    int s = snd[e], r = rcv[e];
    psnd[i] = s;
    float vx = pos[r * 3 + 0] - pos[s * 3 + 0] + shifts[e * 3 + 0];
    float vy = pos[r * 3 + 1] - pos[s * 3 + 1] + shifts[e * 3 + 1];
    float vz = pos[r * 3 + 2] - pos[s * 3 + 2] + shifts[e * 3 + 2];
    float len = sqrtf(vx * vx + vy * vy + vz * vz + 1e-12f);
    float inv = 1.0f / len;
    const float SQ3 = 1.7320508075688772f;
    Yv[i * 3 + 0] = SQ3 * vx * inv;
    Yv[i * 3 + 1] = SQ3 * vy * inv;
    Yv[i * 3 + 2] = SQ3 * vz * inv;
    float u = len * 0.2f;
    float fc = 0.0f;
    if (u < 1.0f) {
        float u2 = u * u, u4 = u2 * u2, u5 = u4 * u, u6 = u5 * u, u7 = u6 * u;
        fc = 1.0f - 21.0f * u5 + 35.0f * u6 - 15.0f * u7;
    }
    float pref = 0.6324555320336759f * inv * fc;
    const float PIO5 = 0.6283185307179586f;
    union { unsigned short u16[8]; uint4 v; } pk;
#pragma unroll
    for (int n = 1; n <= 8; ++n)
        pk.u16[n - 1] = f2bf(pref * sinf((float)n * PIO5 * len));
    uint4* dst = (uint4*)(efb + (size_t)i * 32);
    dst[0] = pk.v;
    dst[1] = make_uint4(0u, 0u, 0u, 0u);
    dst[2] = make_uint4(0u, 0u, 0u, 0u);
    dst[3] = make_uint4(0u, 0u, 0u, 0u);
}

// ---------------------------------------------------------------------------
// gathers (streaming + payload, no spill)
// ---------------------------------------------------------------------------
__global__ __launch_bounds__(256) void k_gather1(
    const int* __restrict__ rowptr, const int* __restrict__ psnd,
    const float* __restrict__ Yv, const unsigned short* __restrict__ wb,
    int e0, int e1,
    const float* __restrict__ gS,
    float* __restrict__ outS, float* __restrict__ outV)
{
    const int t = threadIdx.x;
    const int c = t & 127;
    const int n = blockIdx.x * 2 + (t >> 7);
    if (n >= NN) return;
    int rs = rowptr[n], re = rowptr[n + 1];
    if (rs < e0) rs = e0;
    if (re > e1) re = e1;
    if (rs >= re) return;
    float accs = 0.f, a0 = 0.f, a1 = 0.f, a2 = 0.f;
    for (int i = rs; i < re; ++i) {
        const unsigned short* wp = wb + (size_t)(i - e0) * 256;
        float wss = bf2f(wp[c]);
        float wsv = bf2f(wp[128 + c]);
        float h = gS[psnd[i] * 128 + c];
        float y0 = Yv[i * 3], y1 = Yv[i * 3 + 1], y2 = Yv[i * 3 + 2];
        accs = fmaf(wss, h, accs);
        float tv = wsv * h;
        a0 = fmaf(tv, y0, a0); a1 = fmaf(tv, y1, a1); a2 = fmaf(tv, y2, a2);
    }
    outS[n * 128 + c] += accs;
    outV[n * 384 + c]       += a0;
    outV[n * 384 + 128 + c] += a1;
    outV[n * 384 + 256 + c] += a2;
}

__global__ __launch_bounds__(256) void k_gather23(
    const int* __restrict__ rowptr, const int* __restrict__ psnd,
    const float* __restrict__ Yv, const unsigned short* __restrict__ wb,
    int e0, int e1,
    const float* __restrict__ gS, const float* __restrict__ gV,
    float* __restrict__ outS, float* __restrict__ outV)
{
    const int t = threadIdx.x;
    const int c = t & 127;
    const int n = blockIdx.x * 2 + (t >> 7);
    if (n >= NN) return;
    int rs = rowptr[n], re = rowptr[n + 1];
    if (rs < e0) rs = e0;
    if (re > e1) re = e1;
    if (rs >= re) return;
    float accs = 0.f, a0 = 0.f, a1 = 0.f, a2 = 0.f;
    for (int i = rs; i < re; ++i) {
        const unsigned short* wp = wb + (size_t)(i - e0) * 512;
        float wa = bf2f(wp[c]);
        float wbv = bf2f(wp[128 + c]);
        float wc = bf2f(wp[256 + c]);
        float wd = bf2f(wp[384 + c]);
        int s = psnd[i];
        float hs = gS[s * 128 + c];
        float v0 = gV[s * 384 + c];
        float v1 = gV[s * 384 + 128 + c];
        float v2 = gV[s * 384 + 256 + c];
        float y0 = Yv[i * 3], y1 = Yv[i * 3 + 1], y2 = Yv[i * 3 + 2];
        float hd = v0 * y0 + v1 * y1 + v2 * y2;
        accs = fmaf(wa, hs, accs);
        accs = fmaf(wbv, hd * 0.57735026919f, accs);
        float tv = wc * hs;
        a0 = fmaf(tv, y0, a0); a0 = fmaf(wd, v0, a0);
        a1 = fmaf(tv, y1, a1); a1 = fmaf(wd, v1, a1);
        a2 = fmaf(tv, y2, a2); a2 = fmaf(wd, v2, a2);
    }
    outS[n * 128 + c] += accs;
    outV[n * 384 + c]       += a0;
    outV[n * 384 + 128 + c] += a1;
    outV[n * 384 + 256 + c] += a2;
}

// ---------------------------------------------------------------------------
__global__ void k_species(const float* __restrict__ attrs, int* __restrict__ species)
{
    int n = blockIdx.x * 256 + threadIdx.x;
    if (n >= NN) return;
    int sp = 0;
#pragma unroll
    for (int j = 0; j < NEL; ++j)
        if (attrs[n * NEL + j] > 0.5f) sp = j;
    species[n] = sp;
}

__global__ void k_embed(const float* __restrict__ W_emb, const int* __restrict__ species,
                        float* __restrict__ h)
{
    int t = blockIdx.x * 256 + threadIdx.x;
    if (t >= NN * CC) return;
    int n = t >> 7, c = t & 127;
    h[t] = W_emb[species[n] * CC + c];
}

__global__ void k_rmix(const float* __restrict__ Rmid, const float* __restrict__ Rout,
                       float* __restrict__ rmix)
{
    int c = threadIdx.x;
    float s = 0.f;
#pragma unroll
    for (int k = 0; k < 16; ++k) s = fmaf(Rmid[c * 16 + k], Rout[k], s);
    rmix[c] = s;
}

__global__ void k_B1(const int* __restrict__ species,
                     const float* __restrict__ As_l, const float* __restrict__ Av_l,
                     const float* __restrict__ P_s1, const float* __restrict__ P_ss,
                     const float* __restrict__ P_vv, const float* __restrict__ P_v1,
                     const float* __restrict__ P_sv,
                     float* __restrict__ Bs, float* __restrict__ Bv)
{
    int t = blockIdx.x * 256 + threadIdx.x;
    if (t >= NN * CC) return;
    int n = t >> 7, c = t & 127;
    int sp = species[n];
    int pb = sp * CC + c;
    int vb = n * 384 + c;
    float as = As_l[t];
    float a0 = Av_l[vb], a1 = Av_l[vb + CC], a2 = Av_l[vb + 2 * CC];
    Bs[t] = P_s1[pb] * as + P_ss[pb] * as * as
          + P_vv[pb] * (a0 * a0 + a1 * a1 + a2 * a2) * 0.57735026919f;
    float tv = P_v1[pb] + P_sv[pb] * as;
    Bv[vb] = tv * a0; Bv[vb + CC] = tv * a1; Bv[vb + 2 * CC] = tv * a2;
}

__global__ void k_B2(const int* __restrict__ species,
                     const float* __restrict__ As_l, const float* __restrict__ Av_l,
                     const float* __restrict__ P_v1, const float* __restrict__ P_sv,
                     float* __restrict__ Bv)
{
    int t = blockIdx.x * 256 + threadIdx.x;
    if (t >= NN * CC) return;
    int n = t >> 7, c = t & 127;
    int sp = species[n];
    int pb = sp * CC + c;
    int vb = n * 384 + c;
    float as = As_l[t];
    float tv = P_v1[pb] + P_sv[pb] * as;
    Bv[vb] = tv * Av_l[vb];
    Bv[vb + CC] = tv * Av_l[vb + CC];
    Bv[vb + 2 * CC] = tv * Av_l[vb + 2 * CC];
}

__global__ void k_dip1(const float* __restrict__ h_v, const float* __restrict__ R1,
                       float* __restrict__ dip1)
{
    int n = blockIdx.x, l = threadIdx.x;
    const float* hb = h_v + n * 384;
#pragma unroll
    for (int d = 0; d < 3; ++d) {
        float v = hb[d * CC + l] * R1[l] + hb[d * CC + 64 + l] * R1[64 + l];
        for (int o = 32; o > 0; o >>= 1) v += __shfl_down(v, o);
        if (l == 0) dip1[n * 3 + d] = v;
    }
}

__global__ void k_sc(const int* __restrict__ species, const float* __restrict__ h_v,
                     const float* __restrict__ Wsk, float* __restrict__ h2v)
{
    int n = blockIdx.x, f = threadIdx.x;
    int sp = species[n];
    const float* Wp = Wsk + sp * (CC * CC);
    const float* hvn = h_v + n * 384;
    float a0 = 0.f, a1 = 0.f, a2 = 0.f;
    for (int c = 0; c < CC; ++c) {
        float w = Wp[c * CC + f];
        a0 = fmaf(hvn[c], w, a0);
        a1 = fmaf(hvn[CC + c], w, a1);
        a2 = fmaf(hvn[2 * CC + c], w, a2);
    }
    h2v[n * 384 + f] = a0;
    h2v[n * 384 + CC + f] = a1;
    h2v[n * 384 + 2 * CC + f] = a2;
}

__global__ void k_node_out(const float* __restrict__ h2v, const float* __restrict__ rmix,
                           const float* __restrict__ dip1,
                           const float* __restrict__ charges, const float* __restrict__ pos,
                           float* __restrict__ out, float* __restrict__ tot)
{
    int n = blockIdx.x, l = threadIdx.x;
    const float* hb = h2v + n * 384;
    float r0 = rmix[l], r1 = rmix[64 + l];
    float red[3];
#pragma unroll
    for (int d = 0; d < 3; ++d) {
        float v = hb[d * CC + l] * r0 + hb[d * CC + 64 + l] * r1;
        for (int o = 32; o > 0; o >>= 1) v += __shfl_down(v, o);
        red[d] = v;
    }
    if (l == 0) {
        float q = charges[n];
#pragma unroll
        for (int d = 0; d < 3; ++d) {
            float a = dip1[n * 3 + d] + 0.5f * red[d];
            out[48 + n * 3 + d] = a;
            tot[n * 3 + d] = a + q * pos[n * 3 + d];
        }
    }
}

__global__ __launch_bounds__(256) void k_greduce(const float* __restrict__ tot,
                                                 const int* __restrict__ batch,
                                                 float* __restrict__ out)
{
    __shared__ float r[256 * 3];
    const int g = blockIdx.x;
    const int t = threadIdx.x;
    float s0 = 0.f, s1 = 0.f, s2 = 0.f;
    for (int n = t; n < NN; n += 256) {
        if (batch[n] == g) {
            s0 += tot[n * 3]; s1 += tot[n * 3 + 1]; s2 += tot[n * 3 + 2];
        }
    }
    r[t] = s0; r[256 + t] = s1; r[512 + t] = s2;
    __syncthreads();
    for (int off = 128; off > 0; off >>= 1) {
        if (t < off) {
            r[t] += r[t + off];
            r[256 + t] += r[256 + t + off];
            r[512 + t] += r[512 + t + off];
        }
        __syncthreads();
    }
    if (t < 3) out[g * 3 + t] = r[t * 256];
}

// ---------------------------------------------------------------------------
extern "C" void kernel_launch(void* const* d_in, const int* in_sizes, int n_in,
                              void* d_out, int out_size, void* d_ws, size_t ws_size,
                              hipStream_t stream)
{
    const float* positions = (const float*)d_in[0];
    const float* node_attrs = (const float*)d_in[1];
    const float* charges = (const float*)d_in[2];
    const float* shifts = (const float*)d_in[3];
    const int*   eidx = (const int*)d_in[4];
    const int*   batch = (const int*)d_in[5];
    const float* W_emb  = (const float*)d_in[7];
    const float* W_up1  = (const float*)d_in[8];
    const float* Wr1_1  = (const float*)d_in[9];
    const float* Wr1_2  = (const float*)d_in[10];
    const float* Wr1_3  = (const float*)d_in[11];
    const float* Wr1_o  = (const float*)d_in[12];
    const float* Wlin1_s = (const float*)d_in[13];
    const float* Wlin1_v = (const float*)d_in[14];
    const float* P1_s1 = (const float*)d_in[15];
    const float* P1_ss = (const float*)d_in[16];
    const float* P1_vv = (const float*)d_in[17];
    const float* P1_v1 = (const float*)d_in[18];
    const float* P1_sv = (const float*)d_in[19];
    const float* Lp1_s = (const float*)d_in[20];
    const float* Lp1_v = (const float*)d_in[21];
    const float* R1    = (const float*)d_in[22];
    const float* Wsk   = (const float*)d_in[23];
    const float* Wup2_s = (const float*)d_in[24];
    const float* Wup2_v = (const float*)d_in[25];
    const float* Wr2_1 = (const float*)d_in[26];
    const float* Wr2_2 = (const float*)d_in[27];
    const float* Wr2_3 = (const float*)d_in[28];
    const float* Wr2_o = (const float*)d_in[29];
    const float* Wlin2_s = (const float*)d_in[30];
    const float* Wlin2_v = (const float*)d_in[31];
    const float* P2_v1 = (const float*)d_in[32];
    const float* P2_sv = (const float*)d_in[33];
    const float* Lp2_v = (const float*)d_in[34];
    const float* Rmid  = (const float*)d_in[35];
    const float* Rout  = (const float*)d_in[36];
    (void)in_sizes; (void)n_in; (void)out_size;

    const int* snd = eidx;
    const int* rcv = eidx + EE;
    float* out = (float*)d_out;

    char* ws = (char*)d_ws;
    size_t off = 0;
    auto alloc = [&](size_t bytes) -> void* {
        void* p = (void*)(ws + off);
        off = (off + bytes + 255) & ~(size_t)255;
        return p;
    };
    int*   species = (int*)alloc((size_t)NN * 4);
    int*   deg     = (int*)alloc((size_t)NN * 4);
    int*   rowptr  = (int*)alloc((size_t)(NN + 16) * 4);
    int*   cursor  = (int*)alloc((size_t)NN * 4);
    int*   perm    = (int*)alloc((size_t)EE * 4);
    int*   psnd    = (int*)alloc((size_t)EE * 4);
    float* Yv   = (float*)alloc((size_t)EE * 3 * 4);
    unsigned short* efb = (unsigned short*)alloc((size_t)EE * 32 * 2);
    float* A_s  = (float*)alloc((size_t)NN * CC * 4);
    float* A_v  = (float*)alloc((size_t)NN * 3 * CC * 4);
    float* hbuf = (float*)alloc((size_t)NN * CC * 4);
    float* hu   = (float*)alloc((size_t)NN * CC * 4);
    float* h_v  = (float*)alloc((size_t)NN * 3 * CC * 4);
    float* hv   = (float*)alloc((size_t)NN * 3 * CC * 4);
    float* h2v  = (float*)alloc((size_t)NN * 3 * CC * 4);
    float* dip1 = (float*)alloc((size_t)NN * 3 * 4);
    float* rmix = (float*)alloc((size_t)CC * 4);
    float* tot  = (float*)alloc((size_t)NN * 3 * 4);
    // bf16 transposed edge weights
    unsigned short* W1t_l1 = (unsigned short*)alloc(64 * 32 * 2);
    unsigned short* W2t_l1 = (unsigned short*)alloc(64 * 64 * 2);
    unsigned short* W3t_l1 = (unsigned short*)alloc(64 * 64 * 2);
    unsigned short* Wot_l1 = (unsigned short*)alloc(256 * 64 * 2);
    unsigned short* W1t_l2 = (unsigned short*)alloc(64 * 32 * 2);
    unsigned short* W2t_l2 = (unsigned short*)alloc(64 * 64 * 2);
    unsigned short* W3t_l2 = (unsigned short*)alloc(64 * 64 * 2);
    unsigned short* Wot_l2 = (unsigned short*)alloc(512 * 64 * 2);
    // bf16 transposed node weights (ten 128x128)
    unsigned short* Wn[10];
    for (int m = 0; m < 10; ++m) Wn[m] = (unsigned short*)alloc(128 * 128 * 2);
    unsigned short* hbA = (unsigned short*)alloc((size_t)EE * 64 * 2);
    unsigned short* hbB = (unsigned short*)alloc((size_t)EE * 64 * 2);

    int C = 16;
    if (off + (size_t)(EE / 4) * 512 * 2 + 4096 <= ws_size) C = 4;
    else if (off + (size_t)(EE / 8) * 512 * 2 + 4096 <= ws_size) C = 8;
    const int EC = EE / C;
    unsigned short* wbuf = (unsigned short*)alloc((size_t)EC * 512 * 2);

    const float inv16 = 1.0f / 16.0f;
    const float one = 1.0f;

    hipMemsetAsync(deg, 0, (size_t)NN * 4, stream);
    hipMemsetAsync(A_s, 0, (size_t)NN * CC * 4, stream);
    hipMemsetAsync(A_v, 0, (size_t)NN * 3 * CC * 4, stream);

    // weight prep
    k_wprep<<<cdiv(64 * 32, 256), 256, 0, stream>>>(Wr1_1, W1t_l1, 8, 64, 32);
    k_wprep<<<cdiv(64 * 64, 256), 256, 0, stream>>>(Wr1_2, W2t_l1, 64, 64, 64);
    k_wprep<<<cdiv(64 * 64, 256), 256, 0, stream>>>(Wr1_3, W3t_l1, 64, 64, 64);
    k_wprep<<<cdiv(256 * 64, 256), 256, 0, stream>>>(Wr1_o, Wot_l1, 64, 256, 64);
    k_wprep<<<cdiv(64 * 32, 256), 256, 0, stream>>>(Wr2_1, W1t_l2, 8, 64, 32);
    k_wprep<<<cdiv(64 * 64, 256), 256, 0, stream>>>(Wr2_2, W2t_l2, 64, 64, 64);
    k_wprep<<<cdiv(64 * 64, 256), 256, 0, stream>>>(Wr2_3, W3t_l2, 64, 64, 64);
    k_wprep<<<cdiv(512 * 64, 256), 256, 0, stream>>>(Wr2_o, Wot_l2, 64, 512, 64);
    {
        WP10 wp;
        const float* srcs[10] = {W_up1, Wlin1_s, Wlin1_v, Lp1_s, Lp1_v,
                                 Wup2_s, Wup2_v, Wlin2_s, Wlin2_v, Lp2_v};
        for (int m = 0; m < 10; ++m) { wp.s[m] = srcs[m]; wp.d[m] = Wn[m]; }
        k_wprep10<<<dim3(cdiv(128 * 128, 256), 10), 256, 0, stream>>>(wp);
    }

    // ---- CSR build + permuted geometry ----
    k_count<<<cdiv(EE, 256), 256, 0, stream>>>(rcv, deg);
    k_scan<<<1, 256, 0, stream>>>(deg, rowptr, cursor);
    k_fill<<<cdiv(EE, 256), 256, 0, stream>>>(rcv, cursor, perm);
    k_sortwave<<<cdiv(NN * 64, 256), 256, 0, stream>>>(rowptr, perm);
    k_geom_perm<<<cdiv(EE, 256), 256, 0, stream>>>(positions, shifts, snd, rcv, perm, Yv, efb, psnd);

    k_species<<<cdiv(NN, 256), 256, 0, stream>>>(node_attrs, species);
    k_embed<<<cdiv(NN * CC, 256), 256, 0, stream>>>(W_emb, species, hbuf);
    k_rmix<<<1, CC, 0, stream>>>(Rmid, Rout, rmix);

    // hu = h @ W_up1 (MFMA)
    mfma_gemm_f32<128, 128, 0><<<cdiv(NN, 64), 256, 0, stream>>>(
        hbuf, 128, Wn[0], hu, 128, NN, one);

    // ---- layer 1: MFMA edge MLP -> chunked wgemm + gather ----
    mfma_gemm<32, 64, 1><<<cdiv(EE, 64), 256, 0, stream>>>(efb, 32, W1t_l1, hbA, 64, EE);
    mfma_gemm<64, 64, 1><<<cdiv(EE, 64), 256, 0, stream>>>(hbA, 64, W2t_l1, hbB, 64, EE);
    mfma_gemm<64, 64, 1><<<cdiv(EE, 64), 256, 0, stream>>>(hbB, 64, W3t_l1, hbA, 64, EE);
    for (int ch = 0; ch < C; ++ch) {
        int e0 = ch * EC, e1 = e0 + EC;
        mfma_gemm<64, 128, 2><<<dim3(cdiv(EC, 64), 2), 256, 0, stream>>>(
            hbA + (size_t)e0 * 64, 64, Wot_l1, wbuf, 256, EC);
        k_gather1<<<NN / 2, 256, 0, stream>>>(
            rowptr, psnd, Yv, wbuf, e0, e1, hu, A_s, A_v);
    }

    // ---- layer 1 node side (MFMA) ----
    mfma_gemm_f32<128, 128, 0><<<cdiv(NN, 64), 256, 0, stream>>>(
        A_s, 128, Wn[1], A_s, 128, NN, inv16);
    mfma_gemm_f32<128, 128, 0><<<cdiv(3 * NN, 64), 256, 0, stream>>>(
        A_v, 128, Wn[2], A_v, 128, 3 * NN, inv16);
    k_B1<<<cdiv(NN * CC, 256), 256, 0, stream>>>(
        species, A_s, A_v, P1_s1, P1_ss, P1_vv, P1_v1, P1_sv, hbuf /*Bs*/, A_v /*Bv*/);
    mfma_gemm_f32<128, 128, 0><<<cdiv(NN, 64), 256, 0, stream>>>(
        hbuf, 128, Wn[3], hu /*h_s*/, 128, NN, one);
    mfma_gemm_f32<128, 128, 0><<<cdiv(3 * NN, 64), 256, 0, stream>>>(
        A_v /*Bv*/, 128, Wn[4], h_v, 128, 3 * NN, one);
    k_dip1<<<NN, 64, 0, stream>>>(h_v, R1, dip1);
    mfma_gemm_f32<128, 128, 0><<<cdiv(NN, 64), 256, 0, stream>>>(
        hu /*h_s*/, 128, Wn[5], hbuf /*hs*/, 128, NN, one);
    mfma_gemm_f32<128, 128, 0><<<cdiv(3 * NN, 64), 256, 0, stream>>>(
        h_v, 128, Wn[6], hv, 128, 3 * NN, one);

    // ---- layer 2: MFMA edge MLP -> chunked wgemm + merged gather ----
    hipMemsetAsync(A_s, 0, (size_t)NN * CC * 4, stream);
    hipMemsetAsync(A_v, 0, (size_t)NN * 3 * CC * 4, stream);
    mfma_gemm<32, 64, 1><<<cdiv(EE, 64), 256, 0, stream>>>(efb, 32, W1t_l2, hbA, 64, EE);
    mfma_gemm<64, 64, 1><<<cdiv(EE, 64), 256, 0, stream>>>(hbA, 64, W2t_l2, hbB, 64, EE);
    mfma_gemm<64, 64, 1><<<cdiv(EE, 64), 256, 0, stream>>>(hbB, 64, W3t_l2, hbA, 64, EE);
    for (int ch = 0; ch < C; ++ch) {
        int e0 = ch * EC, e1 = e0 + EC;
        mfma_gemm<64, 128, 2><<<dim3(cdiv(EC, 64), 4), 256, 0, stream>>>(
            hbA + (size_t)e0 * 64, 64, Wot_l2, wbuf, 512, EC);
        k_gather23<<<NN / 2, 256, 0, stream>>>(
            rowptr, psnd, Yv, wbuf, e0, e1, hbuf /*hs*/, hv, A_s, A_v);
    }

    // ---- layer 2 node side (MFMA) ----
    mfma_gemm_f32<128, 128, 0><<<cdiv(NN, 64), 256, 0, stream>>>(
        A_s, 128, Wn[7], A_s, 128, NN, inv16);
    mfma_gemm_f32<128, 128, 0><<<cdiv(3 * NN, 64), 256, 0, stream>>>(
        A_v, 128, Wn[8], A_v, 128, 3 * NN, inv16);
    k_sc<<<NN, 128, 0, stream>>>(species, h_v, Wsk, h2v);
    k_B2<<<cdiv(NN * CC, 256), 256, 0, stream>>>(species, A_s, A_v, P2_v1, P2_sv, A_v /*B2v*/);
    mfma_gemm_f32<128, 128, 6><<<cdiv(3 * NN, 64), 256, 0, stream>>>(
        A_v /*B2v*/, 128, Wn[9], h2v, 128, 3 * NN, one);

    k_node_out<<<NN, 64, 0, stream>>>(h2v, rmix, dip1, charges, positions, out, tot);
    k_greduce<<<NGR, 256, 0, stream>>>(tot, batch, out);
}

// Round 14
// 530.004 us; speedup vs baseline: 4.1766x; 1.1596x over previous
//
#include <hip/hip_runtime.h>

#define NN 10000
#define EE 160000
#define CC 128
#define NEL 10
#define NGR 16

static inline int cdiv(int a, int b) { return (a + b - 1) / b; }

__device__ __forceinline__ float silu_f(float x) { return x / (1.0f + __expf(-x)); }

__device__ __forceinline__ float bf2f(unsigned short u) {
    unsigned int x = ((unsigned int)u) << 16;
    return __uint_as_float(x);
}
__device__ __forceinline__ unsigned short f2bf(float f) {
    unsigned int x = __float_as_uint(f);
    unsigned int r = x + 0x7fffu + ((x >> 16) & 1u);
    return (unsigned short)(r >> 16);
}

typedef __attribute__((ext_vector_type(8))) short bf16x8;
typedef __attribute__((ext_vector_type(4))) float f32x4;

// ---------------------------------------------------------------------------
// MFMA GEMM bf16->bf16 (edge MLP). Wt pre-transposed bf16 [Ntot][K].
// MODE 1: silu, 2: plain. LDS XOR swizzle (row&7)<<4; m89 fragment layout.
// ---------------------------------------------------------------------------
template <int K, int N, int MODE>
__global__ __launch_bounds__(256) void mfma_gemm(
    const unsigned short* __restrict__ in, int in_ld,
    const unsigned short* __restrict__ Wt,
    unsigned short* __restrict__ out, int out_ld,
    int R)
{
    constexpr int NT = N / 16;
    constexpr int KC = K / 32;
    constexpr int CPR = K / 8;
    __shared__ __align__(16) unsigned short Ash[64 * K];
    __shared__ __align__(16) unsigned short Bsh[N * K];

    const int tid = threadIdx.x;
    const int w = tid >> 6;
    const int l = tid & 63;
    const int row0 = blockIdx.x * 64;
    const int cb = blockIdx.y * N;

    for (int cid = tid; cid < 64 * CPR; cid += 256) {
        int r = cid / CPR, k8 = cid % CPR;
        int row = row0 + r;
        uint4 val = make_uint4(0u, 0u, 0u, 0u);
        if (row < R) val = *(const uint4*)(in + (size_t)row * in_ld + k8 * 8);
        unsigned bo = ((unsigned)(r * K + k8 * 8) * 2u) ^ (((unsigned)(r & 7)) << 4);
        *(uint4*)((char*)Ash + bo) = val;
    }
    for (int cid = tid; cid < N * CPR; cid += 256) {
        int nn = cid / CPR, k8 = cid % CPR;
        uint4 val = *(const uint4*)(Wt + (size_t)(cb + nn) * K + k8 * 8);
        unsigned bo = ((unsigned)(nn * K + k8 * 8) * 2u) ^ (((unsigned)(nn & 7)) << 4);
        *(uint4*)((char*)Bsh + bo) = val;
    }
    __syncthreads();

    bf16x8 afr[KC];
#pragma unroll
    for (int kc = 0; kc < KC; ++kc) {
        int r = w * 16 + (l & 15);
        int k = kc * 32 + (l >> 4) * 8;
        unsigned bo = ((unsigned)(r * K + k) * 2u) ^ (((unsigned)(r & 7)) << 4);
        afr[kc] = *(const bf16x8*)((char*)Ash + bo);
    }

    f32x4 acc[NT];
#pragma unroll
    for (int nt = 0; nt < NT; ++nt) {
        acc[nt] = (f32x4){0.f, 0.f, 0.f, 0.f};
#pragma unroll
        for (int kc = 0; kc < KC; ++kc) {
            int col = nt * 16 + (l & 15);
            int k = kc * 32 + (l >> 4) * 8;
            unsigned bo = ((unsigned)(col * K + k) * 2u) ^ (((unsigned)(col & 7)) << 4);
            bf16x8 bfr = *(const bf16x8*)((char*)Bsh + bo);
            acc[nt] = __builtin_amdgcn_mfma_f32_16x16x32_bf16(afr[kc], bfr, acc[nt], 0, 0, 0);
        }
    }

#pragma unroll
    for (int nt = 0; nt < NT; ++nt) {
#pragma unroll
        for (int rg = 0; rg < 4; ++rg) {
            int row = row0 + w * 16 + (l >> 4) * 4 + rg;
            if (row < R) {
                int col = cb + nt * 16 + (l & 15);
                float v = acc[nt][rg];
                if constexpr (MODE == 1) v = silu_f(v);
                out[(size_t)row * out_ld + col] = f2bf(v);
            }
        }
    }
}

// ---------------------------------------------------------------------------
// MFMA GEMM fp32 in (converted to bf16 at stage): MODE 0 f32 store,
// 2: bf16 store, 6: f32 accumulate.
// ---------------------------------------------------------------------------
template <int K, int N, int MODE>
__global__ __launch_bounds__(256) void mfma_gemm_f32(
    const float* __restrict__ in, int in_ld,
    const unsigned short* __restrict__ Wt,
    float* __restrict__ out, int out_ld,
    int R, float scale)
{
    constexpr int NT = N / 16;
    constexpr int KC = K / 32;
    constexpr int CPR = K / 8;
    __shared__ __align__(16) unsigned short Ash[64 * K];
    __shared__ __align__(16) unsigned short Bsh[N * K];

    const int tid = threadIdx.x;
    const int w = tid >> 6;
    const int l = tid & 63;
    const int row0 = blockIdx.x * 64;
    const int cb = blockIdx.y * N;

    for (int cid = tid; cid < 64 * CPR; cid += 256) {
        int r = cid / CPR, k8 = cid % CPR;
        int row = row0 + r;
        union { unsigned short u16[8]; uint4 v; } pk;
        if (row < R) {
            const float* p = in + (size_t)row * in_ld + k8 * 8;
            float4 f0 = *(const float4*)p;
            float4 f1 = *(const float4*)(p + 4);
            pk.u16[0] = f2bf(f0.x); pk.u16[1] = f2bf(f0.y);
            pk.u16[2] = f2bf(f0.z); pk.u16[3] = f2bf(f0.w);
            pk.u16[4] = f2bf(f1.x); pk.u16[5] = f2bf(f1.y);
            pk.u16[6] = f2bf(f1.z); pk.u16[7] = f2bf(f1.w);
        } else {
            pk.v = make_uint4(0u, 0u, 0u, 0u);
        }
        unsigned bo = ((unsigned)(r * K + k8 * 8) * 2u) ^ (((unsigned)(r & 7)) << 4);
        *(uint4*)((char*)Ash + bo) = pk.v;
    }
    for (int cid = tid; cid < N * CPR; cid += 256) {
        int nn = cid / CPR, k8 = cid % CPR;
        uint4 val = *(const uint4*)(Wt + (size_t)(cb + nn) * K + k8 * 8);
        unsigned bo = ((unsigned)(nn * K + k8 * 8) * 2u) ^ (((unsigned)(nn & 7)) << 4);
        *(uint4*)((char*)Bsh + bo) = val;
    }
    __syncthreads();

    bf16x8 afr[KC];
#pragma unroll
    for (int kc = 0; kc < KC; ++kc) {
        int r = w * 16 + (l & 15);
        int k = kc * 32 + (l >> 4) * 8;
        unsigned bo = ((unsigned)(r * K + k) * 2u) ^ (((unsigned)(r & 7)) << 4);
        afr[kc] = *(const bf16x8*)((char*)Ash + bo);
    }

    f32x4 acc[NT];
#pragma unroll
    for (int nt = 0; nt < NT; ++nt) {
        acc[nt] = (f32x4){0.f, 0.f, 0.f, 0.f};
#pragma unroll
        for (int kc = 0; kc < KC; ++kc) {
            int col = nt * 16 + (l & 15);
            int k = kc * 32 + (l >> 4) * 8;
            unsigned bo = ((unsigned)(col * K + k) * 2u) ^ (((unsigned)(col & 7)) << 4);
            bf16x8 bfr = *(const bf16x8*)((char*)Bsh + bo);
            acc[nt] = __builtin_amdgcn_mfma_f32_16x16x32_bf16(afr[kc], bfr, acc[nt], 0, 0, 0);
        }
    }

#pragma unroll
    for (int nt = 0; nt < NT; ++nt) {
#pragma unroll
        for (int rg = 0; rg < 4; ++rg) {
            int row = row0 + w * 16 + (l >> 4) * 4 + rg;
            if (row < R) {
                int col = cb + nt * 16 + (l & 15);
                float v = acc[nt][rg] * scale;
                size_t idx = (size_t)row * out_ld + col;
                if constexpr (MODE == 6)      out[idx] += v;
                else if constexpr (MODE == 2) ((unsigned short*)out)[idx] = f2bf(v);
                else                          out[idx] = v;
            }
        }
    }
}

// batched edge-weight prep: dst[n][k] = src[k][n] bf16, zero-pad k>=K
struct WPE { const float* s[8]; unsigned short* d[8]; int K[8], N[8], Kp[8]; };
__global__ void k_wprepE(WPE wp)
{
    int m = blockIdx.y;
    int i = blockIdx.x * 256 + threadIdx.x;
    int tot = wp.N[m] * wp.Kp[m];
    if (i >= tot) return;
    int n = i / wp.Kp[m], k = i % wp.Kp[m];
    wp.d[m][i] = (k < wp.K[m]) ? f2bf(wp.s[m][k * wp.N[m] + n]) : (unsigned short)0;
}

struct WP10 { const float* s[10]; unsigned short* d[10]; };
__global__ void k_wprep10(WP10 wp)
{
    int m = blockIdx.y;
    int i = blockIdx.x * 256 + threadIdx.x;
    if (i >= 128 * 128) return;
    int n = i / 128, k = i % 128;
    wp.d[m][i] = f2bf(wp.s[m][k * 128 + n]);
}

// ---------------------------------------------------------------------------
// CSR build
// ---------------------------------------------------------------------------
__global__ void k_count(const int* __restrict__ rcv, int* __restrict__ deg)
{
    int e = blockIdx.x * 256 + threadIdx.x;
    if (e < EE) atomicAdd(&deg[rcv[e]], 1);
}

__global__ __launch_bounds__(256) void k_scan(const int* __restrict__ deg,
                                              int* __restrict__ rowptr,
                                              int* __restrict__ cursor)
{
    __shared__ int part[256];
    const int t = threadIdx.x;
    const int PER = (NN + 255) / 256;
    int base = t * PER;
    int s = 0;
    for (int j = 0; j < PER; ++j) { int idx = base + j; if (idx < NN) s += deg[idx]; }
    part[t] = s;
    __syncthreads();
    for (int off = 1; off < 256; off <<= 1) {
        int v = (t >= off) ? part[t - off] : 0;
        __syncthreads();
        part[t] += v;
        __syncthreads();
    }
    int run = (t == 0) ? 0 : part[t - 1];
    for (int j = 0; j < PER; ++j) {
        int idx = base + j;
        if (idx < NN) { rowptr[idx] = run; cursor[idx] = run; run += deg[idx]; }
    }
    if (t == 255) rowptr[NN] = part[255];
}

__global__ void k_fill(const int* __restrict__ rcv, int* __restrict__ cursor,
                       int* __restrict__ perm)
{
    int e = blockIdx.x * 256 + threadIdx.x;
    if (e >= EE) return;
    int pos = atomicAdd(&cursor[rcv[e]], 1);
    perm[pos] = e;
}

__global__ __launch_bounds__(256) void k_sortwave(const int* __restrict__ rowptr,
                                                  int* __restrict__ perm)
{
    int gid = blockIdx.x * 256 + threadIdx.x;
    int wid = gid >> 6;
    int lane = gid & 63;
    if (wid >= NN) return;
    int a = rowptr[wid], b = rowptr[wid + 1];
    int d = b - a;
    if (d <= 1) return;
    if (d <= 64) {
        int v = (lane < d) ? perm[a + lane] : 0x7fffffff;
        int rank = 0;
        for (int j = 0; j < 64; ++j) {
            int vj = __shfl(v, j);
            if (j < d && vj < v) ++rank;
        }
        if (lane < d) perm[a + rank] = v;
    } else if (lane == 0) {
        for (int i = a + 1; i < b; ++i) {
            int v = perm[i]; int j = i - 1;
            while (j >= a && perm[j] > v) { perm[j + 1] = perm[j]; --j; }
            perm[j + 1] = v;
        }
    }
}

// geometry in CSR order; ef as bf16 [EE][32] zero-padded
__global__ void k_geom_perm(const float* __restrict__ pos, const float* __restrict__ shifts,
                            const int* __restrict__ snd, const int* __restrict__ rcv,
                            const int* __restrict__ perm,
                            float* __restrict__ Yv, unsigned short* __restrict__ efb,
                            int* __restrict__ psnd)
{
    int i = blockIdx.x * 256 + threadIdx.x;
    if (i >= EE) return;
    int e = perm[i];
    int s = snd[e], r = rcv[e];
    psnd[i] = s;
    float vx = pos[r * 3 + 0] - pos[s * 3 + 0] + shifts[e * 3 + 0];
    float vy = pos[r * 3 + 1] - pos[s * 3 + 1] + shifts[e * 3 + 1];
    float vz = pos[r * 3 + 2] - pos[s * 3 + 2] + shifts[e * 3 + 2];
    float len = sqrtf(vx * vx + vy * vy + vz * vz + 1e-12f);
    float inv = 1.0f / len;
    const float SQ3 = 1.7320508075688772f;
    Yv[i * 3 + 0] = SQ3 * vx * inv;
    Yv[i * 3 + 1] = SQ3 * vy * inv;
    Yv[i * 3 + 2] = SQ3 * vz * inv;
    float u = len * 0.2f;
    float fc = 0.0f;
    if (u < 1.0f) {
        float u2 = u * u, u4 = u2 * u2, u5 = u4 * u, u6 = u5 * u, u7 = u6 * u;
        fc = 1.0f - 21.0f * u5 + 35.0f * u6 - 15.0f * u7;
    }
    float pref = 0.6324555320336759f * inv * fc;
    const float PIO5 = 0.6283185307179586f;
    union { unsigned short u16[8]; uint4 v; } pk;
#pragma unroll
    for (int n = 1; n <= 8; ++n)
        pk.u16[n - 1] = f2bf(pref * sinf((float)n * PIO5 * len));
    uint4* dst = (uint4*)(efb + (size_t)i * 32);
    dst[0] = pk.v;
    dst[1] = make_uint4(0u, 0u, 0u, 0u);
    dst[2] = make_uint4(0u, 0u, 0u, 0u);
    dst[3] = make_uint4(0u, 0u, 0u, 0u);
}

// ---------------------------------------------------------------------------
// gathers: coalesced bf16 wb + random bf16 payload rows
// ---------------------------------------------------------------------------
__global__ __launch_bounds__(256) void k_gather1(
    const int* __restrict__ rowptr, const int* __restrict__ psnd,
    const float* __restrict__ Yv, const unsigned short* __restrict__ wb,
    int e0, int e1,
    const unsigned short* __restrict__ gS,
    float* __restrict__ outS, float* __restrict__ outV)
{
    const int t = threadIdx.x;
    const int c = t & 127;
    const int n = blockIdx.x * 2 + (t >> 7);
    if (n >= NN) return;
    int rs = rowptr[n], re = rowptr[n + 1];
    if (rs < e0) rs = e0;
    if (re > e1) re = e1;
    if (rs >= re) return;
    float accs = 0.f, a0 = 0.f, a1 = 0.f, a2 = 0.f;
    for (int i = rs; i < re; ++i) {
        const unsigned short* wp = wb + (size_t)(i - e0) * 256;
        float wss = bf2f(wp[c]);
        float wsv = bf2f(wp[128 + c]);
        float h = bf2f(gS[psnd[i] * 128 + c]);
        float y0 = Yv[i * 3], y1 = Yv[i * 3 + 1], y2 = Yv[i * 3 + 2];
        accs = fmaf(wss, h, accs);
        float tv = wsv * h;
        a0 = fmaf(tv, y0, a0); a1 = fmaf(tv, y1, a1); a2 = fmaf(tv, y2, a2);
    }
    outS[n * 128 + c] += accs;
    outV[n * 384 + c]       += a0;
    outV[n * 384 + 128 + c] += a1;
    outV[n * 384 + 256 + c] += a2;
}

__global__ __launch_bounds__(256) void k_gather23(
    const int* __restrict__ rowptr, const int* __restrict__ psnd,
    const float* __restrict__ Yv, const unsigned short* __restrict__ wb,
    int e0, int e1,
    const unsigned short* __restrict__ gS, const unsigned short* __restrict__ gV,
    float* __restrict__ outS, float* __restrict__ outV)
{
    const int t = threadIdx.x;
    const int c = t & 127;
    const int n = blockIdx.x * 2 + (t >> 7);
    if (n >= NN) return;
    int rs = rowptr[n], re = rowptr[n + 1];
    if (rs < e0) rs = e0;
    if (re > e1) re = e1;
    if (rs >= re) return;
    float accs = 0.f, a0 = 0.f, a1 = 0.f, a2 = 0.f;
    for (int i = rs; i < re; ++i) {
        const unsigned short* wp = wb + (size_t)(i - e0) * 512;
        float wa = bf2f(wp[c]);
        float wbv = bf2f(wp[128 + c]);
        float wc = bf2f(wp[256 + c]);
        float wd = bf2f(wp[384 + c]);
        int s = psnd[i];
        float hs = bf2f(gS[s * 128 + c]);
        float v0 = bf2f(gV[s * 384 + c]);
        float v1 = bf2f(gV[s * 384 + 128 + c]);
        float v2 = bf2f(gV[s * 384 + 256 + c]);
        float y0 = Yv[i * 3], y1 = Yv[i * 3 + 1], y2 = Yv[i * 3 + 2];
        float hd = v0 * y0 + v1 * y1 + v2 * y2;
        accs = fmaf(wa, hs, accs);
        accs = fmaf(wbv, hd * 0.57735026919f, accs);
        float tv = wc * hs;
        a0 = fmaf(tv, y0, a0); a0 = fmaf(wd, v0, a0);
        a1 = fmaf(tv, y1, a1); a1 = fmaf(wd, v1, a1);
        a2 = fmaf(tv, y2, a2); a2 = fmaf(wd, v2, a2);
    }
    outS[n * 128 + c] += accs;
    outV[n * 384 + c]       += a0;
    outV[n * 384 + 128 + c] += a1;
    outV[n * 384 + 256 + c] += a2;
}

// ---------------------------------------------------------------------------
__global__ void k_species(const float* __restrict__ attrs, int* __restrict__ species)
{
    int n = blockIdx.x * 256 + threadIdx.x;
    if (n >= NN) return;
    int sp = 0;
#pragma unroll
    for (int j = 0; j < NEL; ++j)
        if (attrs[n * NEL + j] > 0.5f) sp = j;
    species[n] = sp;
}

__global__ void k_embed(const float* __restrict__ W_emb, const int* __restrict__ species,
                        float* __restrict__ h)
{
    int t = blockIdx.x * 256 + threadIdx.x;
    if (t >= NN * CC) return;
    int n = t >> 7, c = t & 127;
    h[t] = W_emb[species[n] * CC + c];
}

__global__ void k_rmix(const float* __restrict__ Rmid, const float* __restrict__ Rout,
                       float* __restrict__ rmix)
{
    int c = threadIdx.x;
    float s = 0.f;
#pragma unroll
    for (int k = 0; k < 16; ++k) s = fmaf(Rmid[c * 16 + k], Rout[k], s);
    rmix[c] = s;
}

__global__ void k_B1(const int* __restrict__ species,
                     const float* __restrict__ As_l, const float* __restrict__ Av_l,
                     const float* __restrict__ P_s1, const float* __restrict__ P_ss,
                     const float* __restrict__ P_vv, const float* __restrict__ P_v1,
                     const float* __restrict__ P_sv,
                     float* __restrict__ Bs, float* __restrict__ Bv)
{
    int t = blockIdx.x * 256 + threadIdx.x;
    if (t >= NN * CC) return;
    int n = t >> 7, c = t & 127;
    int sp = species[n];
    int pb = sp * CC + c;
    int vb = n * 384 + c;
    float as = As_l[t];
    float a0 = Av_l[vb], a1 = Av_l[vb + CC], a2 = Av_l[vb + 2 * CC];
    Bs[t] = P_s1[pb] * as + P_ss[pb] * as * as
          + P_vv[pb] * (a0 * a0 + a1 * a1 + a2 * a2) * 0.57735026919f;
    float tv = P_v1[pb] + P_sv[pb] * as;
    Bv[vb] = tv * a0; Bv[vb + CC] = tv * a1; Bv[vb + 2 * CC] = tv * a2;
}

__global__ void k_B2(const int* __restrict__ species,
                     const float* __restrict__ As_l, const float* __restrict__ Av_l,
                     const float* __restrict__ P_v1, const float* __restrict__ P_sv,
                     float* __restrict__ Bv)
{
    int t = blockIdx.x * 256 + threadIdx.x;
    if (t >= NN * CC) return;
    int n = t >> 7, c = t & 127;
    int sp = species[n];
    int pb = sp * CC + c;
    int vb = n * 384 + c;
    float as = As_l[t];
    float tv = P_v1[pb] + P_sv[pb] * as;
    Bv[vb] = tv * Av_l[vb];
    Bv[vb + CC] = tv * Av_l[vb + CC];
    Bv[vb + 2 * CC] = tv * Av_l[vb + 2 * CC];
}

__global__ void k_dip1(const float* __restrict__ h_v, const float* __restrict__ R1,
                       float* __restrict__ dip1)
{
    int n = blockIdx.x, l = threadIdx.x;
    const float* hb = h_v + n * 384;
#pragma unroll
    for (int d = 0; d < 3; ++d) {
        float v = hb[d * CC + l] * R1[l] + hb[d * CC + 64 + l] * R1[64 + l];
        for (int o = 32; o > 0; o >>= 1) v += __shfl_down(v, o);
        if (l == 0) dip1[n * 3 + d] = v;
    }
}

__global__ void k_sc(const int* __restrict__ species, const float* __restrict__ h_v,
                     const float* __restrict__ Wsk, float* __restrict__ h2v)
{
    int n = blockIdx.x, f = threadIdx.x;
    int sp = species[n];
    const float* Wp = Wsk + sp * (CC * CC);
    const float* hvn = h_v + n * 384;
    float a0 = 0.f, a1 = 0.f, a2 = 0.f;
    for (int c = 0; c < CC; ++c) {
        float w = Wp[c * CC + f];
        a0 = fmaf(hvn[c], w, a0);
        a1 = fmaf(hvn[CC + c], w, a1);
        a2 = fmaf(hvn[2 * CC + c], w, a2);
    }
    h2v[n * 384 + f] = a0;
    h2v[n * 384 + CC + f] = a1;
    h2v[n * 384 + 2 * CC + f] = a2;
}

__global__ void k_node_out(const float* __restrict__ h2v, const float* __restrict__ rmix,
                           const float* __restrict__ dip1,
                           const float* __restrict__ charges, const float* __restrict__ pos,
                           float* __restrict__ out, float* __restrict__ tot)
{
    int n = blockIdx.x, l = threadIdx.x;
    const float* hb = h2v + n * 384;
    float r0 = rmix[l], r1 = rmix[64 + l];
    float red[3];
#pragma unroll
    for (int d = 0; d < 3; ++d) {
        float v = hb[d * CC + l] * r0 + hb[d * CC + 64 + l] * r1;
        for (int o = 32; o > 0; o >>= 1) v += __shfl_down(v, o);
        red[d] = v;
    }
    if (l == 0) {
        float q = charges[n];
#pragma unroll
        for (int d = 0; d < 3; ++d) {
            float a = dip1[n * 3 + d] + 0.5f * red[d];
            out[48 + n * 3 + d] = a;
            tot[n * 3 + d] = a + q * pos[n * 3 + d];
        }
    }
}

__global__ __launch_bounds__(256) void k_greduce(const float* __restrict__ tot,
                                                 const int* __restrict__ batch,
                                                 float* __restrict__ out)
{
    __shared__ float r[256 * 3];
    const int g = blockIdx.x;
    const int t = threadIdx.x;
    float s0 = 0.f, s1 = 0.f, s2 = 0.f;
    for (int n = t; n < NN; n += 256) {
        if (batch[n] == g) {
            s0 += tot[n * 3]; s1 += tot[n * 3 + 1]; s2 += tot[n * 3 + 2];
        }
    }
    r[t] = s0; r[256 + t] = s1; r[512 + t] = s2;
    __syncthreads();
    for (int off = 128; off > 0; off >>= 1) {
        if (t < off) {
            r[t] += r[t + off];
            r[256 + t] += r[256 + t + off];
            r[512 + t] += r[512 + t + off];
        }
        __syncthreads();
    }
    if (t < 3) out[g * 3 + t] = r[t * 256];
}

// ---------------------------------------------------------------------------
extern "C" void kernel_launch(void* const* d_in, const int* in_sizes, int n_in,
                              void* d_out, int out_size, void* d_ws, size_t ws_size,
                              hipStream_t stream)
{
    const float* positions = (const float*)d_in[0];
    const float* node_attrs = (const float*)d_in[1];
    const float* charges = (const float*)d_in[2];
    const float* shifts = (const float*)d_in[3];
    const int*   eidx = (const int*)d_in[4];
    const int*   batch = (const int*)d_in[5];
    const float* W_emb  = (const float*)d_in[7];
    const float* W_up1  = (const float*)d_in[8];
    const float* Wr1_1  = (const float*)d_in[9];
    const float* Wr1_2  = (const float*)d_in[10];
    const float* Wr1_3  = (const float*)d_in[11];
    const float* Wr1_o  = (const float*)d_in[12];
    const float* Wlin1_s = (const float*)d_in[13];
    const float* Wlin1_v = (const float*)d_in[14];
    const float* P1_s1 = (const float*)d_in[15];
    const float* P1_ss = (const float*)d_in[16];
    const float* P1_vv = (const float*)d_in[17];
    const float* P1_v1 = (const float*)d_in[18];
    const float* P1_sv = (const float*)d_in[19];
    const float* Lp1_s = (const float*)d_in[20];
    const float* Lp1_v = (const float*)d_in[21];
    const float* R1    = (const float*)d_in[22];
    const float* Wsk   = (const float*)d_in[23];
    const float* Wup2_s = (const float*)d_in[24];
    const float* Wup2_v = (const float*)d_in[25];
    const float* Wr2_1 = (const float*)d_in[26];
    const float* Wr2_2 = (const float*)d_in[27];
    const float* Wr2_3 = (const float*)d_in[28];
    const float* Wr2_o = (const float*)d_in[29];
    const float* Wlin2_s = (const float*)d_in[30];
    const float* Wlin2_v = (const float*)d_in[31];
    const float* P2_v1 = (const float*)d_in[32];
    const float* P2_sv = (const float*)d_in[33];
    const float* Lp2_v = (const float*)d_in[34];
    const float* Rmid  = (const float*)d_in[35];
    const float* Rout  = (const float*)d_in[36];
    (void)in_sizes; (void)n_in; (void)out_size;

    const int* snd = eidx;
    const int* rcv = eidx + EE;
    float* out = (float*)d_out;

    char* ws = (char*)d_ws;
    size_t off = 0;
    auto alloc = [&](size_t bytes) -> void* {
        void* p = (void*)(ws + off);
        off = (off + bytes + 255) & ~(size_t)255;
        return p;
    };
    int*   species = (int*)alloc((size_t)NN * 4);
    int*   deg     = (int*)alloc((size_t)NN * 4);
    int*   rowptr  = (int*)alloc((size_t)(NN + 16) * 4);
    int*   cursor  = (int*)alloc((size_t)NN * 4);
    int*   perm    = (int*)alloc((size_t)EE * 4);
    int*   psnd    = (int*)alloc((size_t)EE * 4);
    float* Yv   = (float*)alloc((size_t)EE * 3 * 4);
    unsigned short* efb = (unsigned short*)alloc((size_t)EE * 32 * 2);
    float* A_s  = (float*)alloc((size_t)NN * CC * 4);
    float* A_v  = (float*)alloc((size_t)NN * 3 * CC * 4);
    float* hbuf = (float*)alloc((size_t)NN * CC * 4);
    float* hu   = (float*)alloc((size_t)NN * CC * 4);      // h_s (f32)
    float* h_v  = (float*)alloc((size_t)NN * 3 * CC * 4);
    float* h2v  = (float*)alloc((size_t)NN * 3 * CC * 4);
    float* dip1 = (float*)alloc((size_t)NN * 3 * 4);
    float* rmix = (float*)alloc((size_t)CC * 4);
    float* tot  = (float*)alloc((size_t)NN * 3 * 4);
    // bf16 gather payloads
    unsigned short* hub = (unsigned short*)alloc((size_t)NN * CC * 2);
    unsigned short* hsb = (unsigned short*)alloc((size_t)NN * CC * 2);
    unsigned short* hvb = (unsigned short*)alloc((size_t)NN * 3 * CC * 2);
    // bf16 transposed edge weights
    unsigned short* W1t_l1 = (unsigned short*)alloc(64 * 32 * 2);
    unsigned short* W2t_l1 = (unsigned short*)alloc(64 * 64 * 2);
    unsigned short* W3t_l1 = (unsigned short*)alloc(64 * 64 * 2);
    unsigned short* Wot_l1 = (unsigned short*)alloc(256 * 64 * 2);
    unsigned short* W1t_l2 = (unsigned short*)alloc(64 * 32 * 2);
    unsigned short* W2t_l2 = (unsigned short*)alloc(64 * 64 * 2);
    unsigned short* W3t_l2 = (unsigned short*)alloc(64 * 64 * 2);
    unsigned short* Wot_l2 = (unsigned short*)alloc(512 * 64 * 2);
    // bf16 transposed node weights
    unsigned short* Wn[10];
    for (int m = 0; m < 10; ++m) Wn[m] = (unsigned short*)alloc(128 * 128 * 2);
    unsigned short* hbA = (unsigned short*)alloc((size_t)EE * 64 * 2);
    unsigned short* hbB = (unsigned short*)alloc((size_t)EE * 64 * 2);

    int C = 16;
    if      (off + (size_t)EE * 512 * 2 + 4096 <= ws_size)        C = 1;
    else if (off + (size_t)(EE / 2) * 512 * 2 + 4096 <= ws_size)  C = 2;
    else if (off + (size_t)(EE / 4) * 512 * 2 + 4096 <= ws_size)  C = 4;
    else if (off + (size_t)(EE / 8) * 512 * 2 + 4096 <= ws_size)  C = 8;
    const int EC = EE / C;
    unsigned short* wbuf = (unsigned short*)alloc((size_t)EC * 512 * 2);

    const float inv16 = 1.0f / 16.0f;
    const float one = 1.0f;

    hipMemsetAsync(deg, 0, (size_t)NN * 4, stream);
    hipMemsetAsync(A_s, 0, (size_t)NN * CC * 4, stream);
    hipMemsetAsync(A_v, 0, (size_t)NN * 3 * CC * 4, stream);

    // weight prep (2 dispatches)
    {
        WPE wp;
        const float* s[8] = {Wr1_1, Wr1_2, Wr1_3, Wr1_o, Wr2_1, Wr2_2, Wr2_3, Wr2_o};
        unsigned short* d[8] = {W1t_l1, W2t_l1, W3t_l1, Wot_l1, W1t_l2, W2t_l2, W3t_l2, Wot_l2};
        int Ks[8] = {8, 64, 64, 64, 8, 64, 64, 64};
        int Ns[8] = {64, 64, 64, 256, 64, 64, 64, 512};
        int Kp[8] = {32, 64, 64, 64, 32, 64, 64, 64};
        for (int m = 0; m < 8; ++m) { wp.s[m] = s[m]; wp.d[m] = d[m]; wp.K[m] = Ks[m]; wp.N[m] = Ns[m]; wp.Kp[m] = Kp[m]; }
        k_wprepE<<<dim3(cdiv(512 * 64, 256), 8), 256, 0, stream>>>(wp);
    }
    {
        WP10 wp;
        const float* srcs[10] = {W_up1, Wlin1_s, Wlin1_v, Lp1_s, Lp1_v,
                                 Wup2_s, Wup2_v, Wlin2_s, Wlin2_v, Lp2_v};
        for (int m = 0; m < 10; ++m) { wp.s[m] = srcs[m]; wp.d[m] = Wn[m]; }
        k_wprep10<<<dim3(cdiv(128 * 128, 256), 10), 256, 0, stream>>>(wp);
    }

    // ---- CSR build + permuted geometry ----
    k_count<<<cdiv(EE, 256), 256, 0, stream>>>(rcv, deg);
    k_scan<<<1, 256, 0, stream>>>(deg, rowptr, cursor);
    k_fill<<<cdiv(EE, 256), 256, 0, stream>>>(rcv, cursor, perm);
    k_sortwave<<<cdiv(NN * 64, 256), 256, 0, stream>>>(rowptr, perm);
    k_geom_perm<<<cdiv(EE, 256), 256, 0, stream>>>(positions, shifts, snd, rcv, perm, Yv, efb, psnd);

    k_species<<<cdiv(NN, 256), 256, 0, stream>>>(node_attrs, species);
    k_embed<<<cdiv(NN * CC, 256), 256, 0, stream>>>(W_emb, species, hbuf);
    k_rmix<<<1, CC, 0, stream>>>(Rmid, Rout, rmix);

    // hu payload (bf16) = h @ W_up1
    mfma_gemm_f32<128, 128, 2><<<cdiv(NN, 64), 256, 0, stream>>>(
        hbuf, 128, Wn[0], (float*)hub, 128, NN, one);

    // ---- layer 1: MFMA edge MLP -> chunked wgemm + gather ----
    mfma_gemm<32, 64, 1><<<cdiv(EE, 64), 256, 0, stream>>>(efb, 32, W1t_l1, hbA, 64, EE);
    mfma_gemm<64, 64, 1><<<cdiv(EE, 64), 256, 0, stream>>>(hbA, 64, W2t_l1, hbB, 64, EE);
    mfma_gemm<64, 64, 1><<<cdiv(EE, 64), 256, 0, stream>>>(hbB, 64, W3t_l1, hbA, 64, EE);
    for (int ch = 0; ch < C; ++ch) {
        int e0 = ch * EC, e1 = e0 + EC;
        mfma_gemm<64, 128, 2><<<dim3(cdiv(EC, 64), 2), 256, 0, stream>>>(
            hbA + (size_t)e0 * 64, 64, Wot_l1, wbuf, 256, EC);
        k_gather1<<<NN / 2, 256, 0, stream>>>(
            rowptr, psnd, Yv, wbuf, e0, e1, hub, A_s, A_v);
    }

    // ---- layer 1 node side (MFMA) ----
    mfma_gemm_f32<128, 128, 0><<<cdiv(NN, 64), 256, 0, stream>>>(
        A_s, 128, Wn[1], A_s, 128, NN, inv16);
    mfma_gemm_f32<128, 128, 0><<<cdiv(3 * NN, 64), 256, 0, stream>>>(
        A_v, 128, Wn[2], A_v, 128, 3 * NN, inv16);
    k_B1<<<cdiv(NN * CC, 256), 256, 0, stream>>>(
        species, A_s, A_v, P1_s1, P1_ss, P1_vv, P1_v1, P1_sv, hbuf /*Bs*/, A_v /*Bv*/);
    mfma_gemm_f32<128, 128, 0><<<cdiv(NN, 64), 256, 0, stream>>>(
        hbuf, 128, Wn[3], hu /*h_s*/, 128, NN, one);
    mfma_gemm_f32<128, 128, 0><<<cdiv(3 * NN, 64), 256, 0, stream>>>(
        A_v /*Bv*/, 128, Wn[4], h_v, 128, 3 * NN, one);
    k_dip1<<<NN, 64, 0, stream>>>(h_v, R1, dip1);
    mfma_gemm_f32<128, 128, 2><<<cdiv(NN, 64), 256, 0, stream>>>(
        hu /*h_s*/, 128, Wn[5], (float*)hsb, 128, NN, one);
    mfma_gemm_f32<128, 128, 2><<<cdiv(3 * NN, 64), 256, 0, stream>>>(
        h_v, 128, Wn[6], (float*)hvb, 128, 3 * NN, one);

    // ---- layer 2: MFMA edge MLP -> chunked wgemm + merged gather ----
    hipMemsetAsync(A_s, 0, (size_t)NN * CC * 4, stream);
    hipMemsetAsync(A_v, 0, (size_t)NN * 3 * CC * 4, stream);
    mfma_gemm<32, 64, 1><<<cdiv(EE, 64), 256, 0, stream>>>(efb, 32, W1t_l2, hbA, 64, EE);
    mfma_gemm<64, 64, 1><<<cdiv(EE, 64), 256, 0, stream>>>(hbA, 64, W2t_l2, hbB, 64, EE);
    mfma_gemm<64, 64, 1><<<cdiv(EE, 64), 256, 0, stream>>>(hbB, 64, W3t_l2, hbA, 64, EE);
    for (int ch = 0; ch < C; ++ch) {
        int e0 = ch * EC, e1 = e0 + EC;
        mfma_gemm<64, 128, 2><<<dim3(cdiv(EC, 64), 4), 256, 0, stream>>>(
            hbA + (size_t)e0 * 64, 64, Wot_l2, wbuf, 512, EC);
        k_gather23<<<NN / 2, 256, 0, stream>>>(
            rowptr, psnd, Yv, wbuf, e0, e1, hsb, hvb, A_s, A_v);
    }

    // ---- layer 2 node side (MFMA) ----
    mfma_gemm_f32<128, 128, 0><<<cdiv(NN, 64), 256, 0, stream>>>(
        A_s, 128, Wn[7], A_s, 128, NN, inv16);
    mfma_gemm_f32<128, 128, 0><<<cdiv(3 * NN, 64), 256, 0, stream>>>(
        A_v, 128, Wn[8], A_v, 128, 3 * NN, inv16);
    k_sc<<<NN, 128, 0, stream>>>(species, h_v, Wsk, h2v);
    k_B2<<<cdiv(NN * CC, 256), 256, 0, stream>>>(species, A_s, A_v, P2_v1, P2_sv, A_v /*B2v*/);
    mfma_gemm_f32<128, 128, 6><<<cdiv(3 * NN, 64), 256, 0, stream>>>(
        A_v /*B2v*/, 128, Wn[9], h2v, 128, 3 * NN, one);

    k_node_out<<<NN, 64, 0, stream>>>(h2v, rmix, dip1, charges, positions, out, tot);
    k_greduce<<<NGR, 256, 0, stream>>>(tot, batch, out);
}

// Round 15
// 500.175 us; speedup vs baseline: 4.4257x; 1.0596x over previous
//
#include <hip/hip_runtime.h>

#define NN 10000
#define EE 160000
#define CC 128
#define NEL 10
#define NGR 16

static inline int cdiv(int a, int b) { return (a + b - 1) / b; }

__device__ __forceinline__ float silu_f(float x) { return x / (1.0f + __expf(-x)); }

__device__ __forceinline__ float bf2f(unsigned short u) {
    unsigned int x = ((unsigned int)u) << 16;
    return __uint_as_float(x);
}
__device__ __forceinline__ unsigned short f2bf(float f) {
    unsigned int x = __float_as_uint(f);
    unsigned int r = x + 0x7fffu + ((x >> 16) & 1u);
    return (unsigned short)(r >> 16);
}

typedef __attribute__((ext_vector_type(8))) short bf16x8;
typedef __attribute__((ext_vector_type(4))) float f32x4;

// ---------------------------------------------------------------------------
// Fused 3-layer edge MLP (bf16): out = silu(silu(silu(in@W1)@W2)@W3)
// All weights + h1/h2 ping-pong live in LDS (40KB/block -> 4 blocks/CU).
// XOR swizzle (row&7)<<4 throughout; m89 fragment layout.
// ---------------------------------------------------------------------------
template <int KIN>
__global__ __launch_bounds__(256) void mfma_mlp3(
    const unsigned short* __restrict__ in,    // [R][KIN]
    const unsigned short* __restrict__ W1t,   // [64][KIN]
    const unsigned short* __restrict__ W2t,   // [64][64]
    const unsigned short* __restrict__ W3t,   // [64][64]
    unsigned short* __restrict__ out, int R)  // [R][64]
{
    __shared__ __align__(16) unsigned short Ash[64 * KIN];
    __shared__ __align__(16) unsigned short W1s[64 * KIN];
    __shared__ __align__(16) unsigned short W2s[64 * 64];
    __shared__ __align__(16) unsigned short W3s[64 * 64];
    __shared__ __align__(16) unsigned short H1[64 * 64];
    __shared__ __align__(16) unsigned short H2[64 * 64];

    const int tid = threadIdx.x;
    const int w = tid >> 6;
    const int l = tid & 63;
    const int row0 = blockIdx.x * 64;

    constexpr int CPRa = KIN / 8;
    for (int cid = tid; cid < 64 * CPRa; cid += 256) {
        int r = cid / CPRa, k8 = cid % CPRa;
        int row = row0 + r;
        uint4 val = make_uint4(0u, 0u, 0u, 0u);
        if (row < R) val = *(const uint4*)(in + (size_t)row * KIN + k8 * 8);
        unsigned bo = ((unsigned)(r * KIN + k8 * 8) * 2u) ^ (((unsigned)(r & 7)) << 4);
        *(uint4*)((char*)Ash + bo) = val;
    }
    for (int cid = tid; cid < 64 * CPRa; cid += 256) {
        int nn = cid / CPRa, k8 = cid % CPRa;
        uint4 val = *(const uint4*)(W1t + (size_t)nn * KIN + k8 * 8);
        unsigned bo = ((unsigned)(nn * KIN + k8 * 8) * 2u) ^ (((unsigned)(nn & 7)) << 4);
        *(uint4*)((char*)W1s + bo) = val;
    }
    for (int cid = tid; cid < 64 * 8; cid += 256) {
        int nn = cid / 8, k8 = cid % 8;
        uint4 v2 = *(const uint4*)(W2t + (size_t)nn * 64 + k8 * 8);
        uint4 v3 = *(const uint4*)(W3t + (size_t)nn * 64 + k8 * 8);
        unsigned bo = ((unsigned)(nn * 64 + k8 * 8) * 2u) ^ (((unsigned)(nn & 7)) << 4);
        *(uint4*)((char*)W2s + bo) = v2;
        *(uint4*)((char*)W3s + bo) = v3;
    }
    __syncthreads();

    // ---- stage 1: Ash(KIN) @ W1 -> H1 ----
    {
        f32x4 acc[4];
#pragma unroll
        for (int nt = 0; nt < 4; ++nt) acc[nt] = (f32x4){0.f, 0.f, 0.f, 0.f};
#pragma unroll
        for (int kc = 0; kc < KIN / 32; ++kc) {
            int r = w * 16 + (l & 15);
            int k = kc * 32 + (l >> 4) * 8;
            unsigned boA = ((unsigned)(r * KIN + k) * 2u) ^ (((unsigned)(r & 7)) << 4);
            bf16x8 afr = *(const bf16x8*)((char*)Ash + boA);
#pragma unroll
            for (int nt = 0; nt < 4; ++nt) {
                int col = nt * 16 + (l & 15);
                unsigned boB = ((unsigned)(col * KIN + k) * 2u) ^ (((unsigned)(col & 7)) << 4);
                bf16x8 bfr = *(const bf16x8*)((char*)W1s + boB);
                acc[nt] = __builtin_amdgcn_mfma_f32_16x16x32_bf16(afr, bfr, acc[nt], 0, 0, 0);
            }
        }
#pragma unroll
        for (int nt = 0; nt < 4; ++nt)
#pragma unroll
            for (int rg = 0; rg < 4; ++rg) {
                int row = w * 16 + (l >> 4) * 4 + rg;
                int col = nt * 16 + (l & 15);
                unsigned bo = ((unsigned)(row * 64 + col) * 2u) ^ (((unsigned)(row & 7)) << 4);
                *(unsigned short*)((char*)H1 + bo) = f2bf(silu_f(acc[nt][rg]));
            }
    }
    __syncthreads();

    // ---- stage 2: H1 @ W2 -> H2 ----
    {
        f32x4 acc[4];
#pragma unroll
        for (int nt = 0; nt < 4; ++nt) acc[nt] = (f32x4){0.f, 0.f, 0.f, 0.f};
#pragma unroll
        for (int kc = 0; kc < 2; ++kc) {
            int r = w * 16 + (l & 15);
            int k = kc * 32 + (l >> 4) * 8;
            unsigned boA = ((unsigned)(r * 64 + k) * 2u) ^ (((unsigned)(r & 7)) << 4);
            bf16x8 afr = *(const bf16x8*)((char*)H1 + boA);
#pragma unroll
            for (int nt = 0; nt < 4; ++nt) {
                int col = nt * 16 + (l & 15);
                unsigned boB = ((unsigned)(col * 64 + k) * 2u) ^ (((unsigned)(col & 7)) << 4);
                bf16x8 bfr = *(const bf16x8*)((char*)W2s + boB);
                acc[nt] = __builtin_amdgcn_mfma_f32_16x16x32_bf16(afr, bfr, acc[nt], 0, 0, 0);
            }
        }
#pragma unroll
        for (int nt = 0; nt < 4; ++nt)
#pragma unroll
            for (int rg = 0; rg < 4; ++rg) {
                int row = w * 16 + (l >> 4) * 4 + rg;
                int col = nt * 16 + (l & 15);
                unsigned bo = ((unsigned)(row * 64 + col) * 2u) ^ (((unsigned)(row & 7)) << 4);
                *(unsigned short*)((char*)H2 + bo) = f2bf(silu_f(acc[nt][rg]));
            }
    }
    __syncthreads();

    // ---- stage 3: H2 @ W3 -> global out (silu) ----
    {
        f32x4 acc[4];
#pragma unroll
        for (int nt = 0; nt < 4; ++nt) acc[nt] = (f32x4){0.f, 0.f, 0.f, 0.f};
#pragma unroll
        for (int kc = 0; kc < 2; ++kc) {
            int r = w * 16 + (l & 15);
            int k = kc * 32 + (l >> 4) * 8;
            unsigned boA = ((unsigned)(r * 64 + k) * 2u) ^ (((unsigned)(r & 7)) << 4);
            bf16x8 afr = *(const bf16x8*)((char*)H2 + boA);
#pragma unroll
            for (int nt = 0; nt < 4; ++nt) {
                int col = nt * 16 + (l & 15);
                unsigned boB = ((unsigned)(col * 64 + k) * 2u) ^ (((unsigned)(col & 7)) << 4);
                bf16x8 bfr = *(const bf16x8*)((char*)W3s + boB);
                acc[nt] = __builtin_amdgcn_mfma_f32_16x16x32_bf16(afr, bfr, acc[nt], 0, 0, 0);
            }
        }
#pragma unroll
        for (int nt = 0; nt < 4; ++nt)
#pragma unroll
            for (int rg = 0; rg < 4; ++rg) {
                int row = row0 + w * 16 + (l >> 4) * 4 + rg;
                if (row < R) {
                    int col = nt * 16 + (l & 15);
                    out[(size_t)row * 64 + col] = f2bf(silu_f(acc[nt][rg]));
                }
            }
    }
}

// ---------------------------------------------------------------------------
// MFMA GEMM bf16->bf16 (wgemm). MODE 1: silu, 2: plain.
// ---------------------------------------------------------------------------
template <int K, int N, int MODE>
__global__ __launch_bounds__(256) void mfma_gemm(
    const unsigned short* __restrict__ in, int in_ld,
    const unsigned short* __restrict__ Wt,
    unsigned short* __restrict__ out, int out_ld,
    int R)
{
    constexpr int NT = N / 16;
    constexpr int KC = K / 32;
    constexpr int CPR = K / 8;
    __shared__ __align__(16) unsigned short Ash[64 * K];
    __shared__ __align__(16) unsigned short Bsh[N * K];

    const int tid = threadIdx.x;
    const int w = tid >> 6;
    const int l = tid & 63;
    const int row0 = blockIdx.x * 64;
    const int cb = blockIdx.y * N;

    for (int cid = tid; cid < 64 * CPR; cid += 256) {
        int r = cid / CPR, k8 = cid % CPR;
        int row = row0 + r;
        uint4 val = make_uint4(0u, 0u, 0u, 0u);
        if (row < R) val = *(const uint4*)(in + (size_t)row * in_ld + k8 * 8);
        unsigned bo = ((unsigned)(r * K + k8 * 8) * 2u) ^ (((unsigned)(r & 7)) << 4);
        *(uint4*)((char*)Ash + bo) = val;
    }
    for (int cid = tid; cid < N * CPR; cid += 256) {
        int nn = cid / CPR, k8 = cid % CPR;
        uint4 val = *(const uint4*)(Wt + (size_t)(cb + nn) * K + k8 * 8);
        unsigned bo = ((unsigned)(nn * K + k8 * 8) * 2u) ^ (((unsigned)(nn & 7)) << 4);
        *(uint4*)((char*)Bsh + bo) = val;
    }
    __syncthreads();

    bf16x8 afr[KC];
#pragma unroll
    for (int kc = 0; kc < KC; ++kc) {
        int r = w * 16 + (l & 15);
        int k = kc * 32 + (l >> 4) * 8;
        unsigned bo = ((unsigned)(r * K + k) * 2u) ^ (((unsigned)(r & 7)) << 4);
        afr[kc] = *(const bf16x8*)((char*)Ash + bo);
    }

    f32x4 acc[NT];
#pragma unroll
    for (int nt = 0; nt < NT; ++nt) {
        acc[nt] = (f32x4){0.f, 0.f, 0.f, 0.f};
#pragma unroll
        for (int kc = 0; kc < KC; ++kc) {
            int col = nt * 16 + (l & 15);
            int k = kc * 32 + (l >> 4) * 8;
            unsigned bo = ((unsigned)(col * K + k) * 2u) ^ (((unsigned)(col & 7)) << 4);
            bf16x8 bfr = *(const bf16x8*)((char*)Bsh + bo);
            acc[nt] = __builtin_amdgcn_mfma_f32_16x16x32_bf16(afr[kc], bfr, acc[nt], 0, 0, 0);
        }
    }

#pragma unroll
    for (int nt = 0; nt < NT; ++nt) {
#pragma unroll
        for (int rg = 0; rg < 4; ++rg) {
            int row = row0 + w * 16 + (l >> 4) * 4 + rg;
            if (row < R) {
                int col = cb + nt * 16 + (l & 15);
                float v = acc[nt][rg];
                if constexpr (MODE == 1) v = silu_f(v);
                out[(size_t)row * out_ld + col] = f2bf(v);
            }
        }
    }
}

// ---------------------------------------------------------------------------
// MFMA GEMM fp32 in: MODE 0 f32 store, 2 bf16 store, 6 f32 accumulate.
// ---------------------------------------------------------------------------
template <int K, int N, int MODE>
__global__ __launch_bounds__(256) void mfma_gemm_f32(
    const float* __restrict__ in, int in_ld,
    const unsigned short* __restrict__ Wt,
    float* __restrict__ out, int out_ld,
    int R, float scale)
{
    constexpr int NT = N / 16;
    constexpr int KC = K / 32;
    constexpr int CPR = K / 8;
    __shared__ __align__(16) unsigned short Ash[64 * K];
    __shared__ __align__(16) unsigned short Bsh[N * K];

    const int tid = threadIdx.x;
    const int w = tid >> 6;
    const int l = tid & 63;
    const int row0 = blockIdx.x * 64;
    const int cb = blockIdx.y * N;

    for (int cid = tid; cid < 64 * CPR; cid += 256) {
        int r = cid / CPR, k8 = cid % CPR;
        int row = row0 + r;
        union { unsigned short u16[8]; uint4 v; } pk;
        if (row < R) {
            const float* p = in + (size_t)row * in_ld + k8 * 8;
            float4 f0 = *(const float4*)p;
            float4 f1 = *(const float4*)(p + 4);
            pk.u16[0] = f2bf(f0.x); pk.u16[1] = f2bf(f0.y);
            pk.u16[2] = f2bf(f0.z); pk.u16[3] = f2bf(f0.w);
            pk.u16[4] = f2bf(f1.x); pk.u16[5] = f2bf(f1.y);
            pk.u16[6] = f2bf(f1.z); pk.u16[7] = f2bf(f1.w);
        } else {
            pk.v = make_uint4(0u, 0u, 0u, 0u);
        }
        unsigned bo = ((unsigned)(r * K + k8 * 8) * 2u) ^ (((unsigned)(r & 7)) << 4);
        *(uint4*)((char*)Ash + bo) = pk.v;
    }
    for (int cid = tid; cid < N * CPR; cid += 256) {
        int nn = cid / CPR, k8 = cid % CPR;
        uint4 val = *(const uint4*)(Wt + (size_t)(cb + nn) * K + k8 * 8);
        unsigned bo = ((unsigned)(nn * K + k8 * 8) * 2u) ^ (((unsigned)(nn & 7)) << 4);
        *(uint4*)((char*)Bsh + bo) = val;
    }
    __syncthreads();

    bf16x8 afr[KC];
#pragma unroll
    for (int kc = 0; kc < KC; ++kc) {
        int r = w * 16 + (l & 15);
        int k = kc * 32 + (l >> 4) * 8;
        unsigned bo = ((unsigned)(r * K + k) * 2u) ^ (((unsigned)(r & 7)) << 4);
        afr[kc] = *(const bf16x8*)((char*)Ash + bo);
    }

    f32x4 acc[NT];
#pragma unroll
    for (int nt = 0; nt < NT; ++nt) {
        acc[nt] = (f32x4){0.f, 0.f, 0.f, 0.f};
#pragma unroll
        for (int kc = 0; kc < KC; ++kc) {
            int col = nt * 16 + (l & 15);
            int k = kc * 32 + (l >> 4) * 8;
            unsigned bo = ((unsigned)(col * K + k) * 2u) ^ (((unsigned)(col & 7)) << 4);
            bf16x8 bfr = *(const bf16x8*)((char*)Bsh + bo);
            acc[nt] = __builtin_amdgcn_mfma_f32_16x16x32_bf16(afr[kc], bfr, acc[nt], 0, 0, 0);
        }
    }

#pragma unroll
    for (int nt = 0; nt < NT; ++nt) {
#pragma unroll
        for (int rg = 0; rg < 4; ++rg) {
            int row = row0 + w * 16 + (l >> 4) * 4 + rg;
            if (row < R) {
                int col = cb + nt * 16 + (l & 15);
                float v = acc[nt][rg] * scale;
                size_t idx = (size_t)row * out_ld + col;
                if constexpr (MODE == 6)      out[idx] += v;
                else if constexpr (MODE == 2) ((unsigned short*)out)[idx] = f2bf(v);
                else                          out[idx] = v;
            }
        }
    }
}

// batched edge-weight prep
struct WPE { const float* s[8]; unsigned short* d[8]; int K[8], N[8], Kp[8]; };
__global__ void k_wprepE(WPE wp)
{
    int m = blockIdx.y;
    int i = blockIdx.x * 256 + threadIdx.x;
    int tot = wp.N[m] * wp.Kp[m];
    if (i >= tot) return;
    int n = i / wp.Kp[m], k = i % wp.Kp[m];
    wp.d[m][i] = (k < wp.K[m]) ? f2bf(wp.s[m][k * wp.N[m] + n]) : (unsigned short)0;
}

struct WP10 { const float* s[10]; unsigned short* d[10]; };
__global__ void k_wprep10(WP10 wp)
{
    int m = blockIdx.y;
    int i = blockIdx.x * 256 + threadIdx.x;
    if (i >= 128 * 128) return;
    int n = i / 128, k = i % 128;
    wp.d[m][i] = f2bf(wp.s[m][k * 128 + n]);
}

// ---------------------------------------------------------------------------
// CSR build
// ---------------------------------------------------------------------------
__global__ void k_count(const int* __restrict__ rcv, int* __restrict__ deg)
{
    int e = blockIdx.x * 256 + threadIdx.x;
    if (e < EE) atomicAdd(&deg[rcv[e]], 1);
}

__global__ __launch_bounds__(256) void k_scan(const int* __restrict__ deg,
                                              int* __restrict__ rowptr,
                                              int* __restrict__ cursor)
{
    __shared__ int part[256];
    const int t = threadIdx.x;
    const int PER = (NN + 255) / 256;
    int base = t * PER;
    int s = 0;
    for (int j = 0; j < PER; ++j) { int idx = base + j; if (idx < NN) s += deg[idx]; }
    part[t] = s;
    __syncthreads();
    for (int off = 1; off < 256; off <<= 1) {
        int v = (t >= off) ? part[t - off] : 0;
        __syncthreads();
        part[t] += v;
        __syncthreads();
    }
    int run = (t == 0) ? 0 : part[t - 1];
    for (int j = 0; j < PER; ++j) {
        int idx = base + j;
        if (idx < NN) { rowptr[idx] = run; cursor[idx] = run; run += deg[idx]; }
    }
    if (t == 255) rowptr[NN] = part[255];
}

__global__ void k_fill(const int* __restrict__ rcv, int* __restrict__ cursor,
                       int* __restrict__ perm)
{
    int e = blockIdx.x * 256 + threadIdx.x;
    if (e >= EE) return;
    int pos = atomicAdd(&cursor[rcv[e]], 1);
    perm[pos] = e;
}

__global__ __launch_bounds__(256) void k_sortwave(const int* __restrict__ rowptr,
                                                  int* __restrict__ perm)
{
    int gid = blockIdx.x * 256 + threadIdx.x;
    int wid = gid >> 6;
    int lane = gid & 63;
    if (wid >= NN) return;
    int a = rowptr[wid], b = rowptr[wid + 1];
    int d = b - a;
    if (d <= 1) return;
    if (d <= 64) {
        int v = (lane < d) ? perm[a + lane] : 0x7fffffff;
        int rank = 0;
        for (int j = 0; j < 64; ++j) {
            int vj = __shfl(v, j);
            if (j < d && vj < v) ++rank;
        }
        if (lane < d) perm[a + rank] = v;
    } else if (lane == 0) {
        for (int i = a + 1; i < b; ++i) {
            int v = perm[i]; int j = i - 1;
            while (j >= a && perm[j] > v) { perm[j + 1] = perm[j]; --j; }
            perm[j + 1] = v;
        }
    }
}

// geometry in CSR order; ef as bf16 [EE][32] zero-padded
__global__ void k_geom_perm(const float* __restrict__ pos, const float* __restrict__ shifts,
                            const int* __restrict__ snd, const int* __restrict__ rcv,
                            const int* __restrict__ perm,
                            float* __restrict__ Yv, unsigned short* __restrict__ efb,
                            int* __restrict__ psnd)
{
    int i = blockIdx.x * 256 + threadIdx.x;
    if (i >= EE) return;
    int e = perm[i];
    int s = snd[e], r = rcv[e];
    psnd[i] = s;
    float vx = pos[r * 3 + 0] - pos[s * 3 + 0] + shifts[e * 3 + 0];
    float vy = pos[r * 3 + 1] - pos[s * 3 + 1] + shifts[e * 3 + 1];
    float vz = pos[r * 3 + 2] - pos[s * 3 + 2] + shifts[e * 3 + 2];
    float len = sqrtf(vx * vx + vy * vy + vz * vz + 1e-12f);
    float inv = 1.0f / len;
    const float SQ3 = 1.7320508075688772f;
    Yv[i * 3 + 0] = SQ3 * vx * inv;
    Yv[i * 3 + 1] = SQ3 * vy * inv;
    Yv[i * 3 + 2] = SQ3 * vz * inv;
    float u = len * 0.2f;
    float fc = 0.0f;
    if (u < 1.0f) {
        float u2 = u * u, u4 = u2 * u2, u5 = u4 * u, u6 = u5 * u, u7 = u6 * u;
        fc = 1.0f - 21.0f * u5 + 35.0f * u6 - 15.0f * u7;
    }
    float pref = 0.6324555320336759f * inv * fc;
    const float PIO5 = 0.6283185307179586f;
    union { unsigned short u16[8]; uint4 v; } pk;
#pragma unroll
    for (int n = 1; n <= 8; ++n)
        pk.u16[n - 1] = f2bf(pref * sinf((float)n * PIO5 * len));
    uint4* dst = (uint4*)(efb + (size_t)i * 32);
    dst[0] = pk.v;
    dst[1] = make_uint4(0u, 0u, 0u, 0u);
    dst[2] = make_uint4(0u, 0u, 0u, 0u);
    dst[3] = make_uint4(0u, 0u, 0u, 0u);
}

// ---------------------------------------------------------------------------
// gathers: coalesced bf16 wb + random bf16 payload rows
// ---------------------------------------------------------------------------
__global__ __launch_bounds__(256) void k_gather1(
    const int* __restrict__ rowptr, const int* __restrict__ psnd,
    const float* __restrict__ Yv, const unsigned short* __restrict__ wb,
    int e0, int e1,
    const unsigned short* __restrict__ gS,
    float* __restrict__ outS, float* __restrict__ outV)
{
    const int t = threadIdx.x;
    const int c = t & 127;
    const int n = blockIdx.x * 2 + (t >> 7);
    if (n >= NN) return;
    int rs = rowptr[n], re = rowptr[n + 1];
    if (rs < e0) rs = e0;
    if (re > e1) re = e1;
    if (rs >= re) return;
    float accs = 0.f, a0 = 0.f, a1 = 0.f, a2 = 0.f;
    for (int i = rs; i < re; ++i) {
        const unsigned short* wp = wb + (size_t)(i - e0) * 256;
        float wss = bf2f(wp[c]);
        float wsv = bf2f(wp[128 + c]);
        float h = bf2f(gS[psnd[i] * 128 + c]);
        float y0 = Yv[i * 3], y1 = Yv[i * 3 + 1], y2 = Yv[i * 3 + 2];
        accs = fmaf(wss, h, accs);
        float tv = wsv * h;
        a0 = fmaf(tv, y0, a0); a1 = fmaf(tv, y1, a1); a2 = fmaf(tv, y2, a2);
    }
    outS[n * 128 + c] += accs;
    outV[n * 384 + c]       += a0;
    outV[n * 384 + 128 + c] += a1;
    outV[n * 384 + 256 + c] += a2;
}

__global__ __launch_bounds__(256) void k_gather23(
    const int* __restrict__ rowptr, const int* __restrict__ psnd,
    const float* __restrict__ Yv, const unsigned short* __restrict__ wb,
    int e0, int e1,
    const unsigned short* __restrict__ gS, const unsigned short* __restrict__ gV,
    float* __restrict__ outS, float* __restrict__ outV)
{
    const int t = threadIdx.x;
    const int c = t & 127;
    const int n = blockIdx.x * 2 + (t >> 7);
    if (n >= NN) return;
    int rs = rowptr[n], re = rowptr[n + 1];
    if (rs < e0) rs = e0;
    if (re > e1) re = e1;
    if (rs >= re) return;
    float accs = 0.f, a0 = 0.f, a1 = 0.f, a2 = 0.f;
    for (int i = rs; i < re; ++i) {
        const unsigned short* wp = wb + (size_t)(i - e0) * 512;
        float wa = bf2f(wp[c]);
        float wbv = bf2f(wp[128 + c]);
        float wc = bf2f(wp[256 + c]);
        float wd = bf2f(wp[384 + c]);
        int s = psnd[i];
        float hs = bf2f(gS[s * 128 + c]);
        float v0 = bf2f(gV[s * 384 + c]);
        float v1 = bf2f(gV[s * 384 + 128 + c]);
        float v2 = bf2f(gV[s * 384 + 256 + c]);
        float y0 = Yv[i * 3], y1 = Yv[i * 3 + 1], y2 = Yv[i * 3 + 2];
        float hd = v0 * y0 + v1 * y1 + v2 * y2;
        accs = fmaf(wa, hs, accs);
        accs = fmaf(wbv, hd * 0.57735026919f, accs);
        float tv = wc * hs;
        a0 = fmaf(tv, y0, a0); a0 = fmaf(wd, v0, a0);
        a1 = fmaf(tv, y1, a1); a1 = fmaf(wd, v1, a1);
        a2 = fmaf(tv, y2, a2); a2 = fmaf(wd, v2, a2);
    }
    outS[n * 128 + c] += accs;
    outV[n * 384 + c]       += a0;
    outV[n * 384 + 128 + c] += a1;
    outV[n * 384 + 256 + c] += a2;
}

// ---------------------------------------------------------------------------
// species + embed fused
__global__ void k_embed2(const float* __restrict__ attrs, const float* __restrict__ W_emb,
                         int* __restrict__ species, float* __restrict__ h)
{
    int t = blockIdx.x * 256 + threadIdx.x;
    if (t >= NN * CC) return;
    int n = t >> 7, c = t & 127;
    int sp = 0;
#pragma unroll
    for (int j = 0; j < NEL; ++j)
        if (attrs[n * NEL + j] > 0.5f) sp = j;
    if (c == 0) species[n] = sp;
    h[t] = W_emb[sp * CC + c];
}

__global__ void k_B1(const int* __restrict__ species,
                     const float* __restrict__ As_l, const float* __restrict__ Av_l,
                     const float* __restrict__ P_s1, const float* __restrict__ P_ss,
                     const float* __restrict__ P_vv, const float* __restrict__ P_v1,
                     const float* __restrict__ P_sv,
                     float* __restrict__ Bs, float* __restrict__ Bv)
{
    int t = blockIdx.x * 256 + threadIdx.x;
    if (t >= NN * CC) return;
    int n = t >> 7, c = t & 127;
    int sp = species[n];
    int pb = sp * CC + c;
    int vb = n * 384 + c;
    float as = As_l[t];
    float a0 = Av_l[vb], a1 = Av_l[vb + CC], a2 = Av_l[vb + 2 * CC];
    Bs[t] = P_s1[pb] * as + P_ss[pb] * as * as
          + P_vv[pb] * (a0 * a0 + a1 * a1 + a2 * a2) * 0.57735026919f;
    float tv = P_v1[pb] + P_sv[pb] * as;
    Bv[vb] = tv * a0; Bv[vb + CC] = tv * a1; Bv[vb + 2 * CC] = tv * a2;
}

__global__ void k_B2(const int* __restrict__ species,
                     const float* __restrict__ As_l, const float* __restrict__ Av_l,
                     const float* __restrict__ P_v1, const float* __restrict__ P_sv,
                     float* __restrict__ Bv)
{
    int t = blockIdx.x * 256 + threadIdx.x;
    if (t >= NN * CC) return;
    int n = t >> 7, c = t & 127;
    int sp = species[n];
    int pb = sp * CC + c;
    int vb = n * 384 + c;
    float as = As_l[t];
    float tv = P_v1[pb] + P_sv[pb] * as;
    Bv[vb] = tv * Av_l[vb];
    Bv[vb + CC] = tv * Av_l[vb + CC];
    Bv[vb + 2 * CC] = tv * Av_l[vb + 2 * CC];
}

__global__ void k_sc(const int* __restrict__ species, const float* __restrict__ h_v,
                     const float* __restrict__ Wsk, float* __restrict__ h2v)
{
    int n = blockIdx.x, f = threadIdx.x;
    int sp = species[n];
    const float* Wp = Wsk + sp * (CC * CC);
    const float* hvn = h_v + n * 384;
    float a0 = 0.f, a1 = 0.f, a2 = 0.f;
    for (int c = 0; c < CC; ++c) {
        float w = Wp[c * CC + f];
        a0 = fmaf(hvn[c], w, a0);
        a1 = fmaf(hvn[CC + c], w, a1);
        a2 = fmaf(hvn[2 * CC + c], w, a2);
    }
    h2v[n * 384 + f] = a0;
    h2v[n * 384 + CC + f] = a1;
    h2v[n * 384 + 2 * CC + f] = a2;
}

// node output: rmix + dip1 + mid-dot fused (all linear reductions combined)
__global__ void k_node_out2(const float* __restrict__ h2v, const float* __restrict__ h_v,
                            const float* __restrict__ R1,
                            const float* __restrict__ Rmid, const float* __restrict__ Rout,
                            const float* __restrict__ charges, const float* __restrict__ pos,
                            float* __restrict__ out, float* __restrict__ tot)
{
    int n = blockIdx.x, l = threadIdx.x;
    float r0 = 0.f, r1 = 0.f;
#pragma unroll
    for (int k = 0; k < 16; ++k) {
        r0 = fmaf(Rmid[l * 16 + k], Rout[k], r0);
        r1 = fmaf(Rmid[(64 + l) * 16 + k], Rout[k], r1);
    }
    const float* hb = h2v + n * 384;
    const float* hv1 = h_v + n * 384;
    float R1a = R1[l], R1b = R1[64 + l];
    float red[3];
#pragma unroll
    for (int d = 0; d < 3; ++d) {
        float v = hb[d * CC + l] * r0 + hb[d * CC + 64 + l] * r1;
        float dv = hv1[d * CC + l] * R1a + hv1[d * CC + 64 + l] * R1b;
        float m = dv + 0.5f * v;
        for (int o = 32; o > 0; o >>= 1) m += __shfl_down(m, o);
        red[d] = m;
    }
    if (l == 0) {
        float q = charges[n];
#pragma unroll
        for (int d = 0; d < 3; ++d) {
            float a = red[d];
            out[48 + n * 3 + d] = a;
            tot[n * 3 + d] = a + q * pos[n * 3 + d];
        }
    }
}

__global__ __launch_bounds__(256) void k_greduce(const float* __restrict__ tot,
                                                 const int* __restrict__ batch,
                                                 float* __restrict__ out)
{
    __shared__ float r[256 * 3];
    const int g = blockIdx.x;
    const int t = threadIdx.x;
    float s0 = 0.f, s1 = 0.f, s2 = 0.f;
    for (int n = t; n < NN; n += 256) {
        if (batch[n] == g) {
            s0 += tot[n * 3]; s1 += tot[n * 3 + 1]; s2 += tot[n * 3 + 2];
        }
    }
    r[t] = s0; r[256 + t] = s1; r[512 + t] = s2;
    __syncthreads();
    for (int off = 128; off > 0; off >>= 1) {
        if (t < off) {
            r[t] += r[t + off];
            r[256 + t] += r[256 + t + off];
            r[512 + t] += r[512 + t + off];
        }
        __syncthreads();
    }
    if (t < 3) out[g * 3 + t] = r[t * 256];
}

// ---------------------------------------------------------------------------
extern "C" void kernel_launch(void* const* d_in, const int* in_sizes, int n_in,
                              void* d_out, int out_size, void* d_ws, size_t ws_size,
                              hipStream_t stream)
{
    const float* positions = (const float*)d_in[0];
    const float* node_attrs = (const float*)d_in[1];
    const float* charges = (const float*)d_in[2];
    const float* shifts = (const float*)d_in[3];
    const int*   eidx = (const int*)d_in[4];
    const int*   batch = (const int*)d_in[5];
    const float* W_emb  = (const float*)d_in[7];
    const float* W_up1  = (const float*)d_in[8];
    const float* Wr1_1  = (const float*)d_in[9];
    const float* Wr1_2  = (const float*)d_in[10];
    const float* Wr1_3  = (const float*)d_in[11];
    const float* Wr1_o  = (const float*)d_in[12];
    const float* Wlin1_s = (const float*)d_in[13];
    const float* Wlin1_v = (const float*)d_in[14];
    const float* P1_s1 = (const float*)d_in[15];
    const float* P1_ss = (const float*)d_in[16];
    const float* P1_vv = (const float*)d_in[17];
    const float* P1_v1 = (const float*)d_in[18];
    const float* P1_sv = (const float*)d_in[19];
    const float* Lp1_s = (const float*)d_in[20];
    const float* Lp1_v = (const float*)d_in[21];
    const float* R1    = (const float*)d_in[22];
    const float* Wsk   = (const float*)d_in[23];
    const float* Wup2_s = (const float*)d_in[24];
    const float* Wup2_v = (const float*)d_in[25];
    const float* Wr2_1 = (const float*)d_in[26];
    const float* Wr2_2 = (const float*)d_in[27];
    const float* Wr2_3 = (const float*)d_in[28];
    const float* Wr2_o = (const float*)d_in[29];
    const float* Wlin2_s = (const float*)d_in[30];
    const float* Wlin2_v = (const float*)d_in[31];
    const float* P2_v1 = (const float*)d_in[32];
    const float* P2_sv = (const float*)d_in[33];
    const float* Lp2_v = (const float*)d_in[34];
    const float* Rmid  = (const float*)d_in[35];
    const float* Rout  = (const float*)d_in[36];
    (void)in_sizes; (void)n_in; (void)out_size;

    const int* snd = eidx;
    const int* rcv = eidx + EE;
    float* out = (float*)d_out;

    char* ws = (char*)d_ws;
    size_t off = 0;
    auto alloc = [&](size_t bytes) -> void* {
        void* p = (void*)(ws + off);
        off = (off + bytes + 255) & ~(size_t)255;
        return p;
    };
    int*   species = (int*)alloc((size_t)NN * 4);
    int*   deg     = (int*)alloc((size_t)NN * 4);
    int*   rowptr  = (int*)alloc((size_t)(NN + 16) * 4);
    int*   cursor  = (int*)alloc((size_t)NN * 4);
    int*   perm    = (int*)alloc((size_t)EE * 4);
    int*   psnd    = (int*)alloc((size_t)EE * 4);
    float* Yv   = (float*)alloc((size_t)EE * 3 * 4);
    unsigned short* efb = (unsigned short*)alloc((size_t)EE * 32 * 2);
    float* A_s  = (float*)alloc((size_t)NN * CC * 4);       // contiguous with A_v
    float* A_v  = (float*)alloc((size_t)NN * 3 * CC * 4);
    float* hbuf = (float*)alloc((size_t)NN * CC * 4);
    float* hu   = (float*)alloc((size_t)NN * CC * 4);
    float* h_v  = (float*)alloc((size_t)NN * 3 * CC * 4);
    float* h2v  = (float*)alloc((size_t)NN * 3 * CC * 4);
    float* tot  = (float*)alloc((size_t)NN * 3 * 4);
    unsigned short* hub = (unsigned short*)alloc((size_t)NN * CC * 2);
    unsigned short* hsb = (unsigned short*)alloc((size_t)NN * CC * 2);
    unsigned short* hvb = (unsigned short*)alloc((size_t)NN * 3 * CC * 2);
    unsigned short* W1t_l1 = (unsigned short*)alloc(64 * 32 * 2);
    unsigned short* W2t_l1 = (unsigned short*)alloc(64 * 64 * 2);
    unsigned short* W3t_l1 = (unsigned short*)alloc(64 * 64 * 2);
    unsigned short* Wot_l1 = (unsigned short*)alloc(256 * 64 * 2);
    unsigned short* W1t_l2 = (unsigned short*)alloc(64 * 32 * 2);
    unsigned short* W2t_l2 = (unsigned short*)alloc(64 * 64 * 2);
    unsigned short* W3t_l2 = (unsigned short*)alloc(64 * 64 * 2);
    unsigned short* Wot_l2 = (unsigned short*)alloc(512 * 64 * 2);
    unsigned short* Wn[10];
    for (int m = 0; m < 10; ++m) Wn[m] = (unsigned short*)alloc(128 * 128 * 2);
    unsigned short* hbA = (unsigned short*)alloc((size_t)EE * 64 * 2);

    int C = 16;
    if      (off + (size_t)EE * 512 * 2 + 4096 <= ws_size)        C = 1;
    else if (off + (size_t)(EE / 2) * 512 * 2 + 4096 <= ws_size)  C = 2;
    else if (off + (size_t)(EE / 4) * 512 * 2 + 4096 <= ws_size)  C = 4;
    else if (off + (size_t)(EE / 8) * 512 * 2 + 4096 <= ws_size)  C = 8;
    const int EC = EE / C;
    unsigned short* wbuf = (unsigned short*)alloc((size_t)EC * 512 * 2);

    const float inv16 = 1.0f / 16.0f;
    const float one = 1.0f;

    hipMemsetAsync(deg, 0, (size_t)NN * 4, stream);
    hipMemsetAsync(A_s, 0, (size_t)NN * 4 * CC * 4, stream);   // A_s + A_v contiguous

    // weight prep (2 dispatches)
    {
        WPE wp;
        const float* s[8] = {Wr1_1, Wr1_2, Wr1_3, Wr1_o, Wr2_1, Wr2_2, Wr2_3, Wr2_o};
        unsigned short* d[8] = {W1t_l1, W2t_l1, W3t_l1, Wot_l1, W1t_l2, W2t_l2, W3t_l2, Wot_l2};
        int Ks[8] = {8, 64, 64, 64, 8, 64, 64, 64};
        int Ns[8] = {64, 64, 64, 256, 64, 64, 64, 512};
        int Kp[8] = {32, 64, 64, 64, 32, 64, 64, 64};
        for (int m = 0; m < 8; ++m) { wp.s[m] = s[m]; wp.d[m] = d[m]; wp.K[m] = Ks[m]; wp.N[m] = Ns[m]; wp.Kp[m] = Kp[m]; }
        k_wprepE<<<dim3(cdiv(512 * 64, 256), 8), 256, 0, stream>>>(wp);
    }
    {
        WP10 wp;
        const float* srcs[10] = {W_up1, Wlin1_s, Wlin1_v, Lp1_s, Lp1_v,
                                 Wup2_s, Wup2_v, Wlin2_s, Wlin2_v, Lp2_v};
        for (int m = 0; m < 10; ++m) { wp.s[m] = srcs[m]; wp.d[m] = Wn[m]; }
        k_wprep10<<<dim3(cdiv(128 * 128, 256), 10), 256, 0, stream>>>(wp);
    }

    // ---- CSR build + permuted geometry ----
    k_count<<<cdiv(EE, 256), 256, 0, stream>>>(rcv, deg);
    k_scan<<<1, 256, 0, stream>>>(deg, rowptr, cursor);
    k_fill<<<cdiv(EE, 256), 256, 0, stream>>>(rcv, cursor, perm);
    k_sortwave<<<cdiv(NN * 64, 256), 256, 0, stream>>>(rowptr, perm);
    k_geom_perm<<<cdiv(EE, 256), 256, 0, stream>>>(positions, shifts, snd, rcv, perm, Yv, efb, psnd);

    k_embed2<<<cdiv(NN * CC, 256), 256, 0, stream>>>(node_attrs, W_emb, species, hbuf);

    // hu payload (bf16) = h @ W_up1
    mfma_gemm_f32<128, 128, 2><<<cdiv(NN, 64), 256, 0, stream>>>(
        hbuf, 128, Wn[0], (float*)hub, 128, NN, one);

    // ---- layer 1: fused edge MLP -> chunked wgemm + gather ----
    mfma_mlp3<32><<<cdiv(EE, 64), 256, 0, stream>>>(efb, W1t_l1, W2t_l1, W3t_l1, hbA, EE);
    for (int ch = 0; ch < C; ++ch) {
        int e0 = ch * EC, e1 = e0 + EC;
        mfma_gemm<64, 128, 2><<<dim3(cdiv(EC, 64), 2), 256, 0, stream>>>(
            hbA + (size_t)e0 * 64, 64, Wot_l1, wbuf, 256, EC);
        k_gather1<<<NN / 2, 256, 0, stream>>>(
            rowptr, psnd, Yv, wbuf, e0, e1, hub, A_s, A_v);
    }

    // ---- layer 1 node side (MFMA) ----
    mfma_gemm_f32<128, 128, 0><<<cdiv(NN, 64), 256, 0, stream>>>(
        A_s, 128, Wn[1], A_s, 128, NN, inv16);
    mfma_gemm_f32<128, 128, 0><<<cdiv(3 * NN, 64), 256, 0, stream>>>(
        A_v, 128, Wn[2], A_v, 128, 3 * NN, inv16);
    k_B1<<<cdiv(NN * CC, 256), 256, 0, stream>>>(
        species, A_s, A_v, P1_s1, P1_ss, P1_vv, P1_v1, P1_sv, hbuf /*Bs*/, A_v /*Bv*/);
    mfma_gemm_f32<128, 128, 0><<<cdiv(NN, 64), 256, 0, stream>>>(
        hbuf, 128, Wn[3], hu /*h_s*/, 128, NN, one);
    mfma_gemm_f32<128, 128, 0><<<cdiv(3 * NN, 64), 256, 0, stream>>>(
        A_v /*Bv*/, 128, Wn[4], h_v, 128, 3 * NN, one);
    mfma_gemm_f32<128, 128, 2><<<cdiv(NN, 64), 256, 0, stream>>>(
        hu /*h_s*/, 128, Wn[5], (float*)hsb, 128, NN, one);
    mfma_gemm_f32<128, 128, 2><<<cdiv(3 * NN, 64), 256, 0, stream>>>(
        h_v, 128, Wn[6], (float*)hvb, 128, 3 * NN, one);

    // ---- layer 2: fused edge MLP -> chunked wgemm + merged gather ----
    hipMemsetAsync(A_s, 0, (size_t)NN * 4 * CC * 4, stream);   // A_s + A_v
    mfma_mlp3<32><<<cdiv(EE, 64), 256, 0, stream>>>(efb, W1t_l2, W2t_l2, W3t_l2, hbA, EE);
    for (int ch = 0; ch < C; ++ch) {
        int e0 = ch * EC, e1 = e0 + EC;
        mfma_gemm<64, 128, 2><<<dim3(cdiv(EC, 64), 4), 256, 0, stream>>>(
            hbA + (size_t)e0 * 64, 64, Wot_l2, wbuf, 512, EC);
        k_gather23<<<NN / 2, 256, 0, stream>>>(
            rowptr, psnd, Yv, wbuf, e0, e1, hsb, hvb, A_s, A_v);
    }

    // ---- layer 2 node side (MFMA) ----
    mfma_gemm_f32<128, 128, 0><<<cdiv(NN, 64), 256, 0, stream>>>(
        A_s, 128, Wn[7], A_s, 128, NN, inv16);
    mfma_gemm_f32<128, 128, 0><<<cdiv(3 * NN, 64), 256, 0, stream>>>(
        A_v, 128, Wn[8], A_v, 128, 3 * NN, inv16);
    k_sc<<<NN, 128, 0, stream>>>(species, h_v, Wsk, h2v);
    k_B2<<<cdiv(NN * CC, 256), 256, 0, stream>>>(species, A_s, A_v, P2_v1, P2_sv, A_v /*B2v*/);
    mfma_gemm_f32<128, 128, 6><<<cdiv(3 * NN, 64), 256, 0, stream>>>(
        A_v /*B2v*/, 128, Wn[9], h2v, 128, 3 * NN, one);

    k_node_out2<<<NN, 64, 0, stream>>>(h2v, h_v, R1, Rmid, Rout, charges, positions, out, tot);
    k_greduce<<<NGR, 256, 0, stream>>>(tot, batch, out);
}

// Round 16
// 493.864 us; speedup vs baseline: 4.4823x; 1.0128x over previous
//
#include <hip/hip_runtime.h>

#define NN 10000
#define EE 160000
#define CC 128
#define NEL 10
#define NGR 16

static inline int cdiv(int a, int b) { return (a + b - 1) / b; }

__device__ __forceinline__ float silu_f(float x) { return x / (1.0f + __expf(-x)); }

__device__ __forceinline__ float bf2f(unsigned short u) {
    unsigned int x = ((unsigned int)u) << 16;
    return __uint_as_float(x);
}
__device__ __forceinline__ unsigned short f2bf(float f) {
    unsigned int x = __float_as_uint(f);
    unsigned int r = x + 0x7fffu + ((x >> 16) & 1u);
    return (unsigned short)(r >> 16);
}

typedef __attribute__((ext_vector_type(8))) short bf16x8;
typedef __attribute__((ext_vector_type(4))) float f32x4;

// ---------------------------------------------------------------------------
// Fused 3-layer edge MLP (bf16): out = silu(silu(silu(in@W1)@W2)@W3)
// ---------------------------------------------------------------------------
template <int KIN>
__global__ __launch_bounds__(256) void mfma_mlp3(
    const unsigned short* __restrict__ in,
    const unsigned short* __restrict__ W1t,
    const unsigned short* __restrict__ W2t,
    const unsigned short* __restrict__ W3t,
    unsigned short* __restrict__ out, int R)
{
    __shared__ __align__(16) unsigned short Ash[64 * KIN];
    __shared__ __align__(16) unsigned short W1s[64 * KIN];
    __shared__ __align__(16) unsigned short W2s[64 * 64];
    __shared__ __align__(16) unsigned short W3s[64 * 64];
    __shared__ __align__(16) unsigned short H1[64 * 64];
    __shared__ __align__(16) unsigned short H2[64 * 64];

    const int tid = threadIdx.x;
    const int w = tid >> 6;
    const int l = tid & 63;
    const int row0 = blockIdx.x * 64;

    constexpr int CPRa = KIN / 8;
    for (int cid = tid; cid < 64 * CPRa; cid += 256) {
        int r = cid / CPRa, k8 = cid % CPRa;
        int row = row0 + r;
        uint4 val = make_uint4(0u, 0u, 0u, 0u);
        if (row < R) val = *(const uint4*)(in + (size_t)row * KIN + k8 * 8);
        unsigned bo = ((unsigned)(r * KIN + k8 * 8) * 2u) ^ (((unsigned)(r & 7)) << 4);
        *(uint4*)((char*)Ash + bo) = val;
    }
    for (int cid = tid; cid < 64 * CPRa; cid += 256) {
        int nn = cid / CPRa, k8 = cid % CPRa;
        uint4 val = *(const uint4*)(W1t + (size_t)nn * KIN + k8 * 8);
        unsigned bo = ((unsigned)(nn * KIN + k8 * 8) * 2u) ^ (((unsigned)(nn & 7)) << 4);
        *(uint4*)((char*)W1s + bo) = val;
    }
    for (int cid = tid; cid < 64 * 8; cid += 256) {
        int nn = cid / 8, k8 = cid % 8;
        uint4 v2 = *(const uint4*)(W2t + (size_t)nn * 64 + k8 * 8);
        uint4 v3 = *(const uint4*)(W3t + (size_t)nn * 64 + k8 * 8);
        unsigned bo = ((unsigned)(nn * 64 + k8 * 8) * 2u) ^ (((unsigned)(nn & 7)) << 4);
        *(uint4*)((char*)W2s + bo) = v2;
        *(uint4*)((char*)W3s + bo) = v3;
    }
    __syncthreads();

    {
        f32x4 acc[4];
#pragma unroll
        for (int nt = 0; nt < 4; ++nt) acc[nt] = (f32x4){0.f, 0.f, 0.f, 0.f};
#pragma unroll
        for (int kc = 0; kc < KIN / 32; ++kc) {
            int r = w * 16 + (l & 15);
            int k = kc * 32 + (l >> 4) * 8;
            unsigned boA = ((unsigned)(r * KIN + k) * 2u) ^ (((unsigned)(r & 7)) << 4);
            bf16x8 afr = *(const bf16x8*)((char*)Ash + boA);
#pragma unroll
            for (int nt = 0; nt < 4; ++nt) {
                int col = nt * 16 + (l & 15);
                unsigned boB = ((unsigned)(col * KIN + k) * 2u) ^ (((unsigned)(col & 7)) << 4);
                bf16x8 bfr = *(const bf16x8*)((char*)W1s + boB);
                acc[nt] = __builtin_amdgcn_mfma_f32_16x16x32_bf16(afr, bfr, acc[nt], 0, 0, 0);
            }
        }
#pragma unroll
        for (int nt = 0; nt < 4; ++nt)
#pragma unroll
            for (int rg = 0; rg < 4; ++rg) {
                int row = w * 16 + (l >> 4) * 4 + rg;
                int col = nt * 16 + (l & 15);
                unsigned bo = ((unsigned)(row * 64 + col) * 2u) ^ (((unsigned)(row & 7)) << 4);
                *(unsigned short*)((char*)H1 + bo) = f2bf(silu_f(acc[nt][rg]));
            }
    }
    __syncthreads();

    {
        f32x4 acc[4];
#pragma unroll
        for (int nt = 0; nt < 4; ++nt) acc[nt] = (f32x4){0.f, 0.f, 0.f, 0.f};
#pragma unroll
        for (int kc = 0; kc < 2; ++kc) {
            int r = w * 16 + (l & 15);
            int k = kc * 32 + (l >> 4) * 8;
            unsigned boA = ((unsigned)(r * 64 + k) * 2u) ^ (((unsigned)(r & 7)) << 4);
            bf16x8 afr = *(const bf16x8*)((char*)H1 + boA);
#pragma unroll
            for (int nt = 0; nt < 4; ++nt) {
                int col = nt * 16 + (l & 15);
                unsigned boB = ((unsigned)(col * 64 + k) * 2u) ^ (((unsigned)(col & 7)) << 4);
                bf16x8 bfr = *(const bf16x8*)((char*)W2s + boB);
                acc[nt] = __builtin_amdgcn_mfma_f32_16x16x32_bf16(afr, bfr, acc[nt], 0, 0, 0);
            }
        }
#pragma unroll
        for (int nt = 0; nt < 4; ++nt)
#pragma unroll
            for (int rg = 0; rg < 4; ++rg) {
                int row = w * 16 + (l >> 4) * 4 + rg;
                int col = nt * 16 + (l & 15);
                unsigned bo = ((unsigned)(row * 64 + col) * 2u) ^ (((unsigned)(row & 7)) << 4);
                *(unsigned short*)((char*)H2 + bo) = f2bf(silu_f(acc[nt][rg]));
            }
    }
    __syncthreads();

    {
        f32x4 acc[4];
#pragma unroll
        for (int nt = 0; nt < 4; ++nt) acc[nt] = (f32x4){0.f, 0.f, 0.f, 0.f};
#pragma unroll
        for (int kc = 0; kc < 2; ++kc) {
            int r = w * 16 + (l & 15);
            int k = kc * 32 + (l >> 4) * 8;
            unsigned boA = ((unsigned)(r * 64 + k) * 2u) ^ (((unsigned)(r & 7)) << 4);
            bf16x8 afr = *(const bf16x8*)((char*)H2 + boA);
#pragma unroll
            for (int nt = 0; nt < 4; ++nt) {
                int col = nt * 16 + (l & 15);
                unsigned boB = ((unsigned)(col * 64 + k) * 2u) ^ (((unsigned)(col & 7)) << 4);
                bf16x8 bfr = *(const bf16x8*)((char*)W3s + boB);
                acc[nt] = __builtin_amdgcn_mfma_f32_16x16x32_bf16(afr, bfr, acc[nt], 0, 0, 0);
            }
        }
#pragma unroll
        for (int nt = 0; nt < 4; ++nt)
#pragma unroll
            for (int rg = 0; rg < 4; ++rg) {
                int row = row0 + w * 16 + (l >> 4) * 4 + rg;
                if (row < R) {
                    int col = nt * 16 + (l & 15);
                    out[(size_t)row * 64 + col] = f2bf(silu_f(acc[nt][rg]));
                }
            }
    }
}

// ---------------------------------------------------------------------------
// MFMA GEMM bf16->bf16 (wgemm). MODE 1: silu, 2: plain.
// ---------------------------------------------------------------------------
template <int K, int N, int MODE>
__global__ __launch_bounds__(256) void mfma_gemm(
    const unsigned short* __restrict__ in, int in_ld,
    const unsigned short* __restrict__ Wt,
    unsigned short* __restrict__ out, int out_ld,
    int R)
{
    constexpr int NT = N / 16;
    constexpr int KC = K / 32;
    constexpr int CPR = K / 8;
    __shared__ __align__(16) unsigned short Ash[64 * K];
    __shared__ __align__(16) unsigned short Bsh[N * K];

    const int tid = threadIdx.x;
    const int w = tid >> 6;
    const int l = tid & 63;
    const int row0 = blockIdx.x * 64;
    const int cb = blockIdx.y * N;

    for (int cid = tid; cid < 64 * CPR; cid += 256) {
        int r = cid / CPR, k8 = cid % CPR;
        int row = row0 + r;
        uint4 val = make_uint4(0u, 0u, 0u, 0u);
        if (row < R) val = *(const uint4*)(in + (size_t)row * in_ld + k8 * 8);
        unsigned bo = ((unsigned)(r * K + k8 * 8) * 2u) ^ (((unsigned)(r & 7)) << 4);
        *(uint4*)((char*)Ash + bo) = val;
    }
    for (int cid = tid; cid < N * CPR; cid += 256) {
        int nn = cid / CPR, k8 = cid % CPR;
        uint4 val = *(const uint4*)(Wt + (size_t)(cb + nn) * K + k8 * 8);
        unsigned bo = ((unsigned)(nn * K + k8 * 8) * 2u) ^ (((unsigned)(nn & 7)) << 4);
        *(uint4*)((char*)Bsh + bo) = val;
    }
    __syncthreads();

    bf16x8 afr[KC];
#pragma unroll
    for (int kc = 0; kc < KC; ++kc) {
        int r = w * 16 + (l & 15);
        int k = kc * 32 + (l >> 4) * 8;
        unsigned bo = ((unsigned)(r * K + k) * 2u) ^ (((unsigned)(r & 7)) << 4);
        afr[kc] = *(const bf16x8*)((char*)Ash + bo);
    }

    f32x4 acc[NT];
#pragma unroll
    for (int nt = 0; nt < NT; ++nt) {
        acc[nt] = (f32x4){0.f, 0.f, 0.f, 0.f};
#pragma unroll
        for (int kc = 0; kc < KC; ++kc) {
            int col = nt * 16 + (l & 15);
            int k = kc * 32 + (l >> 4) * 8;
            unsigned bo = ((unsigned)(col * K + k) * 2u) ^ (((unsigned)(col & 7)) << 4);
            bf16x8 bfr = *(const bf16x8*)((char*)Bsh + bo);
            acc[nt] = __builtin_amdgcn_mfma_f32_16x16x32_bf16(afr[kc], bfr, acc[nt], 0, 0, 0);
        }
    }

#pragma unroll
    for (int nt = 0; nt < NT; ++nt) {
#pragma unroll
        for (int rg = 0; rg < 4; ++rg) {
            int row = row0 + w * 16 + (l >> 4) * 4 + rg;
            if (row < R) {
                int col = cb + nt * 16 + (l & 15);
                float v = acc[nt][rg];
                if constexpr (MODE == 1) v = silu_f(v);
                out[(size_t)row * out_ld + col] = f2bf(v);
            }
        }
    }
}

// ---------------------------------------------------------------------------
// MFMA GEMM fp32 in: MODE 0 f32 store, 2 bf16 store, 6 f32 accumulate.
// ---------------------------------------------------------------------------
template <int K, int N, int MODE>
__global__ __launch_bounds__(256) void mfma_gemm_f32(
    const float* __restrict__ in, int in_ld,
    const unsigned short* __restrict__ Wt,
    float* __restrict__ out, int out_ld,
    int R, float scale)
{
    constexpr int NT = N / 16;
    constexpr int KC = K / 32;
    constexpr int CPR = K / 8;
    __shared__ __align__(16) unsigned short Ash[64 * K];
    __shared__ __align__(16) unsigned short Bsh[N * K];

    const int tid = threadIdx.x;
    const int w = tid >> 6;
    const int l = tid & 63;
    const int row0 = blockIdx.x * 64;
    const int cb = blockIdx.y * N;

    for (int cid = tid; cid < 64 * CPR; cid += 256) {
        int r = cid / CPR, k8 = cid % CPR;
        int row = row0 + r;
        union { unsigned short u16[8]; uint4 v; } pk;
        if (row < R) {
            const float* p = in + (size_t)row * in_ld + k8 * 8;
            float4 f0 = *(const float4*)p;
            float4 f1 = *(const float4*)(p + 4);
            pk.u16[0] = f2bf(f0.x); pk.u16[1] = f2bf(f0.y);
            pk.u16[2] = f2bf(f0.z); pk.u16[3] = f2bf(f0.w);
            pk.u16[4] = f2bf(f1.x); pk.u16[5] = f2bf(f1.y);
            pk.u16[6] = f2bf(f1.z); pk.u16[7] = f2bf(f1.w);
        } else {
            pk.v = make_uint4(0u, 0u, 0u, 0u);
        }
        unsigned bo = ((unsigned)(r * K + k8 * 8) * 2u) ^ (((unsigned)(r & 7)) << 4);
        *(uint4*)((char*)Ash + bo) = pk.v;
    }
    for (int cid = tid; cid < N * CPR; cid += 256) {
        int nn = cid / CPR, k8 = cid % CPR;
        uint4 val = *(const uint4*)(Wt + (size_t)(cb + nn) * K + k8 * 8);
        unsigned bo = ((unsigned)(nn * K + k8 * 8) * 2u) ^ (((unsigned)(nn & 7)) << 4);
        *(uint4*)((char*)Bsh + bo) = val;
    }
    __syncthreads();

    bf16x8 afr[KC];
#pragma unroll
    for (int kc = 0; kc < KC; ++kc) {
        int r = w * 16 + (l & 15);
        int k = kc * 32 + (l >> 4) * 8;
        unsigned bo = ((unsigned)(r * K + k) * 2u) ^ (((unsigned)(r & 7)) << 4);
        afr[kc] = *(const bf16x8*)((char*)Ash + bo);
    }

    f32x4 acc[NT];
#pragma unroll
    for (int nt = 0; nt < NT; ++nt) {
        acc[nt] = (f32x4){0.f, 0.f, 0.f, 0.f};
#pragma unroll
        for (int kc = 0; kc < KC; ++kc) {
            int col = nt * 16 + (l & 15);
            int k = kc * 32 + (l >> 4) * 8;
            unsigned bo = ((unsigned)(col * K + k) * 2u) ^ (((unsigned)(col & 7)) << 4);
            bf16x8 bfr = *(const bf16x8*)((char*)Bsh + bo);
            acc[nt] = __builtin_amdgcn_mfma_f32_16x16x32_bf16(afr[kc], bfr, acc[nt], 0, 0, 0);
        }
    }

#pragma unroll
    for (int nt = 0; nt < NT; ++nt) {
#pragma unroll
        for (int rg = 0; rg < 4; ++rg) {
            int row = row0 + w * 16 + (l >> 4) * 4 + rg;
            if (row < R) {
                int col = cb + nt * 16 + (l & 15);
                float v = acc[nt][rg] * scale;
                size_t idx = (size_t)row * out_ld + col;
                if constexpr (MODE == 6)      out[idx] += v;
                else if constexpr (MODE == 2) ((unsigned short*)out)[idx] = f2bf(v);
                else                          out[idx] = v;
            }
        }
    }
}

// batched edge-weight prep
struct WPE { const float* s[8]; unsigned short* d[8]; int K[8], N[8], Kp[8]; };
__global__ void k_wprepE(WPE wp)
{
    int m = blockIdx.y;
    int i = blockIdx.x * 256 + threadIdx.x;
    int tot = wp.N[m] * wp.Kp[m];
    if (i >= tot) return;
    int n = i / wp.Kp[m], k = i % wp.Kp[m];
    wp.d[m][i] = (k < wp.K[m]) ? f2bf(wp.s[m][k * wp.N[m] + n]) : (unsigned short)0;
}

struct WP10 { const float* s[10]; unsigned short* d[10]; };
__global__ void k_wprep10(WP10 wp)
{
    int m = blockIdx.y;
    int i = blockIdx.x * 256 + threadIdx.x;
    if (i >= 128 * 128) return;
    int n = i / 128, k = i % 128;
    wp.d[m][i] = f2bf(wp.s[m][k * 128 + n]);
}

// EMB2[s][c] = sum_k W_emb[s][k] * W_up1[k][c]  (fp32 exact, bf16 store)
__global__ void k_emb2mm(const float* __restrict__ W_emb, const float* __restrict__ W_up1,
                         unsigned short* __restrict__ EMB2)
{
    int i = blockIdx.x * 256 + threadIdx.x;
    if (i >= NEL * CC) return;
    int s = i / CC, c = i % CC;
    float acc = 0.f;
    for (int k = 0; k < CC; ++k)
        acc = fmaf(W_emb[s * CC + k], W_up1[k * CC + c], acc);
    EMB2[i] = f2bf(acc);
}

// species + hub lookup (hu = EMB2[sp] algebraically; h never materialized)
__global__ void k_spec_hub(const float* __restrict__ attrs,
                           const unsigned short* __restrict__ EMB2,
                           int* __restrict__ species, unsigned short* __restrict__ hub)
{
    int t = blockIdx.x * 256 + threadIdx.x;
    if (t >= NN * CC) return;
    int n = t >> 7, c = t & 127;
    int sp = 0;
#pragma unroll
    for (int j = 0; j < NEL; ++j)
        if (attrs[n * NEL + j] > 0.5f) sp = j;
    if (c == 0) species[n] = sp;
    hub[t] = EMB2[sp * CC + c];
}

// ---------------------------------------------------------------------------
// CSR build
// ---------------------------------------------------------------------------
__global__ void k_count(const int* __restrict__ rcv, int* __restrict__ deg)
{
    int e = blockIdx.x * 256 + threadIdx.x;
    if (e < EE) atomicAdd(&deg[rcv[e]], 1);
}

__global__ __launch_bounds__(256) void k_scan(const int* __restrict__ deg,
                                              int* __restrict__ rowptr,
                                              int* __restrict__ cursor)
{
    __shared__ int part[256];
    const int t = threadIdx.x;
    const int PER = (NN + 255) / 256;
    int base = t * PER;
    int s = 0;
    for (int j = 0; j < PER; ++j) { int idx = base + j; if (idx < NN) s += deg[idx]; }
    part[t] = s;
    __syncthreads();
    for (int off = 1; off < 256; off <<= 1) {
        int v = (t >= off) ? part[t - off] : 0;
        __syncthreads();
        part[t] += v;
        __syncthreads();
    }
    int run = (t == 0) ? 0 : part[t - 1];
    for (int j = 0; j < PER; ++j) {
        int idx = base + j;
        if (idx < NN) { rowptr[idx] = run; cursor[idx] = run; run += deg[idx]; }
    }
    if (t == 255) rowptr[NN] = part[255];
}

__global__ void k_fill(const int* __restrict__ rcv, int* __restrict__ cursor,
                       int* __restrict__ perm)
{
    int e = blockIdx.x * 256 + threadIdx.x;
    if (e >= EE) return;
    int pos = atomicAdd(&cursor[rcv[e]], 1);
    perm[pos] = e;
}

// geometry for one edge e, written at CSR slot i
__device__ __forceinline__ void geom_one(
    const float* __restrict__ pos, const float* __restrict__ shifts,
    const int* __restrict__ snd, const int* __restrict__ rcv,
    int e, int i, float* __restrict__ Yv, unsigned short* __restrict__ efb,
    int* __restrict__ psnd)
{
    int s = snd[e], r = rcv[e];
    psnd[i] = s;
    float vx = pos[r * 3 + 0] - pos[s * 3 + 0] + shifts[e * 3 + 0];
    float vy = pos[r * 3 + 1] - pos[s * 3 + 1] + shifts[e * 3 + 1];
    float vz = pos[r * 3 + 2] - pos[s * 3 + 2] + shifts[e * 3 + 2];
    float len = sqrtf(vx * vx + vy * vy + vz * vz + 1e-12f);
    float inv = 1.0f / len;
    const float SQ3 = 1.7320508075688772f;
    Yv[i * 3 + 0] = SQ3 * vx * inv;
    Yv[i * 3 + 1] = SQ3 * vy * inv;
    Yv[i * 3 + 2] = SQ3 * vz * inv;
    float u = len * 0.2f;
    float fc = 0.0f;
    if (u < 1.0f) {
        float u2 = u * u, u4 = u2 * u2, u5 = u4 * u, u6 = u5 * u, u7 = u6 * u;
        fc = 1.0f - 21.0f * u5 + 35.0f * u6 - 15.0f * u7;
    }
    float pref = 0.6324555320336759f * inv * fc;
    const float PIO5 = 0.6283185307179586f;
    union { unsigned short u16[8]; uint4 v; } pk;
#pragma unroll
    for (int n = 1; n <= 8; ++n)
        pk.u16[n - 1] = f2bf(pref * sinf((float)n * PIO5 * len));
    uint4* dst = (uint4*)(efb + (size_t)i * 32);
    dst[0] = pk.v;
    dst[1] = make_uint4(0u, 0u, 0u, 0u);
    dst[2] = make_uint4(0u, 0u, 0u, 0u);
    dst[3] = make_uint4(0u, 0u, 0u, 0u);
}

// fused: per-node wave rank-sort + geometry written directly at sorted slot
__global__ __launch_bounds__(256) void k_sortgeom(
    const int* __restrict__ rowptr, int* __restrict__ perm,
    const float* __restrict__ pos, const float* __restrict__ shifts,
    const int* __restrict__ snd, const int* __restrict__ rcv,
    float* __restrict__ Yv, unsigned short* __restrict__ efb,
    int* __restrict__ psnd)
{
    int gid = blockIdx.x * 256 + threadIdx.x;
    int wid = gid >> 6;
    int lane = gid & 63;
    if (wid >= NN) return;
    int a = rowptr[wid], b = rowptr[wid + 1];
    int d = b - a;
    if (d <= 0) return;
    if (d <= 64) {
        int v = (lane < d) ? perm[a + lane] : 0x7fffffff;
        int rank = 0;
        for (int j = 0; j < 64; ++j) {
            int vj = __shfl(v, j);
            if (j < d && vj < v) ++rank;
        }
        if (lane < d)
            geom_one(pos, shifts, snd, rcv, v, a + rank, Yv, efb, psnd);
    } else {
        if (lane == 0) {
            for (int i = a + 1; i < b; ++i) {
                int v = perm[i]; int j = i - 1;
                while (j >= a && perm[j] > v) { perm[j + 1] = perm[j]; --j; }
                perm[j + 1] = v;
            }
            __threadfence();
        }
        // wave-synchronous: all lanes reach here after lane 0's fence
        for (int i = a + lane; i < b; i += 64)
            geom_one(pos, shifts, snd, rcv, perm[i], i, Yv, efb, psnd);
    }
}

// ---------------------------------------------------------------------------
// gathers: coalesced bf16 wb + random bf16 payload rows
// ---------------------------------------------------------------------------
__global__ __launch_bounds__(256) void k_gather1(
    const int* __restrict__ rowptr, const int* __restrict__ psnd,
    const float* __restrict__ Yv, const unsigned short* __restrict__ wb,
    int e0, int e1,
    const unsigned short* __restrict__ gS,
    float* __restrict__ outS, float* __restrict__ outV)
{
    const int t = threadIdx.x;
    const int c = t & 127;
    const int n = blockIdx.x * 2 + (t >> 7);
    if (n >= NN) return;
    int rs = rowptr[n], re = rowptr[n + 1];
    if (rs < e0) rs = e0;
    if (re > e1) re = e1;
    if (rs >= re) return;
    float accs = 0.f, a0 = 0.f, a1 = 0.f, a2 = 0.f;
    for (int i = rs; i < re; ++i) {
        const unsigned short* wp = wb + (size_t)(i - e0) * 256;
        float wss = bf2f(wp[c]);
        float wsv = bf2f(wp[128 + c]);
        float h = bf2f(gS[psnd[i] * 128 + c]);
        float y0 = Yv[i * 3], y1 = Yv[i * 3 + 1], y2 = Yv[i * 3 + 2];
        accs = fmaf(wss, h, accs);
        float tv = wsv * h;
        a0 = fmaf(tv, y0, a0); a1 = fmaf(tv, y1, a1); a2 = fmaf(tv, y2, a2);
    }
    outS[n * 128 + c] += accs;
    outV[n * 384 + c]       += a0;
    outV[n * 384 + 128 + c] += a1;
    outV[n * 384 + 256 + c] += a2;
}

__global__ __launch_bounds__(256) void k_gather23(
    const int* __restrict__ rowptr, const int* __restrict__ psnd,
    const float* __restrict__ Yv, const unsigned short* __restrict__ wb,
    int e0, int e1,
    const unsigned short* __restrict__ gS, const unsigned short* __restrict__ gV,
    float* __restrict__ outS, float* __restrict__ outV)
{
    const int t = threadIdx.x;
    const int c = t & 127;
    const int n = blockIdx.x * 2 + (t >> 7);
    if (n >= NN) return;
    int rs = rowptr[n], re = rowptr[n + 1];
    if (rs < e0) rs = e0;
    if (re > e1) re = e1;
    if (rs >= re) return;
    float accs = 0.f, a0 = 0.f, a1 = 0.f, a2 = 0.f;
    for (int i = rs; i < re; ++i) {
        const unsigned short* wp = wb + (size_t)(i - e0) * 512;
        float wa = bf2f(wp[c]);
        float wbv = bf2f(wp[128 + c]);
        float wc = bf2f(wp[256 + c]);
        float wd = bf2f(wp[384 + c]);
        int s = psnd[i];
        float hs = bf2f(gS[s * 128 + c]);
        float v0 = bf2f(gV[s * 384 + c]);
        float v1 = bf2f(gV[s * 384 + 128 + c]);
        float v2 = bf2f(gV[s * 384 + 256 + c]);
        float y0 = Yv[i * 3], y1 = Yv[i * 3 + 1], y2 = Yv[i * 3 + 2];
        float hd = v0 * y0 + v1 * y1 + v2 * y2;
        accs = fmaf(wa, hs, accs);
        accs = fmaf(wbv, hd * 0.57735026919f, accs);
        float tv = wc * hs;
        a0 = fmaf(tv, y0, a0); a0 = fmaf(wd, v0, a0);
        a1 = fmaf(tv, y1, a1); a1 = fmaf(wd, v1, a1);
        a2 = fmaf(tv, y2, a2); a2 = fmaf(wd, v2, a2);
    }
    outS[n * 128 + c] += accs;
    outV[n * 384 + c]       += a0;
    outV[n * 384 + 128 + c] += a1;
    outV[n * 384 + 256 + c] += a2;
}

// ---------------------------------------------------------------------------
__global__ void k_B1(const int* __restrict__ species,
                     const float* __restrict__ As_l, const float* __restrict__ Av_l,
                     const float* __restrict__ P_s1, const float* __restrict__ P_ss,
                     const float* __restrict__ P_vv, const float* __restrict__ P_v1,
                     const float* __restrict__ P_sv,
                     float* __restrict__ Bs, float* __restrict__ Bv)
{
    int t = blockIdx.x * 256 + threadIdx.x;
    if (t >= NN * CC) return;
    int n = t >> 7, c = t & 127;
    int sp = species[n];
    int pb = sp * CC + c;
    int vb = n * 384 + c;
    float as = As_l[t];
    float a0 = Av_l[vb], a1 = Av_l[vb + CC], a2 = Av_l[vb + 2 * CC];
    Bs[t] = P_s1[pb] * as + P_ss[pb] * as * as
          + P_vv[pb] * (a0 * a0 + a1 * a1 + a2 * a2) * 0.57735026919f;
    float tv = P_v1[pb] + P_sv[pb] * as;
    Bv[vb] = tv * a0; Bv[vb + CC] = tv * a1; Bv[vb + 2 * CC] = tv * a2;
}

__global__ void k_B2(const int* __restrict__ species,
                     const float* __restrict__ As_l, const float* __restrict__ Av_l,
                     const float* __restrict__ P_v1, const float* __restrict__ P_sv,
                     float* __restrict__ Bv)
{
    int t = blockIdx.x * 256 + threadIdx.x;
    if (t >= NN * CC) return;
    int n = t >> 7, c = t & 127;
    int sp = species[n];
    int pb = sp * CC + c;
    int vb = n * 384 + c;
    float as = As_l[t];
    float tv = P_v1[pb] + P_sv[pb] * as;
    Bv[vb] = tv * Av_l[vb];
    Bv[vb + CC] = tv * Av_l[vb + CC];
    Bv[vb + 2 * CC] = tv * Av_l[vb + 2 * CC];
}

__global__ void k_sc(const int* __restrict__ species, const float* __restrict__ h_v,
                     const float* __restrict__ Wsk, float* __restrict__ h2v)
{
    int n = blockIdx.x, f = threadIdx.x;
    int sp = species[n];
    const float* Wp = Wsk + sp * (CC * CC);
    const float* hvn = h_v + n * 384;
    float a0 = 0.f, a1 = 0.f, a2 = 0.f;
    for (int c = 0; c < CC; ++c) {
        float w = Wp[c * CC + f];
        a0 = fmaf(hvn[c], w, a0);
        a1 = fmaf(hvn[CC + c], w, a1);
        a2 = fmaf(hvn[2 * CC + c], w, a2);
    }
    h2v[n * 384 + f] = a0;
    h2v[n * 384 + CC + f] = a1;
    h2v[n * 384 + 2 * CC + f] = a2;
}

__global__ void k_node_out2(const float* __restrict__ h2v, const float* __restrict__ h_v,
                            const float* __restrict__ R1,
                            const float* __restrict__ Rmid, const float* __restrict__ Rout,
                            const float* __restrict__ charges, const float* __restrict__ pos,
                            float* __restrict__ out, float* __restrict__ tot)
{
    int n = blockIdx.x, l = threadIdx.x;
    float r0 = 0.f, r1 = 0.f;
#pragma unroll
    for (int k = 0; k < 16; ++k) {
        r0 = fmaf(Rmid[l * 16 + k], Rout[k], r0);
        r1 = fmaf(Rmid[(64 + l) * 16 + k], Rout[k], r1);
    }
    const float* hb = h2v + n * 384;
    const float* hv1 = h_v + n * 384;
    float R1a = R1[l], R1b = R1[64 + l];
    float red[3];
#pragma unroll
    for (int d = 0; d < 3; ++d) {
        float v = hb[d * CC + l] * r0 + hb[d * CC + 64 + l] * r1;
        float dv = hv1[d * CC + l] * R1a + hv1[d * CC + 64 + l] * R1b;
        float m = dv + 0.5f * v;
        for (int o = 32; o > 0; o >>= 1) m += __shfl_down(m, o);
        red[d] = m;
    }
    if (l == 0) {
        float q = charges[n];
#pragma unroll
        for (int d = 0; d < 3; ++d) {
            float a = red[d];
            out[48 + n * 3 + d] = a;
            tot[n * 3 + d] = a + q * pos[n * 3 + d];
        }
    }
}

__global__ __launch_bounds__(256) void k_greduce(const float* __restrict__ tot,
                                                 const int* __restrict__ batch,
                                                 float* __restrict__ out)
{
    __shared__ float r[256 * 3];
    const int g = blockIdx.x;
    const int t = threadIdx.x;
    float s0 = 0.f, s1 = 0.f, s2 = 0.f;
    for (int n = t; n < NN; n += 256) {
        if (batch[n] == g) {
            s0 += tot[n * 3]; s1 += tot[n * 3 + 1]; s2 += tot[n * 3 + 2];
        }
    }
    r[t] = s0; r[256 + t] = s1; r[512 + t] = s2;
    __syncthreads();
    for (int off = 128; off > 0; off >>= 1) {
        if (t < off) {
            r[t] += r[t + off];
            r[256 + t] += r[256 + t + off];
            r[512 + t] += r[512 + t + off];
        }
        __syncthreads();
    }
    if (t < 3) out[g * 3 + t] = r[t * 256];
}

// ---------------------------------------------------------------------------
extern "C" void kernel_launch(void* const* d_in, const int* in_sizes, int n_in,
                              void* d_out, int out_size, void* d_ws, size_t ws_size,
                              hipStream_t stream)
{
    const float* positions = (const float*)d_in[0];
    const float* node_attrs = (const float*)d_in[1];
    const float* charges = (const float*)d_in[2];
    const float* shifts = (const float*)d_in[3];
    const int*   eidx = (const int*)d_in[4];
    const int*   batch = (const int*)d_in[5];
    const float* W_emb  = (const float*)d_in[7];
    const float* W_up1  = (const float*)d_in[8];
    const float* Wr1_1  = (const float*)d_in[9];
    const float* Wr1_2  = (const float*)d_in[10];
    const float* Wr1_3  = (const float*)d_in[11];
    const float* Wr1_o  = (const float*)d_in[12];
    const float* Wlin1_s = (const float*)d_in[13];
    const float* Wlin1_v = (const float*)d_in[14];
    const float* P1_s1 = (const float*)d_in[15];
    const float* P1_ss = (const float*)d_in[16];
    const float* P1_vv = (const float*)d_in[17];
    const float* P1_v1 = (const float*)d_in[18];
    const float* P1_sv = (const float*)d_in[19];
    const float* Lp1_s = (const float*)d_in[20];
    const float* Lp1_v = (const float*)d_in[21];
    const float* R1    = (const float*)d_in[22];
    const float* Wsk   = (const float*)d_in[23];
    const float* Wup2_s = (const float*)d_in[24];
    const float* Wup2_v = (const float*)d_in[25];
    const float* Wr2_1 = (const float*)d_in[26];
    const float* Wr2_2 = (const float*)d_in[27];
    const float* Wr2_3 = (const float*)d_in[28];
    const float* Wr2_o = (const float*)d_in[29];
    const float* Wlin2_s = (const float*)d_in[30];
    const float* Wlin2_v = (const float*)d_in[31];
    const float* P2_v1 = (const float*)d_in[32];
    const float* P2_sv = (const float*)d_in[33];
    const float* Lp2_v = (const float*)d_in[34];
    const float* Rmid  = (const float*)d_in[35];
    const float* Rout  = (const float*)d_in[36];
    (void)in_sizes; (void)n_in; (void)out_size;

    const int* snd = eidx;
    const int* rcv = eidx + EE;
    float* out = (float*)d_out;

    char* ws = (char*)d_ws;
    size_t off = 0;
    auto alloc = [&](size_t bytes) -> void* {
        void* p = (void*)(ws + off);
        off = (off + bytes + 255) & ~(size_t)255;
        return p;
    };
    int*   species = (int*)alloc((size_t)NN * 4);
    int*   deg     = (int*)alloc((size_t)NN * 4);
    int*   rowptr  = (int*)alloc((size_t)(NN + 16) * 4);
    int*   cursor  = (int*)alloc((size_t)NN * 4);
    int*   perm    = (int*)alloc((size_t)EE * 4);
    int*   psnd    = (int*)alloc((size_t)EE * 4);
    float* Yv   = (float*)alloc((size_t)EE * 3 * 4);
    unsigned short* efb = (unsigned short*)alloc((size_t)EE * 32 * 2);
    float* A_s  = (float*)alloc((size_t)NN * CC * 4);       // contiguous with A_v
    float* A_v  = (float*)alloc((size_t)NN * 3 * CC * 4);
    float* hbuf = (float*)alloc((size_t)NN * CC * 4);
    float* hu   = (float*)alloc((size_t)NN * CC * 4);
    float* h_v  = (float*)alloc((size_t)NN * 3 * CC * 4);
    float* h2v  = (float*)alloc((size_t)NN * 3 * CC * 4);
    float* tot  = (float*)alloc((size_t)NN * 3 * 4);
    unsigned short* hub = (unsigned short*)alloc((size_t)NN * CC * 2);
    unsigned short* hsb = (unsigned short*)alloc((size_t)NN * CC * 2);
    unsigned short* hvb = (unsigned short*)alloc((size_t)NN * 3 * CC * 2);
    unsigned short* EMB2 = (unsigned short*)alloc(NEL * CC * 2);
    unsigned short* W1t_l1 = (unsigned short*)alloc(64 * 32 * 2);
    unsigned short* W2t_l1 = (unsigned short*)alloc(64 * 64 * 2);
    unsigned short* W3t_l1 = (unsigned short*)alloc(64 * 64 * 2);
    unsigned short* Wot_l1 = (unsigned short*)alloc(256 * 64 * 2);
    unsigned short* W1t_l2 = (unsigned short*)alloc(64 * 32 * 2);
    unsigned short* W2t_l2 = (unsigned short*)alloc(64 * 64 * 2);
    unsigned short* W3t_l2 = (unsigned short*)alloc(64 * 64 * 2);
    unsigned short* Wot_l2 = (unsigned short*)alloc(512 * 64 * 2);
    unsigned short* Wn[10];
    for (int m = 0; m < 10; ++m) Wn[m] = (unsigned short*)alloc(128 * 128 * 2);
    unsigned short* hbA = (unsigned short*)alloc((size_t)EE * 64 * 2);

    int C = 16;
    if      (off + (size_t)EE * 512 * 2 + 4096 <= ws_size)        C = 1;
    else if (off + (size_t)(EE / 2) * 512 * 2 + 4096 <= ws_size)  C = 2;
    else if (off + (size_t)(EE / 4) * 512 * 2 + 4096 <= ws_size)  C = 4;
    else if (off + (size_t)(EE / 8) * 512 * 2 + 4096 <= ws_size)  C = 8;
    const int EC = EE / C;
    unsigned short* wbuf = (unsigned short*)alloc((size_t)EC * 512 * 2);

    const float inv16 = 1.0f / 16.0f;
    const float one = 1.0f;

    hipMemsetAsync(deg, 0, (size_t)NN * 4, stream);
    hipMemsetAsync(A_s, 0, (size_t)NN * 4 * CC * 4, stream);   // A_s + A_v contiguous

    // weight prep (3 small dispatches)
    {
        WPE wp;
        const float* s[8] = {Wr1_1, Wr1_2, Wr1_3, Wr1_o, Wr2_1, Wr2_2, Wr2_3, Wr2_o};
        unsigned short* d[8] = {W1t_l1, W2t_l1, W3t_l1, Wot_l1, W1t_l2, W2t_l2, W3t_l2, Wot_l2};
        int Ks[8] = {8, 64, 64, 64, 8, 64, 64, 64};
        int Ns[8] = {64, 64, 64, 256, 64, 64, 64, 512};
        int Kp[8] = {32, 64, 64, 64, 32, 64, 64, 64};
        for (int m = 0; m < 8; ++m) { wp.s[m] = s[m]; wp.d[m] = d[m]; wp.K[m] = Ks[m]; wp.N[m] = Ns[m]; wp.Kp[m] = Kp[m]; }
        k_wprepE<<<dim3(cdiv(512 * 64, 256), 8), 256, 0, stream>>>(wp);
    }
    {
        WP10 wp;
        const float* srcs[10] = {W_up1, Wlin1_s, Wlin1_v, Lp1_s, Lp1_v,
                                 Wup2_s, Wup2_v, Wlin2_s, Wlin2_v, Lp2_v};
        for (int m = 0; m < 10; ++m) { wp.s[m] = srcs[m]; wp.d[m] = Wn[m]; }
        k_wprep10<<<dim3(cdiv(128 * 128, 256), 10), 256, 0, stream>>>(wp);
    }
    k_emb2mm<<<cdiv(NEL * CC, 256), 256, 0, stream>>>(W_emb, W_up1, EMB2);

    // ---- CSR build + fused sort+geometry ----
    k_count<<<cdiv(EE, 256), 256, 0, stream>>>(rcv, deg);
    k_scan<<<1, 256, 0, stream>>>(deg, rowptr, cursor);
    k_fill<<<cdiv(EE, 256), 256, 0, stream>>>(rcv, cursor, perm);
    k_sortgeom<<<cdiv(NN * 64, 256), 256, 0, stream>>>(
        rowptr, perm, positions, shifts, snd, rcv, Yv, efb, psnd);

    k_spec_hub<<<cdiv(NN * CC, 256), 256, 0, stream>>>(node_attrs, EMB2, species, hub);

    // ---- layer 1: fused edge MLP -> chunked wgemm + gather ----
    mfma_mlp3<32><<<cdiv(EE, 64), 256, 0, stream>>>(efb, W1t_l1, W2t_l1, W3t_l1, hbA, EE);
    for (int ch = 0; ch < C; ++ch) {
        int e0 = ch * EC, e1 = e0 + EC;
        mfma_gemm<64, 128, 2><<<dim3(cdiv(EC, 64), 2), 256, 0, stream>>>(
            hbA + (size_t)e0 * 64, 64, Wot_l1, wbuf, 256, EC);
        k_gather1<<<NN / 2, 256, 0, stream>>>(
            rowptr, psnd, Yv, wbuf, e0, e1, hub, A_s, A_v);
    }

    // ---- layer 1 node side (MFMA) ----
    mfma_gemm_f32<128, 128, 0><<<cdiv(NN, 64), 256, 0, stream>>>(
        A_s, 128, Wn[1], A_s, 128, NN, inv16);
    mfma_gemm_f32<128, 128, 0><<<cdiv(3 * NN, 64), 256, 0, stream>>>(
        A_v, 128, Wn[2], A_v, 128, 3 * NN, inv16);
    k_B1<<<cdiv(NN * CC, 256), 256, 0, stream>>>(
        species, A_s, A_v, P1_s1, P1_ss, P1_vv, P1_v1, P1_sv, hbuf /*Bs*/, A_v /*Bv*/);
    mfma_gemm_f32<128, 128, 0><<<cdiv(NN, 64), 256, 0, stream>>>(
        hbuf, 128, Wn[3], hu /*h_s*/, 128, NN, one);
    mfma_gemm_f32<128, 128, 0><<<cdiv(3 * NN, 64), 256, 0, stream>>>(
        A_v /*Bv*/, 128, Wn[4], h_v, 128, 3 * NN, one);
    mfma_gemm_f32<128, 128, 2><<<cdiv(NN, 64), 256, 0, stream>>>(
        hu /*h_s*/, 128, Wn[5], (float*)hsb, 128, NN, one);
    mfma_gemm_f32<128, 128, 2><<<cdiv(3 * NN, 64), 256, 0, stream>>>(
        h_v, 128, Wn[6], (float*)hvb, 128, 3 * NN, one);

    // ---- layer 2: fused edge MLP -> chunked wgemm + merged gather ----
    hipMemsetAsync(A_s, 0, (size_t)NN * 4 * CC * 4, stream);
    mfma_mlp3<32><<<cdiv(EE, 64), 256, 0, stream>>>(efb, W1t_l2, W2t_l2, W3t_l2, hbA, EE);
    for (int ch = 0; ch < C; ++ch) {
        int e0 = ch * EC, e1 = e0 + EC;
        mfma_gemm<64, 128, 2><<<dim3(cdiv(EC, 64), 4), 256, 0, stream>>>(
            hbA + (size_t)e0 * 64, 64, Wot_l2, wbuf, 512, EC);
        k_gather23<<<NN / 2, 256, 0, stream>>>(
            rowptr, psnd, Yv, wbuf, e0, e1, hsb, hvb, A_s, A_v);
    }

    // ---- layer 2 node side (MFMA) ----
    mfma_gemm_f32<128, 128, 0><<<cdiv(NN, 64), 256, 0, stream>>>(
        A_s, 128, Wn[7], A_s, 128, NN, inv16);
    mfma_gemm_f32<128, 128, 0><<<cdiv(3 * NN, 64), 256, 0, stream>>>(
        A_v, 128, Wn[8], A_v, 128, 3 * NN, inv16);
    k_sc<<<NN, 128, 0, stream>>>(species, h_v, Wsk, h2v);
    k_B2<<<cdiv(NN * CC, 256), 256, 0, stream>>>(species, A_s, A_v, P2_v1, P2_sv, A_v /*B2v*/);
    mfma_gemm_f32<128, 128, 6><<<cdiv(3 * NN, 64), 256, 0, stream>>>(
        A_v /*B2v*/, 128, Wn[9], h2v, 128, 3 * NN, one);

    k_node_out2<<<NN, 64, 0, stream>>>(h2v, h_v, R1, Rmid, Rout, charges, positions, out, tot);
    k_greduce<<<NGR, 256, 0, stream>>>(tot, batch, out);
}